// Round 1
// baseline (876.437 us; speedup 1.0000x reference)
//
#include <hip/hip_runtime.h>

constexpr int NN = 100000;   // nodes
constexpr int NE = 1600000;  // edges
constexpr int HD = 256;      // hidden

typedef __attribute__((ext_vector_type(4))) float  f32x4;
typedef __attribute__((ext_vector_type(8))) short  bf16x8;

__device__ __forceinline__ float bf2f(short u) {
  union { unsigned int i; float f; } c;
  c.i = ((unsigned int)(unsigned short)u) << 16;
  return c.f;
}
__device__ __forceinline__ short f2bf(float f) {
  union { float f; unsigned int i; } c; c.f = f;
  unsigned int i = c.i + 0x7fffu + ((c.i >> 16) & 1u);
  return (short)(i >> 16);
}

// ---- edge dtype detection: int64 -> all odd 32-bit words (high words) are 0 ----
__global__ void k_detect(const int* __restrict__ ew, int* __restrict__ flag) {
  __shared__ int bad;
  if (threadIdx.x == 0) bad = 0;
  __syncthreads();
  int nz = 0;
  for (int i = threadIdx.x; i < 2048; i += 256) nz |= ew[2 * i + 1];
  if (nz) atomicOr(&bad, 1);
  __syncthreads();
  if (threadIdx.x == 0) *flag = (bad == 0) ? 1 : 0;
}

// ---- convert weights to bf16, transposed for LDS-friendly B staging ----
__global__ void k_cvtW(const float* __restrict__ W1, const float* __restrict__ W2,
                       const float* __restrict__ Wl1, short* __restrict__ W1T,
                       short* __restrict__ W2T, short* __restrict__ Wl1T) {
  int b = blockIdx.x, t = threadIdx.x;
  if (b < 256)       W1T[b * 256 + t]        = f2bf(W1[t * 256 + b]);
  else if (b < 512){ int n = b - 256; W2T[n * 256 + t]  = f2bf(W2[t * 256 + n]); }
  else             { int n = b - 512; Wl1T[n * 256 + t] = f2bf(Wl1[t * 128 + n]); }
}

__global__ void k_hist(const int* __restrict__ ew, const int* __restrict__ flag,
                       int* __restrict__ deg) {
  int m64 = *flag;
  int stride = gridDim.x * blockDim.x;
  for (int e = blockIdx.x * blockDim.x + threadIdx.x; e < NE; e += stride) {
    int d = m64 ? ew[2 * (NE + e)] : ew[NE + e];
    atomicAdd(&deg[d], 1);
  }
}

__global__ void k_scan1(const int* __restrict__ deg, int* __restrict__ bsum) {
  __shared__ int s[256];
  int t = threadIdx.x;
  int base = blockIdx.x * 1024 + t * 4;
  int v = 0;
#pragma unroll
  for (int i = 0; i < 4; i++) { int idx = base + i; if (idx < NN) v += deg[idx]; }
  s[t] = v; __syncthreads();
  for (int o = 128; o > 0; o >>= 1) { if (t < o) s[t] += s[t + o]; __syncthreads(); }
  if (t == 0) bsum[blockIdx.x] = s[0];
}

__global__ void k_scan2(int* __restrict__ bsum, int nb) {
  __shared__ int s[128];
  int t = threadIdx.x;
  int v = (t < nb) ? bsum[t] : 0;
  s[t] = v; __syncthreads();
  for (int o = 1; o < 128; o <<= 1) {
    int u = (t >= o) ? s[t - o] : 0;
    __syncthreads();
    s[t] += u;
    __syncthreads();
  }
  if (t < nb) bsum[t] = s[t] - v;  // exclusive
}

__global__ void k_scan3(const int* __restrict__ deg, const int* __restrict__ bsum,
                        int* __restrict__ off_, int* __restrict__ cur_) {
  __shared__ int s[256];
  int t = threadIdx.x;
  int base = blockIdx.x * 1024 + t * 4;
  int v[4]; int sum = 0;
#pragma unroll
  for (int i = 0; i < 4; i++) { int idx = base + i; v[i] = (idx < NN) ? deg[idx] : 0; sum += v[i]; }
  s[t] = sum; __syncthreads();
  for (int o = 1; o < 256; o <<= 1) {
    int u = (t >= o) ? s[t - o] : 0;
    __syncthreads();
    s[t] += u;
    __syncthreads();
  }
  int run = s[t] - sum + bsum[blockIdx.x];
#pragma unroll
  for (int i = 0; i < 4; i++) {
    int idx = base + i;
    if (idx < NN) { off_[idx] = run; cur_[idx] = run; run += v[i]; }
    else if (idx == NN) { off_[idx] = run; }
  }
}

__global__ void k_fill(const int* __restrict__ ew, const int* __restrict__ flag,
                       int* __restrict__ cur_, int* __restrict__ csr) {
  int m64 = *flag;
  int stride = gridDim.x * blockDim.x;
  for (int e = blockIdx.x * blockDim.x + threadIdx.x; e < NE; e += stride) {
    int d = m64 ? ew[2 * (NE + e)] : ew[NE + e];
    int s = m64 ? ew[2 * e] : ew[e];
    int pos = atomicAdd(&cur_[d], 1);
    csr[pos] = s;
  }
}

// one block per node: h0 = x[n] + sum_{in-edges} x[src]
__global__ __launch_bounds__(256) void k_agg(const float* __restrict__ x,
                                             const int* __restrict__ off_,
                                             const int* __restrict__ csr,
                                             short* __restrict__ h0) {
  int n = blockIdx.x, t = threadIdx.x;
  int s0 = off_[n], s1 = off_[n + 1];
  float acc = x[(size_t)n * HD + t];
  for (int j = s0; j < s1; j++) {
    int s = csr[j];
    acc += x[(size_t)s * HD + t];
  }
  h0[(size_t)n * HD + t] = f2bf(acc);
}

// C[M x 256] = A[M x 256](bf16) * B(256 x 256, given as BT[256][256] bf16) + bias, opt lrelu^2
template <int ACT>
__global__ __launch_bounds__(256) void k_gemm(const short* __restrict__ A,
                                              const short* __restrict__ BT,
                                              const float* __restrict__ bias,
                                              short* __restrict__ C, int M) {
  __shared__ short ldsA[4096];  // [128][32] bf16
  __shared__ short ldsB[4096];  // [128 cols][32 k] bf16
  int tid = threadIdx.x;
  int bm = blockIdx.x >> 1, bn = blockIdx.x & 1;
  int bm0 = bm * 128, bn0 = bn * 128;
  int lane = tid & 63, w = tid >> 6;
  int wm = w >> 1, wn = w & 1;
  int lr = lane & 15, lg = lane >> 4;
  f32x4 acc[4][4] = {};
  for (int kt = 0; kt < 256; kt += 32) {
#pragma unroll
    for (int c = 0; c < 2; c++) {
      int chunk = c * 256 + tid;
      int row = chunk >> 2;
      int kc = (chunk & 3) * 8;
      int rA = bm0 + row; if (rA > M - 1) rA = M - 1;
      *((bf16x8*)ldsA + chunk) = *(const bf16x8*)(A + (size_t)rA * 256 + kt + kc);
      *((bf16x8*)ldsB + chunk) = *(const bf16x8*)(BT + (size_t)(bn0 + row) * 256 + kt + kc);
    }
    __syncthreads();
    bf16x8 af[4], bfr[4];
#pragma unroll
    for (int mi = 0; mi < 4; mi++) af[mi] = *((const bf16x8*)ldsA + ((wm * 64 + mi * 16 + lr) * 4 + lg));
#pragma unroll
    for (int ni = 0; ni < 4; ni++) bfr[ni] = *((const bf16x8*)ldsB + ((wn * 64 + ni * 16 + lr) * 4 + lg));
#pragma unroll
    for (int mi = 0; mi < 4; mi++)
#pragma unroll
      for (int ni = 0; ni < 4; ni++)
        acc[mi][ni] = __builtin_amdgcn_mfma_f32_16x16x32_bf16(af[mi], bfr[ni], acc[mi][ni], 0, 0, 0);
    __syncthreads();
  }
#pragma unroll
  for (int ni = 0; ni < 4; ni++) {
    int col = bn0 + wn * 64 + ni * 16 + lr;
    float bv = bias[col];
#pragma unroll
    for (int mi = 0; mi < 4; mi++) {
#pragma unroll
      for (int r = 0; r < 4; r++) {
        int row = bm0 + wm * 64 + mi * 16 + lg * 4 + r;
        if (row < M) {
          float tv = acc[mi][ni][r] + bv;
          if (ACT == 1) tv = tv > 0.f ? tv : 0.01f * tv;  // lrelu(lrelu(t,0.1),0.1)
          C[(size_t)row * 256 + col] = f2bf(tv);
        }
      }
    }
  }
}

// per-column sum and sumsq over M rows of a bf16 [M][256] buffer
__global__ void k_colstats(const short* __restrict__ B, float* __restrict__ sum,
                           float* __restrict__ ssq, int M) {
  int t = threadIdx.x;
  int r0 = blockIdx.x * 256;
  int rend = r0 + 256 < M ? r0 + 256 : M;
  float s = 0.f, q = 0.f;
  for (int r = r0; r < rend; r++) {
    float v = bf2f(B[(size_t)r * 256 + t]);
    s += v; q += v * v;
  }
  atomicAdd(&sum[t], s);
  atomicAdd(&ssq[t], q);
}

__global__ void k_bnprep(const float* __restrict__ sum, const float* __restrict__ ssq,
                         const float* __restrict__ g, const float* __restrict__ be,
                         float* __restrict__ scale, float* __restrict__ shift, int M) {
  int c = threadIdx.x;
  float mu = sum[c] / (float)M;
  float var = ssq[c] / (float)M - mu * mu;
  float rs = rsqrtf(var + 1e-5f);
  float sc = g[c] * rs;
  scale[c] = sc;
  shift[c] = be[c] - mu * sc;
}

// t1n = relu(bn(t1))
__global__ void k_elem1(const short* __restrict__ in, const float* __restrict__ sc,
                        const float* __restrict__ sh, short* __restrict__ outb) {
  __shared__ float ls[256], lh[256];
  int t = threadIdx.x;
  ls[t] = sc[t]; lh[t] = sh[t];
  __syncthreads();
  int stride = gridDim.x * blockDim.x;
  for (int chunk = blockIdx.x * blockDim.x + t; chunk < NN * HD / 8; chunk += stride) {
    bf16x8 v = *((const bf16x8*)in + chunk);
    int c0 = (chunk & 31) * 8;
    bf16x8 o;
#pragma unroll
    for (int j = 0; j < 8; j++) {
      float f = bf2f(v[j]) * ls[c0 + j] + lh[c0 + j];
      f = f > 0.f ? f : 0.f;
      o[j] = f2bf(f);
    }
    *((bf16x8*)outb + chunk) = o;
  }
}

// hin = bf16(x + 0.01 * lrelu(bn4(v)))
__global__ void k_elem2(const short* __restrict__ vin, const float* __restrict__ x,
                        const float* __restrict__ sc, const float* __restrict__ sh,
                        short* __restrict__ outb) {
  __shared__ float ls[256], lh[256];
  int t = threadIdx.x;
  ls[t] = sc[t]; lh[t] = sh[t];
  __syncthreads();
  int stride = gridDim.x * blockDim.x;
  for (int chunk = blockIdx.x * blockDim.x + t; chunk < NN * HD / 8; chunk += stride) {
    bf16x8 v = *((const bf16x8*)vin + chunk);
    float4 x0 = *((const float4*)x + 2 * (size_t)chunk);
    float4 x1 = *((const float4*)x + 2 * (size_t)chunk + 1);
    float xs[8] = {x0.x, x0.y, x0.z, x0.w, x1.x, x1.y, x1.z, x1.w};
    int c0 = (chunk & 31) * 8;
    bf16x8 o;
#pragma unroll
    for (int j = 0; j < 8; j++) {
      float f = bf2f(v[j]) * ls[c0 + j] + lh[c0 + j];
      f = f > 0.f ? f : 0.1f * f;
      o[j] = f2bf(xs[j] + 0.01f * f);
    }
    *((bf16x8*)outb + chunk) = o;
  }
}

// head: z = lrelu(hin @ Wl1 + bl1) [128 wide], out = z @ Wl3 + bl3 [10 wide]
__global__ __launch_bounds__(256) void k_head(const short* __restrict__ A,
                                              const short* __restrict__ BT,
                                              const float* __restrict__ bl1,
                                              const float* __restrict__ Wl3,
                                              const float* __restrict__ bl3,
                                              float* __restrict__ out, int M) {
  __shared__ char smem[128 * 140 * 2 + 1280 * 4];  // z(bf16, stride 140) + wl3(f32)
  short* zs  = (short*)smem;
  float* wl3 = (float*)(smem + 128 * 140 * 2);
  short* ldsA = (short*)smem;          // staging aliases z region (dead until after K loop)
  short* ldsB = (short*)smem + 4096;
  int tid = threadIdx.x;
  for (int i = tid; i < 1280; i += 256) wl3[i] = Wl3[i];
  int bm0 = blockIdx.x * 128;
  int lane = tid & 63, w = tid >> 6;
  int wm = w >> 1, wn = w & 1;
  int lr = lane & 15, lg = lane >> 4;
  f32x4 acc[4][4] = {};
  for (int kt = 0; kt < 256; kt += 32) {
#pragma unroll
    for (int c = 0; c < 2; c++) {
      int chunk = c * 256 + tid;
      int row = chunk >> 2;
      int kc = (chunk & 3) * 8;
      int rA = bm0 + row; if (rA > M - 1) rA = M - 1;
      *((bf16x8*)ldsA + chunk) = *(const bf16x8*)(A + (size_t)rA * 256 + kt + kc);
      *((bf16x8*)ldsB + chunk) = *(const bf16x8*)(BT + (size_t)row * 256 + kt + kc);
    }
    __syncthreads();
    bf16x8 af[4], bfr[4];
#pragma unroll
    for (int mi = 0; mi < 4; mi++) af[mi] = *((const bf16x8*)ldsA + ((wm * 64 + mi * 16 + lr) * 4 + lg));
#pragma unroll
    for (int ni = 0; ni < 4; ni++) bfr[ni] = *((const bf16x8*)ldsB + ((wn * 64 + ni * 16 + lr) * 4 + lg));
#pragma unroll
    for (int mi = 0; mi < 4; mi++)
#pragma unroll
      for (int ni = 0; ni < 4; ni++)
        acc[mi][ni] = __builtin_amdgcn_mfma_f32_16x16x32_bf16(af[mi], bfr[ni], acc[mi][ni], 0, 0, 0);
    __syncthreads();
  }
#pragma unroll
  for (int ni = 0; ni < 4; ni++) {
    int col = wn * 64 + ni * 16 + lr;
    float bv = bl1[col];
#pragma unroll
    for (int mi = 0; mi < 4; mi++) {
#pragma unroll
      for (int r = 0; r < 4; r++) {
        int rl = wm * 64 + mi * 16 + lg * 4 + r;
        float tv = acc[mi][ni][r] + bv;
        tv = tv > 0.f ? tv : 0.1f * tv;
        zs[rl * 140 + col] = f2bf(tv);
      }
    }
  }
  __syncthreads();
  int r = tid >> 1, ch = tid & 1;
  float av[5];
#pragma unroll
  for (int c = 0; c < 5; c++) av[c] = bl3[ch * 5 + c];
  for (int k = 0; k < 128; k++) {
    float zv = bf2f(zs[r * 140 + k]);
#pragma unroll
    for (int c = 0; c < 5; c++) av[c] += zv * wl3[k * 10 + ch * 5 + c];
  }
  int grow = bm0 + r;
  if (grow < M) {
#pragma unroll
    for (int c = 0; c < 5; c++) out[(size_t)grow * 10 + ch * 5 + c] = av[c];
  }
}

extern "C" void kernel_launch(void* const* d_in, const int* in_sizes, int n_in,
                              void* d_out, int out_size, void* d_ws, size_t ws_size,
                              hipStream_t stream) {
  const float* x   = (const float*)d_in[0];
  const int*   ew  = (const int*)d_in[1];
  const float* W1  = (const float*)d_in[2];
  const float* b1  = (const float*)d_in[3];
  const float* g1  = (const float*)d_in[4];
  const float* be1 = (const float*)d_in[5];
  const float* W2  = (const float*)d_in[6];
  const float* b2  = (const float*)d_in[7];
  const float* g4  = (const float*)d_in[8];
  const float* be4 = (const float*)d_in[9];
  const float* Wl1 = (const float*)d_in[10];
  const float* bl1 = (const float*)d_in[11];
  const float* Wl3 = (const float*)d_in[12];
  const float* bl3 = (const float*)d_in[13];
  float* out = (float*)d_out;

  char* ws = (char*)d_ws;
  const size_t OFF_OFF  = 0;          // (N+1) ints
  const size_t OFF_CUR  = 400128;
  const size_t OFF_DEG  = 800256;     // memset start
  const size_t OFF_STATS= 1200384;    // 4x256 f32 (sum1,ssq1,sum4,ssq4)
  const size_t OFF_BN   = 1204480;    // 4x256 f32 (sc1,sh1,sc4,sh4)
  const size_t OFF_FLAG = 1208576;
  const size_t OFF_BSUM = 1208704;
  const size_t OFF_W1T  = 1209216;
  const size_t OFF_W2T  = 1340288;
  const size_t OFF_WL1T = 1471360;
  const size_t OFF_CSR  = 1536896;
  const size_t OFF_BUFA = 7936896;
  const size_t OFF_BUFB = 59136896;
  if (ws_size < 110336896) return;

  int* off_  = (int*)(ws + OFF_OFF);
  int* cur_  = (int*)(ws + OFF_CUR);
  int* deg_  = (int*)(ws + OFF_DEG);
  float* sum1 = (float*)(ws + OFF_STATS);
  float* ssq1 = sum1 + 256;
  float* sum4 = sum1 + 512;
  float* ssq4 = sum1 + 768;
  float* sc1 = (float*)(ws + OFF_BN);
  float* sh1 = sc1 + 256;
  float* sc4 = sc1 + 512;
  float* sh4 = sc1 + 768;
  int* flag_ = (int*)(ws + OFF_FLAG);
  int* bsum_ = (int*)(ws + OFF_BSUM);
  short* W1T  = (short*)(ws + OFF_W1T);
  short* W2T  = (short*)(ws + OFF_W2T);
  short* Wl1T = (short*)(ws + OFF_WL1T);
  int* csr_   = (int*)(ws + OFF_CSR);
  short* bufA = (short*)(ws + OFF_BUFA);
  short* bufB = (short*)(ws + OFF_BUFB);

  hipMemsetAsync(ws + OFF_DEG, 0, OFF_BN - OFF_DEG, stream);  // deg + stats
  k_detect<<<1, 256, 0, stream>>>(ew, flag_);
  k_cvtW<<<640, 256, 0, stream>>>(W1, W2, Wl1, W1T, W2T, Wl1T);
  k_hist<<<2048, 256, 0, stream>>>(ew, flag_, deg_);
  k_scan1<<<98, 256, 0, stream>>>(deg_, bsum_);
  k_scan2<<<1, 128, 0, stream>>>(bsum_, 98);
  k_scan3<<<98, 256, 0, stream>>>(deg_, bsum_, off_, cur_);
  k_fill<<<2048, 256, 0, stream>>>(ew, flag_, cur_, csr_);
  k_agg<<<NN, 256, 0, stream>>>(x, off_, csr_, bufA);
  k_gemm<0><<<1564, 256, 0, stream>>>(bufA, W1T, b1, bufB, NN);
  k_colstats<<<391, 256, 0, stream>>>(bufB, sum1, ssq1, NN);
  k_bnprep<<<1, 256, 0, stream>>>(sum1, ssq1, g1, be1, sc1, sh1, NN);
  k_elem1<<<2048, 256, 0, stream>>>(bufB, sc1, sh1, bufA);
  k_gemm<1><<<1564, 256, 0, stream>>>(bufA, W2T, b2, bufB, NN);
  k_colstats<<<391, 256, 0, stream>>>(bufB, sum4, ssq4, NN);
  k_bnprep<<<1, 256, 0, stream>>>(sum4, ssq4, g4, be4, sc4, sh4, NN);
  k_elem2<<<2048, 256, 0, stream>>>(bufB, x, sc4, sh4, bufA);
  k_head<<<782, 256, 0, stream>>>(bufA, Wl1T, bl1, Wl3, bl3, out, NN);
}

// Round 2
// 545.792 us; speedup vs baseline: 1.6058x; 1.6058x over previous
//
#include <hip/hip_runtime.h>

constexpr int NN = 100000;   // nodes
constexpr int NE = 1600000;  // edges
constexpr int HD = 256;      // hidden

typedef __attribute__((ext_vector_type(4))) float  f32x4;
typedef __attribute__((ext_vector_type(8))) short  bf16x8;

__device__ __forceinline__ float bf2f(unsigned short u) {
  union { unsigned int i; float f; } c;
  c.i = ((unsigned int)u) << 16;
  return c.f;
}
__device__ __forceinline__ short f2bf(float f) {
  union { float f; unsigned int i; } c; c.f = f;
  unsigned int i = c.i + 0x7fffu + ((c.i >> 16) & 1u);
  return (short)(i >> 16);
}

// ---- edge dtype detection: int64 -> all odd 32-bit words (high words) are 0 ----
__global__ void k_detect(const int* __restrict__ ew, int* __restrict__ flag) {
  __shared__ int bad;
  if (threadIdx.x == 0) bad = 0;
  __syncthreads();
  int nz = 0;
  for (int i = threadIdx.x; i < 2048; i += 256) nz |= ew[2 * i + 1];
  if (nz) atomicOr(&bad, 1);
  __syncthreads();
  if (threadIdx.x == 0) *flag = (bad == 0) ? 1 : 0;
}

// ---- convert weights to bf16, transposed for LDS-friendly B staging ----
__global__ void k_cvtW(const float* __restrict__ W1, const float* __restrict__ W2,
                       const float* __restrict__ Wl1, short* __restrict__ W1T,
                       short* __restrict__ W2T, short* __restrict__ Wl1T) {
  int b = blockIdx.x, t = threadIdx.x;
  if (b < 256)       W1T[b * 256 + t]        = f2bf(W1[t * 256 + b]);
  else if (b < 512){ int n = b - 256; W2T[n * 256 + t]  = f2bf(W2[t * 256 + n]); }
  else             { int n = b - 512; Wl1T[n * 256 + t] = f2bf(Wl1[t * 128 + n]); }
}

// ---- x (f32) -> xb (bf16), streaming ----
__global__ void k_cvtX(const float* __restrict__ x, short* __restrict__ xb) {
  int c = blockIdx.x * 256 + threadIdx.x;  // 3.2M chunks of 8, grid exact
  float4 a = ((const float4*)x)[2 * (size_t)c];
  float4 b = ((const float4*)x)[2 * (size_t)c + 1];
  bf16x8 o;
  o[0] = f2bf(a.x); o[1] = f2bf(a.y); o[2] = f2bf(a.z); o[3] = f2bf(a.w);
  o[4] = f2bf(b.x); o[5] = f2bf(b.y); o[6] = f2bf(b.z); o[7] = f2bf(b.w);
  ((bf16x8*)xb)[c] = o;
}

__global__ void k_hist(const int* __restrict__ ew, const int* __restrict__ flag,
                       int* __restrict__ deg) {
  int m64 = *flag;
  int stride = gridDim.x * blockDim.x;
  for (int e = blockIdx.x * blockDim.x + threadIdx.x; e < NE; e += stride) {
    int d = m64 ? ew[2 * (NE + e)] : ew[NE + e];
    atomicAdd(&deg[d], 1);
  }
}

__global__ void k_scan1(const int* __restrict__ deg, int* __restrict__ bsum) {
  __shared__ int s[256];
  int t = threadIdx.x;
  int base = blockIdx.x * 1024 + t * 4;
  int v = 0;
#pragma unroll
  for (int i = 0; i < 4; i++) { int idx = base + i; if (idx < NN) v += deg[idx]; }
  s[t] = v; __syncthreads();
  for (int o = 128; o > 0; o >>= 1) { if (t < o) s[t] += s[t + o]; __syncthreads(); }
  if (t == 0) bsum[blockIdx.x] = s[0];
}

__global__ void k_scan2(int* __restrict__ bsum, int nb) {
  __shared__ int s[128];
  int t = threadIdx.x;
  int v = (t < nb) ? bsum[t] : 0;
  s[t] = v; __syncthreads();
  for (int o = 1; o < 128; o <<= 1) {
    int u = (t >= o) ? s[t - o] : 0;
    __syncthreads();
    s[t] += u;
    __syncthreads();
  }
  if (t < nb) bsum[t] = s[t] - v;  // exclusive
}

__global__ void k_scan3(const int* __restrict__ deg, const int* __restrict__ bsum,
                        int* __restrict__ off_, int* __restrict__ cur_) {
  __shared__ int s[256];
  int t = threadIdx.x;
  int base = blockIdx.x * 1024 + t * 4;
  int v[4]; int sum = 0;
#pragma unroll
  for (int i = 0; i < 4; i++) { int idx = base + i; v[i] = (idx < NN) ? deg[idx] : 0; sum += v[i]; }
  s[t] = sum; __syncthreads();
  for (int o = 1; o < 256; o <<= 1) {
    int u = (t >= o) ? s[t - o] : 0;
    __syncthreads();
    s[t] += u;
    __syncthreads();
  }
  int run = s[t] - sum + bsum[blockIdx.x];
#pragma unroll
  for (int i = 0; i < 4; i++) {
    int idx = base + i;
    if (idx < NN) { off_[idx] = run; cur_[idx] = run; run += v[i]; }
    else if (idx == NN) { off_[idx] = run; }
  }
}

__global__ void k_fill(const int* __restrict__ ew, const int* __restrict__ flag,
                       int* __restrict__ cur_, int* __restrict__ csr) {
  int m64 = *flag;
  int stride = gridDim.x * blockDim.x;
  for (int e = blockIdx.x * blockDim.x + threadIdx.x; e < NE; e += stride) {
    int d = m64 ? ew[2 * (NE + e)] : ew[NE + e];
    int s = m64 ? ew[2 * e] : ew[e];
    int pos = atomicAdd(&cur_[d], 1);
    csr[pos] = s;
  }
}

// one WAVE per node, lane owns 4 columns (ushort4 = 8B), 8-deep load ILP
__global__ __launch_bounds__(256) void k_agg2(const short* __restrict__ xb,
                                              const int* __restrict__ off_,
                                              const int* __restrict__ csr,
                                              short* __restrict__ h0) {
  int node = blockIdx.x * 4 + (threadIdx.x >> 6);  // grid 25000 exact
  int lane = threadIdx.x & 63;
  const ushort* xu = (const ushort*)xb;
  size_t coff = (size_t)lane * 4;
  int s0 = off_[node], s1 = off_[node + 1];
  ushort4 sv = *(const ushort4*)(xu + (size_t)node * 256 + coff);
  float a0 = bf2f(sv.x), a1 = bf2f(sv.y), a2 = bf2f(sv.z), a3 = bf2f(sv.w);
  int j = s0;
  while (j + 8 <= s1) {
    int idx[8];
#pragma unroll
    for (int u = 0; u < 8; u++) idx[u] = csr[j + u];
    ushort4 v[8];
#pragma unroll
    for (int u = 0; u < 8; u++) v[u] = *(const ushort4*)(xu + (size_t)idx[u] * 256 + coff);
#pragma unroll
    for (int u = 0; u < 8; u++) {
      a0 += bf2f(v[u].x); a1 += bf2f(v[u].y);
      a2 += bf2f(v[u].z); a3 += bf2f(v[u].w);
    }
    j += 8;
  }
  if (j + 4 <= s1) {
    int idx[4];
#pragma unroll
    for (int u = 0; u < 4; u++) idx[u] = csr[j + u];
    ushort4 v[4];
#pragma unroll
    for (int u = 0; u < 4; u++) v[u] = *(const ushort4*)(xu + (size_t)idx[u] * 256 + coff);
#pragma unroll
    for (int u = 0; u < 4; u++) {
      a0 += bf2f(v[u].x); a1 += bf2f(v[u].y);
      a2 += bf2f(v[u].z); a3 += bf2f(v[u].w);
    }
    j += 4;
  }
  for (; j < s1; j++) {
    int s = csr[j];
    ushort4 v = *(const ushort4*)(xu + (size_t)s * 256 + coff);
    a0 += bf2f(v.x); a1 += bf2f(v.y); a2 += bf2f(v.z); a3 += bf2f(v.w);
  }
  ushort4 o;
  o.x = (ushort)f2bf(a0); o.y = (ushort)f2bf(a1);
  o.z = (ushort)f2bf(a2); o.w = (ushort)f2bf(a3);
  *(ushort4*)((ushort*)h0 + (size_t)node * 256 + coff) = o;
}

// C[M x 256] = act(A' * B + bias); A' = optional bn+relu transform of A (fused elem1)
// STATS: per-column sum/sumsq of the (activated, f32) output via shfl+LDS+atomics
template <int ACT, int TIN, int STATS>
__global__ __launch_bounds__(256) void k_gemm(const short* __restrict__ A,
                                              const short* __restrict__ BT,
                                              const float* __restrict__ bias,
                                              short* __restrict__ C, int M,
                                              const float* __restrict__ tsc,
                                              const float* __restrict__ tsh,
                                              float* __restrict__ gsum,
                                              float* __restrict__ gssq) {
  __shared__ short ldsA[4096];  // [128][32] bf16
  __shared__ short ldsB[4096];  // [128 cols][32 k] bf16
  __shared__ float lsc[256], lsh[256];
  __shared__ float lsum[128], lssq[128];
  int tid = threadIdx.x;
  if (TIN) { lsc[tid] = tsc[tid]; lsh[tid] = tsh[tid]; }
  if (STATS && tid < 128) { lsum[tid] = 0.f; lssq[tid] = 0.f; }
  __syncthreads();
  int bm = blockIdx.x >> 1, bn = blockIdx.x & 1;
  int bm0 = bm * 128, bn0 = bn * 128;
  int lane = tid & 63, w = tid >> 6;
  int wm = w >> 1, wn = w & 1;
  int lr = lane & 15, lg = lane >> 4;
  f32x4 acc[4][4] = {};
  for (int kt = 0; kt < 256; kt += 32) {
#pragma unroll
    for (int c = 0; c < 2; c++) {
      int chunk = c * 256 + tid;
      int row = chunk >> 2;
      int kc = (chunk & 3) * 8;
      int rA = bm0 + row; if (rA > M - 1) rA = M - 1;
      bf16x8 va = *(const bf16x8*)(A + (size_t)rA * 256 + kt + kc);
      if (TIN) {
        bf16x8 tt;
#pragma unroll
        for (int jj = 0; jj < 8; jj++) {
          float f = bf2f((unsigned short)va[jj]) * lsc[kt + kc + jj] + lsh[kt + kc + jj];
          f = fmaxf(f, 0.f);
          tt[jj] = f2bf(f);
        }
        va = tt;
      }
      *((bf16x8*)ldsA + chunk) = va;
      *((bf16x8*)ldsB + chunk) = *(const bf16x8*)(BT + (size_t)(bn0 + row) * 256 + kt + kc);
    }
    __syncthreads();
    bf16x8 af[4], bfr[4];
#pragma unroll
    for (int mi = 0; mi < 4; mi++) af[mi] = *((const bf16x8*)ldsA + ((wm * 64 + mi * 16 + lr) * 4 + lg));
#pragma unroll
    for (int ni = 0; ni < 4; ni++) bfr[ni] = *((const bf16x8*)ldsB + ((wn * 64 + ni * 16 + lr) * 4 + lg));
#pragma unroll
    for (int mi = 0; mi < 4; mi++)
#pragma unroll
      for (int ni = 0; ni < 4; ni++)
        acc[mi][ni] = __builtin_amdgcn_mfma_f32_16x16x32_bf16(af[mi], bfr[ni], acc[mi][ni], 0, 0, 0);
    __syncthreads();
  }
#pragma unroll
  for (int ni = 0; ni < 4; ni++) {
    int col = bn0 + wn * 64 + ni * 16 + lr;
    float bv = bias[col];
    float ps = 0.f, pq = 0.f;
#pragma unroll
    for (int mi = 0; mi < 4; mi++) {
#pragma unroll
      for (int r = 0; r < 4; r++) {
        int row = bm0 + wm * 64 + mi * 16 + lg * 4 + r;
        float tv = acc[mi][ni][r] + bv;
        if (ACT == 1) tv = tv > 0.f ? tv : 0.01f * tv;  // lrelu(lrelu(t,0.1),0.1)
        if (row < M) {
          if (STATS) { ps += tv; pq += tv * tv; }
          C[(size_t)row * 256 + col] = f2bf(tv);
        }
      }
    }
    if (STATS) {
      ps += __shfl_xor(ps, 16); pq += __shfl_xor(pq, 16);
      ps += __shfl_xor(ps, 32); pq += __shfl_xor(pq, 32);
      if (lane < 16) {
        atomicAdd(&lsum[wn * 64 + ni * 16 + lane], ps);
        atomicAdd(&lssq[wn * 64 + ni * 16 + lane], pq);
      }
    }
  }
  if (STATS) {
    __syncthreads();
    if (tid < 128) {
      atomicAdd(&gsum[bn0 + tid], lsum[tid]);
      atomicAdd(&gssq[bn0 + tid], lssq[tid]);
    }
  }
}

__global__ void k_bnprep(const float* __restrict__ sum, const float* __restrict__ ssq,
                         const float* __restrict__ g, const float* __restrict__ be,
                         float* __restrict__ scale, float* __restrict__ shift, int M) {
  int c = threadIdx.x;
  float mu = sum[c] / (float)M;
  float var = ssq[c] / (float)M - mu * mu;
  float rs = rsqrtf(var + 1e-5f);
  float sc = g[c] * rs;
  scale[c] = sc;
  shift[c] = be[c] - mu * sc;
}

// head with fused elem2 on A-staging:
//   A' = bf16( x + 0.01 * lrelu(bn4(V)) );  z = lrelu(A' @ Wl1 + bl1);  out = z @ Wl3 + bl3
__global__ __launch_bounds__(256) void k_head(const short* __restrict__ V,
                                              const float* __restrict__ x,
                                              const short* __restrict__ BT,
                                              const float* __restrict__ bl1,
                                              const float* __restrict__ Wl3,
                                              const float* __restrict__ bl3,
                                              const float* __restrict__ tsc,
                                              const float* __restrict__ tsh,
                                              float* __restrict__ out, int M) {
  __shared__ char smem[128 * 140 * 2 + 1280 * 4];  // z(bf16, stride 140) + wl3(f32)
  __shared__ float lsc[256], lsh[256];
  short* zs  = (short*)smem;
  float* wl3 = (float*)(smem + 128 * 140 * 2);
  short* ldsA = (short*)smem;          // staging aliases z region (dead until after K loop)
  short* ldsB = (short*)smem + 4096;
  int tid = threadIdx.x;
  for (int i = tid; i < 1280; i += 256) wl3[i] = Wl3[i];
  lsc[tid] = tsc[tid]; lsh[tid] = tsh[tid];
  __syncthreads();
  int bm0 = blockIdx.x * 128;
  int lane = tid & 63, w = tid >> 6;
  int wm = w >> 1, wn = w & 1;
  int lr = lane & 15, lg = lane >> 4;
  f32x4 acc[4][4] = {};
  for (int kt = 0; kt < 256; kt += 32) {
#pragma unroll
    for (int c = 0; c < 2; c++) {
      int chunk = c * 256 + tid;
      int row = chunk >> 2;
      int kc = (chunk & 3) * 8;
      int rA = bm0 + row; if (rA > M - 1) rA = M - 1;
      bf16x8 va = *(const bf16x8*)(V + (size_t)rA * 256 + kt + kc);
      float4 x0 = *(const float4*)(x + (size_t)rA * 256 + kt + kc);
      float4 x1 = *(const float4*)(x + (size_t)rA * 256 + kt + kc + 4);
      float xs[8] = {x0.x, x0.y, x0.z, x0.w, x1.x, x1.y, x1.z, x1.w};
      bf16x8 tt;
#pragma unroll
      for (int jj = 0; jj < 8; jj++) {
        float f = bf2f((unsigned short)va[jj]) * lsc[kt + kc + jj] + lsh[kt + kc + jj];
        f = f > 0.f ? f : 0.1f * f;
        tt[jj] = f2bf(xs[jj] + 0.01f * f);
      }
      *((bf16x8*)ldsA + chunk) = tt;
      *((bf16x8*)ldsB + chunk) = *(const bf16x8*)(BT + (size_t)row * 256 + kt + kc);
    }
    __syncthreads();
    bf16x8 af[4], bfr[4];
#pragma unroll
    for (int mi = 0; mi < 4; mi++) af[mi] = *((const bf16x8*)ldsA + ((wm * 64 + mi * 16 + lr) * 4 + lg));
#pragma unroll
    for (int ni = 0; ni < 4; ni++) bfr[ni] = *((const bf16x8*)ldsB + ((wn * 64 + ni * 16 + lr) * 4 + lg));
#pragma unroll
    for (int mi = 0; mi < 4; mi++)
#pragma unroll
      for (int ni = 0; ni < 4; ni++)
        acc[mi][ni] = __builtin_amdgcn_mfma_f32_16x16x32_bf16(af[mi], bfr[ni], acc[mi][ni], 0, 0, 0);
    __syncthreads();
  }
#pragma unroll
  for (int ni = 0; ni < 4; ni++) {
    int col = wn * 64 + ni * 16 + lr;
    float bv = bl1[col];
#pragma unroll
    for (int mi = 0; mi < 4; mi++) {
#pragma unroll
      for (int r = 0; r < 4; r++) {
        int rl = wm * 64 + mi * 16 + lg * 4 + r;
        float tv = acc[mi][ni][r] + bv;
        tv = tv > 0.f ? tv : 0.1f * tv;
        zs[rl * 140 + col] = f2bf(tv);
      }
    }
  }
  __syncthreads();
  int r = tid >> 1, ch = tid & 1;
  float av[5];
#pragma unroll
  for (int c = 0; c < 5; c++) av[c] = bl3[ch * 5 + c];
  for (int k = 0; k < 128; k++) {
    float zv = bf2f((unsigned short)zs[r * 140 + k]);
#pragma unroll
    for (int c = 0; c < 5; c++) av[c] += zv * wl3[k * 10 + ch * 5 + c];
  }
  int grow = bm0 + r;
  if (grow < M) {
#pragma unroll
    for (int c = 0; c < 5; c++) out[(size_t)grow * 10 + ch * 5 + c] = av[c];
  }
}

extern "C" void kernel_launch(void* const* d_in, const int* in_sizes, int n_in,
                              void* d_out, int out_size, void* d_ws, size_t ws_size,
                              hipStream_t stream) {
  const float* x   = (const float*)d_in[0];
  const int*   ew  = (const int*)d_in[1];
  const float* W1  = (const float*)d_in[2];
  const float* b1  = (const float*)d_in[3];
  const float* g1  = (const float*)d_in[4];
  const float* be1 = (const float*)d_in[5];
  const float* W2  = (const float*)d_in[6];
  const float* b2  = (const float*)d_in[7];
  const float* g4  = (const float*)d_in[8];
  const float* be4 = (const float*)d_in[9];
  const float* Wl1 = (const float*)d_in[10];
  const float* bl1 = (const float*)d_in[11];
  const float* Wl3 = (const float*)d_in[12];
  const float* bl3 = (const float*)d_in[13];
  float* out = (float*)d_out;

  char* ws = (char*)d_ws;
  const size_t OFF_OFF  = 0;          // (N+1) ints
  const size_t OFF_CUR  = 400128;
  const size_t OFF_DEG  = 800256;     // memset start
  const size_t OFF_STATS= 1200384;    // 4x256 f32 (sum1,ssq1,sum4,ssq4)
  const size_t OFF_BN   = 1204480;    // 4x256 f32 (sc1,sh1,sc4,sh4)
  const size_t OFF_FLAG = 1208576;
  const size_t OFF_BSUM = 1208704;
  const size_t OFF_W1T  = 1209216;
  const size_t OFF_W2T  = 1340288;
  const size_t OFF_WL1T = 1471360;
  const size_t OFF_CSR  = 1536896;
  const size_t OFF_BUFA = 7936896;
  const size_t OFF_BUFB = 59136896;   // xb aliases bufB (xb dead before GEMM1 writes bufB)
  if (ws_size < 110336896) return;

  int* off_  = (int*)(ws + OFF_OFF);
  int* cur_  = (int*)(ws + OFF_CUR);
  int* deg_  = (int*)(ws + OFF_DEG);
  float* sum1 = (float*)(ws + OFF_STATS);
  float* ssq1 = sum1 + 256;
  float* sum4 = sum1 + 512;
  float* ssq4 = sum1 + 768;
  float* sc1 = (float*)(ws + OFF_BN);
  float* sh1 = sc1 + 256;
  float* sc4 = sc1 + 512;
  float* sh4 = sc1 + 768;
  int* flag_ = (int*)(ws + OFF_FLAG);
  int* bsum_ = (int*)(ws + OFF_BSUM);
  short* W1T  = (short*)(ws + OFF_W1T);
  short* W2T  = (short*)(ws + OFF_W2T);
  short* Wl1T = (short*)(ws + OFF_WL1T);
  int* csr_   = (int*)(ws + OFF_CSR);
  short* bufA = (short*)(ws + OFF_BUFA);
  short* bufB = (short*)(ws + OFF_BUFB);
  short* xb   = bufB;  // alias

  hipMemsetAsync(ws + OFF_DEG, 0, OFF_BN - OFF_DEG, stream);  // deg + stats
  k_detect<<<1, 256, 0, stream>>>(ew, flag_);
  k_cvtW<<<640, 256, 0, stream>>>(W1, W2, Wl1, W1T, W2T, Wl1T);
  k_cvtX<<<12500, 256, 0, stream>>>(x, xb);
  k_hist<<<2048, 256, 0, stream>>>(ew, flag_, deg_);
  k_scan1<<<98, 256, 0, stream>>>(deg_, bsum_);
  k_scan2<<<1, 128, 0, stream>>>(bsum_, 98);
  k_scan3<<<98, 256, 0, stream>>>(deg_, bsum_, off_, cur_);
  k_fill<<<2048, 256, 0, stream>>>(ew, flag_, cur_, csr_);
  k_agg2<<<25000, 256, 0, stream>>>(xb, off_, csr_, bufA);
  k_gemm<0, 0, 1><<<1564, 256, 0, stream>>>(bufA, W1T, b1, bufB, NN,
                                            nullptr, nullptr, sum1, ssq1);
  k_bnprep<<<1, 256, 0, stream>>>(sum1, ssq1, g1, be1, sc1, sh1, NN);
  k_gemm<1, 1, 1><<<1564, 256, 0, stream>>>(bufB, W2T, b2, bufA, NN,
                                            sc1, sh1, sum4, ssq4);
  k_bnprep<<<1, 256, 0, stream>>>(sum4, ssq4, g4, be4, sc4, sh4, NN);
  k_head<<<782, 256, 0, stream>>>(bufA, x, Wl1T, bl1, Wl3, bl3, sc4, sh4, out, NN);
}

// Round 3
// 382.280 us; speedup vs baseline: 2.2927x; 1.4277x over previous
//
#include <hip/hip_runtime.h>

constexpr int NN = 100000;   // nodes
constexpr int NE = 1600000;  // edges
constexpr int HD = 256;      // hidden
constexpr int NBUCK = 782;   // ceil(NN/128)
constexpr int CGRID = 98;    // count/scatter blocks (98*16384 >= NE)

typedef __attribute__((ext_vector_type(4))) float  f32x4;
typedef __attribute__((ext_vector_type(8))) short  bf16x8;

__device__ __forceinline__ float bf2f(unsigned short u) {
  union { unsigned int i; float f; } c;
  c.i = ((unsigned int)u) << 16;
  return c.f;
}
__device__ __forceinline__ short f2bf(float f) {
  union { float f; unsigned int i; } c; c.f = f;
  unsigned int i = c.i + 0x7fffu + ((c.i >> 16) & 1u);
  return (short)(i >> 16);
}

// ---- edge dtype detection: int64 -> all odd 32-bit words (high words) are 0 ----
__global__ void k_detect(const int* __restrict__ ew, int* __restrict__ flag) {
  __shared__ int bad;
  if (threadIdx.x == 0) bad = 0;
  __syncthreads();
  int nz = 0;
  for (int i = threadIdx.x; i < 2048; i += 256) nz |= ew[2 * i + 1];
  if (nz) atomicOr(&bad, 1);
  __syncthreads();
  if (threadIdx.x == 0) *flag = (bad == 0) ? 1 : 0;
}

// ---- convert weights to bf16, transposed for LDS-friendly B staging ----
__global__ void k_cvtW(const float* __restrict__ W1, const float* __restrict__ W2,
                       const float* __restrict__ Wl1, short* __restrict__ W1T,
                       short* __restrict__ W2T, short* __restrict__ Wl1T) {
  int b = blockIdx.x, t = threadIdx.x;
  if (b < 256)       W1T[b * 256 + t]        = f2bf(W1[t * 256 + b]);
  else if (b < 512){ int n = b - 256; W2T[n * 256 + t]  = f2bf(W2[t * 256 + n]); }
  else             { int n = b - 512; Wl1T[n * 256 + t] = f2bf(Wl1[t * 128 + n]); }
}

// ---- x (f32) -> xb (bf16), streaming ----
__global__ void k_cvtX(const float* __restrict__ x, short* __restrict__ xb) {
  int c = blockIdx.x * 256 + threadIdx.x;  // 3.2M chunks of 8, grid exact
  float4 a = ((const float4*)x)[2 * (size_t)c];
  float4 b = ((const float4*)x)[2 * (size_t)c + 1];
  bf16x8 o;
  o[0] = f2bf(a.x); o[1] = f2bf(a.y); o[2] = f2bf(a.z); o[3] = f2bf(a.w);
  o[4] = f2bf(b.x); o[5] = f2bf(b.y); o[6] = f2bf(b.z); o[7] = f2bf(b.w);
  ((bf16x8*)xb)[c] = o;
}

// ---- pass 1: per-block bucket histogram (no global atomics) ----
__global__ __launch_bounds__(1024) void k_count(const int* __restrict__ ew,
                                                const int* __restrict__ flag,
                                                int* __restrict__ cntmat) {
  __shared__ int lcnt[NBUCK];
  int m64 = *flag;
  int t = threadIdx.x;
  for (int i = t; i < NBUCK; i += 1024) lcnt[i] = 0;
  __syncthreads();
  int base = blockIdx.x * 16384;
#pragma unroll
  for (int u = 0; u < 16; u++) {
    int e = base + u * 1024 + t;
    if (e < NE) {
      int d = m64 ? ew[2 * (NE + e)] : ew[NE + e];
      atomicAdd(&lcnt[d >> 7], 1);
    }
  }
  __syncthreads();
  for (int i = t; i < NBUCK; i += 1024) cntmat[blockIdx.x * NBUCK + i] = lcnt[i];
}

// ---- pass 2: column scan -> per-(block,bucket) bases + bucket bases ----
__global__ __launch_bounds__(1024) void k_colscan(int* __restrict__ cntmat,
                                                  int* __restrict__ bases,
                                                  int* __restrict__ off_) {
  __shared__ int tot[1024];
  int t = threadIdx.x;
  int sum = 0;
  if (t < NBUCK) {
    for (int g = 0; g < CGRID; g++) sum += cntmat[g * NBUCK + t];
    tot[t] = sum;
  }
  __syncthreads();
  int v = (t < NBUCK) ? sum : 0;
  for (int o = 1; o < 1024; o <<= 1) {
    int u = (t >= o && t < NBUCK) ? tot[t - o] : 0;
    __syncthreads();
    if (t < NBUCK) tot[t] += u;
    __syncthreads();
  }
  if (t < NBUCK) {
    int b = tot[t] - v;  // exclusive
    bases[t] = b;
    int run = b;
    for (int g = 0; g < CGRID; g++) {
      int c = cntmat[g * NBUCK + t];
      cntmat[g * NBUCK + t] = run;
      run += c;
    }
  }
  if (t == NBUCK) bases[NBUCK] = NE;
  if (t == NBUCK + 1) off_[NN] = NE;
}

// ---- pass 3: dense bucketed scatter of packed (src | ld<<17) ----
__global__ __launch_bounds__(1024) void k_scatter(const int* __restrict__ ew,
                                                  const int* __restrict__ flag,
                                                  const int* __restrict__ cntmat,
                                                  int* __restrict__ pairs) {
  __shared__ int lcur[NBUCK];
  int m64 = *flag;
  int t = threadIdx.x;
  for (int i = t; i < NBUCK; i += 1024) lcur[i] = cntmat[blockIdx.x * NBUCK + i];
  __syncthreads();
  int base = blockIdx.x * 16384;
#pragma unroll
  for (int u = 0; u < 16; u++) {
    int e = base + u * 1024 + t;
    if (e < NE) {
      int d = m64 ? ew[2 * (NE + e)] : ew[NE + e];
      int s = m64 ? ew[2 * e] : ew[e];
      int slot = atomicAdd(&lcur[d >> 7], 1);
      pairs[slot] = s | ((d & 127) << 17);
    }
  }
}

// ---- pass 4: per-bucket counting sort in LDS -> off_ + csr ----
__global__ __launch_bounds__(256) void k_bsort(const int* __restrict__ pairs,
                                               const int* __restrict__ bases,
                                               int* __restrict__ off_,
                                               int* __restrict__ csr) {
  __shared__ int lcnt[128], lofs[128], lcur[128];
  int b = blockIdx.x, t = threadIdx.x;
  int s0 = bases[b], s1 = bases[b + 1];
  if (t < 128) lcnt[t] = 0;
  __syncthreads();
  for (int j = s0 + t; j < s1; j += 256) atomicAdd(&lcnt[(pairs[j] >> 17) & 127], 1);
  __syncthreads();
  int v = (t < 128) ? lcnt[t] : 0;
  if (t < 128) lofs[t] = v;
  __syncthreads();
  for (int o = 1; o < 128; o <<= 1) {
    int u = (t >= o && t < 128) ? lofs[t - o] : 0;
    __syncthreads();
    if (t < 128) lofs[t] += u;
    __syncthreads();
  }
  if (t < 128) {
    int ex = lofs[t] - v;  // exclusive
    lcur[t] = ex;
    int node = b * 128 + t;
    if (node < NN) off_[node] = s0 + ex;
  }
  __syncthreads();
  for (int j = s0 + t; j < s1; j += 256) {
    int p = pairs[j];
    int slot = atomicAdd(&lcur[(p >> 17) & 127], 1);
    csr[s0 + slot] = p & 0x1FFFF;
  }
}

// one WAVE per node, lane owns 4 columns (ushort4 = 8B), 8-deep load ILP
__global__ __launch_bounds__(256) void k_agg2(const short* __restrict__ xb,
                                              const int* __restrict__ off_,
                                              const int* __restrict__ csr,
                                              short* __restrict__ h0) {
  int node = blockIdx.x * 4 + (threadIdx.x >> 6);  // grid 25000 exact
  int lane = threadIdx.x & 63;
  const ushort* xu = (const ushort*)xb;
  size_t coff = (size_t)lane * 4;
  int s0 = off_[node], s1 = off_[node + 1];
  ushort4 sv = *(const ushort4*)(xu + (size_t)node * 256 + coff);
  float a0 = bf2f(sv.x), a1 = bf2f(sv.y), a2 = bf2f(sv.z), a3 = bf2f(sv.w);
  int j = s0;
  while (j + 8 <= s1) {
    int idx[8];
#pragma unroll
    for (int u = 0; u < 8; u++) idx[u] = csr[j + u];
    ushort4 v[8];
#pragma unroll
    for (int u = 0; u < 8; u++) v[u] = *(const ushort4*)(xu + (size_t)idx[u] * 256 + coff);
#pragma unroll
    for (int u = 0; u < 8; u++) {
      a0 += bf2f(v[u].x); a1 += bf2f(v[u].y);
      a2 += bf2f(v[u].z); a3 += bf2f(v[u].w);
    }
    j += 8;
  }
  if (j + 4 <= s1) {
    int idx[4];
#pragma unroll
    for (int u = 0; u < 4; u++) idx[u] = csr[j + u];
    ushort4 v[4];
#pragma unroll
    for (int u = 0; u < 4; u++) v[u] = *(const ushort4*)(xu + (size_t)idx[u] * 256 + coff);
#pragma unroll
    for (int u = 0; u < 4; u++) {
      a0 += bf2f(v[u].x); a1 += bf2f(v[u].y);
      a2 += bf2f(v[u].z); a3 += bf2f(v[u].w);
    }
    j += 4;
  }
  for (; j < s1; j++) {
    int s = csr[j];
    ushort4 v = *(const ushort4*)(xu + (size_t)s * 256 + coff);
    a0 += bf2f(v.x); a1 += bf2f(v.y); a2 += bf2f(v.z); a3 += bf2f(v.w);
  }
  ushort4 o;
  o.x = (ushort)f2bf(a0); o.y = (ushort)f2bf(a1);
  o.z = (ushort)f2bf(a2); o.w = (ushort)f2bf(a3);
  *(ushort4*)((ushort*)h0 + (size_t)node * 256 + coff) = o;
}

// C[M x 256] = act(A' * B + bias); A' = optional bn+relu transform of A (fused elem1)
// STATS: per-column sum/sumsq of the (activated, f32) output via shfl+LDS+atomics
template <int ACT, int TIN, int STATS>
__global__ __launch_bounds__(256) void k_gemm(const short* __restrict__ A,
                                              const short* __restrict__ BT,
                                              const float* __restrict__ bias,
                                              short* __restrict__ C, int M,
                                              const float* __restrict__ tsc,
                                              const float* __restrict__ tsh,
                                              float* __restrict__ gsum,
                                              float* __restrict__ gssq) {
  __shared__ short ldsA[4096];  // [128][32] bf16
  __shared__ short ldsB[4096];  // [128 cols][32 k] bf16
  __shared__ float lsc[256], lsh[256];
  __shared__ float lsum[128], lssq[128];
  int tid = threadIdx.x;
  if (TIN) { lsc[tid] = tsc[tid]; lsh[tid] = tsh[tid]; }
  if (STATS && tid < 128) { lsum[tid] = 0.f; lssq[tid] = 0.f; }
  __syncthreads();
  int bm = blockIdx.x >> 1, bn = blockIdx.x & 1;
  int bm0 = bm * 128, bn0 = bn * 128;
  int lane = tid & 63, w = tid >> 6;
  int wm = w >> 1, wn = w & 1;
  int lr = lane & 15, lg = lane >> 4;
  f32x4 acc[4][4] = {};
  for (int kt = 0; kt < 256; kt += 32) {
#pragma unroll
    for (int c = 0; c < 2; c++) {
      int chunk = c * 256 + tid;
      int row = chunk >> 2;
      int kc = (chunk & 3) * 8;
      int rA = bm0 + row; if (rA > M - 1) rA = M - 1;
      bf16x8 va = *(const bf16x8*)(A + (size_t)rA * 256 + kt + kc);
      if (TIN) {
        bf16x8 tt;
#pragma unroll
        for (int jj = 0; jj < 8; jj++) {
          float f = bf2f((unsigned short)va[jj]) * lsc[kt + kc + jj] + lsh[kt + kc + jj];
          f = fmaxf(f, 0.f);
          tt[jj] = f2bf(f);
        }
        va = tt;
      }
      *((bf16x8*)ldsA + chunk) = va;
      *((bf16x8*)ldsB + chunk) = *(const bf16x8*)(BT + (size_t)(bn0 + row) * 256 + kt + kc);
    }
    __syncthreads();
    bf16x8 af[4], bfr[4];
#pragma unroll
    for (int mi = 0; mi < 4; mi++) af[mi] = *((const bf16x8*)ldsA + ((wm * 64 + mi * 16 + lr) * 4 + lg));
#pragma unroll
    for (int ni = 0; ni < 4; ni++) bfr[ni] = *((const bf16x8*)ldsB + ((wn * 64 + ni * 16 + lr) * 4 + lg));
#pragma unroll
    for (int mi = 0; mi < 4; mi++)
#pragma unroll
      for (int ni = 0; ni < 4; ni++)
        acc[mi][ni] = __builtin_amdgcn_mfma_f32_16x16x32_bf16(af[mi], bfr[ni], acc[mi][ni], 0, 0, 0);
    __syncthreads();
  }
#pragma unroll
  for (int ni = 0; ni < 4; ni++) {
    int col = bn0 + wn * 64 + ni * 16 + lr;
    float bv = bias[col];
    float ps = 0.f, pq = 0.f;
#pragma unroll
    for (int mi = 0; mi < 4; mi++) {
#pragma unroll
      for (int r = 0; r < 4; r++) {
        int row = bm0 + wm * 64 + mi * 16 + lg * 4 + r;
        float tv = acc[mi][ni][r] + bv;
        if (ACT == 1) tv = tv > 0.f ? tv : 0.01f * tv;  // lrelu(lrelu(t,0.1),0.1)
        if (row < M) {
          if (STATS) { ps += tv; pq += tv * tv; }
          C[(size_t)row * 256 + col] = f2bf(tv);
        }
      }
    }
    if (STATS) {
      ps += __shfl_xor(ps, 16); pq += __shfl_xor(pq, 16);
      ps += __shfl_xor(ps, 32); pq += __shfl_xor(pq, 32);
      if (lane < 16) {
        atomicAdd(&lsum[wn * 64 + ni * 16 + lane], ps);
        atomicAdd(&lssq[wn * 64 + ni * 16 + lane], pq);
      }
    }
  }
  if (STATS) {
    __syncthreads();
    if (tid < 128) {
      atomicAdd(&gsum[bn0 + tid], lsum[tid]);
      atomicAdd(&gssq[bn0 + tid], lssq[tid]);
    }
  }
}

__global__ void k_bnprep(const float* __restrict__ sum, const float* __restrict__ ssq,
                         const float* __restrict__ g, const float* __restrict__ be,
                         float* __restrict__ scale, float* __restrict__ shift, int M) {
  int c = threadIdx.x;
  float mu = sum[c] / (float)M;
  float var = ssq[c] / (float)M - mu * mu;
  float rs = rsqrtf(var + 1e-5f);
  float sc = g[c] * rs;
  scale[c] = sc;
  shift[c] = be[c] - mu * sc;
}

// head with fused elem2 on A-staging:
//   A' = bf16( x + 0.01 * lrelu(bn4(V)) );  z = lrelu(A' @ Wl1 + bl1);  out = z @ Wl3 + bl3
__global__ __launch_bounds__(256) void k_head(const short* __restrict__ V,
                                              const float* __restrict__ x,
                                              const short* __restrict__ BT,
                                              const float* __restrict__ bl1,
                                              const float* __restrict__ Wl3,
                                              const float* __restrict__ bl3,
                                              const float* __restrict__ tsc,
                                              const float* __restrict__ tsh,
                                              float* __restrict__ out, int M) {
  __shared__ char smem[128 * 140 * 2 + 1280 * 4];  // z(bf16, stride 140) + wl3(f32)
  __shared__ float lsc[256], lsh[256];
  short* zs  = (short*)smem;
  float* wl3 = (float*)(smem + 128 * 140 * 2);
  short* ldsA = (short*)smem;          // staging aliases z region (dead until after K loop)
  short* ldsB = (short*)smem + 4096;
  int tid = threadIdx.x;
  for (int i = tid; i < 1280; i += 256) wl3[i] = Wl3[i];
  lsc[tid] = tsc[tid]; lsh[tid] = tsh[tid];
  __syncthreads();
  int bm0 = blockIdx.x * 128;
  int lane = tid & 63, w = tid >> 6;
  int wm = w >> 1, wn = w & 1;
  int lr = lane & 15, lg = lane >> 4;
  f32x4 acc[4][4] = {};
  for (int kt = 0; kt < 256; kt += 32) {
#pragma unroll
    for (int c = 0; c < 2; c++) {
      int chunk = c * 256 + tid;
      int row = chunk >> 2;
      int kc = (chunk & 3) * 8;
      int rA = bm0 + row; if (rA > M - 1) rA = M - 1;
      bf16x8 va = *(const bf16x8*)(V + (size_t)rA * 256 + kt + kc);
      float4 x0 = *(const float4*)(x + (size_t)rA * 256 + kt + kc);
      float4 x1 = *(const float4*)(x + (size_t)rA * 256 + kt + kc + 4);
      float xs[8] = {x0.x, x0.y, x0.z, x0.w, x1.x, x1.y, x1.z, x1.w};
      bf16x8 tt;
#pragma unroll
      for (int jj = 0; jj < 8; jj++) {
        float f = bf2f((unsigned short)va[jj]) * lsc[kt + kc + jj] + lsh[kt + kc + jj];
        f = f > 0.f ? f : 0.1f * f;
        tt[jj] = f2bf(xs[jj] + 0.01f * f);
      }
      *((bf16x8*)ldsA + chunk) = tt;
      *((bf16x8*)ldsB + chunk) = *(const bf16x8*)(BT + (size_t)row * 256 + kt + kc);
    }
    __syncthreads();
    bf16x8 af[4], bfr[4];
#pragma unroll
    for (int mi = 0; mi < 4; mi++) af[mi] = *((const bf16x8*)ldsA + ((wm * 64 + mi * 16 + lr) * 4 + lg));
#pragma unroll
    for (int ni = 0; ni < 4; ni++) bfr[ni] = *((const bf16x8*)ldsB + ((wn * 64 + ni * 16 + lr) * 4 + lg));
#pragma unroll
    for (int mi = 0; mi < 4; mi++)
#pragma unroll
      for (int ni = 0; ni < 4; ni++)
        acc[mi][ni] = __builtin_amdgcn_mfma_f32_16x16x32_bf16(af[mi], bfr[ni], acc[mi][ni], 0, 0, 0);
    __syncthreads();
  }
#pragma unroll
  for (int ni = 0; ni < 4; ni++) {
    int col = wn * 64 + ni * 16 + lr;
    float bv = bl1[col];
#pragma unroll
    for (int mi = 0; mi < 4; mi++) {
#pragma unroll
      for (int r = 0; r < 4; r++) {
        int rl = wm * 64 + mi * 16 + lg * 4 + r;
        float tv = acc[mi][ni][r] + bv;
        tv = tv > 0.f ? tv : 0.1f * tv;
        zs[rl * 140 + col] = f2bf(tv);
      }
    }
  }
  __syncthreads();
  int r = tid >> 1, ch = tid & 1;
  float av[5];
#pragma unroll
  for (int c = 0; c < 5; c++) av[c] = bl3[ch * 5 + c];
  for (int k = 0; k < 128; k++) {
    float zv = bf2f((unsigned short)zs[r * 140 + k]);
#pragma unroll
    for (int c = 0; c < 5; c++) av[c] += zv * wl3[k * 10 + ch * 5 + c];
  }
  int grow = bm0 + r;
  if (grow < M) {
#pragma unroll
    for (int c = 0; c < 5; c++) out[(size_t)grow * 10 + ch * 5 + c] = av[c];
  }
}

extern "C" void kernel_launch(void* const* d_in, const int* in_sizes, int n_in,
                              void* d_out, int out_size, void* d_ws, size_t ws_size,
                              hipStream_t stream) {
  const float* x   = (const float*)d_in[0];
  const int*   ew  = (const int*)d_in[1];
  const float* W1  = (const float*)d_in[2];
  const float* b1  = (const float*)d_in[3];
  const float* g1  = (const float*)d_in[4];
  const float* be1 = (const float*)d_in[5];
  const float* W2  = (const float*)d_in[6];
  const float* b2  = (const float*)d_in[7];
  const float* g4  = (const float*)d_in[8];
  const float* be4 = (const float*)d_in[9];
  const float* Wl1 = (const float*)d_in[10];
  const float* bl1 = (const float*)d_in[11];
  const float* Wl3 = (const float*)d_in[12];
  const float* bl3 = (const float*)d_in[13];
  float* out = (float*)d_out;

  char* ws = (char*)d_ws;
  const size_t OFF_OFF  = 0;          // (N+1) ints
  const size_t OFF_BASES= 400128;     // NBUCK+1 ints
  const size_t OFF_CNT  = 800256;     // CGRID x NBUCK ints (306KB)
  const size_t OFF_STATS= 1200384;    // 4x256 f32 (sum1,ssq1,sum4,ssq4) -- memset
  const size_t OFF_BN   = 1204480;    // 4x256 f32 (sc1,sh1,sc4,sh4)
  const size_t OFF_FLAG = 1208576;
  const size_t OFF_W1T  = 1209216;
  const size_t OFF_W2T  = 1340288;
  const size_t OFF_WL1T = 1471360;
  const size_t OFF_CSR  = 1536896;    // NE ints (6.4MB)
  const size_t OFF_BUFA = 7936896;    // 51.2MB ; pairs (6.4MB) aliases this
  const size_t OFF_BUFB = 59136896;   // xb aliases bufB (xb dead before GEMM1 writes bufB)
  if (ws_size < 110336896) return;

  int* off_  = (int*)(ws + OFF_OFF);
  int* bases_= (int*)(ws + OFF_BASES);
  int* cnt_  = (int*)(ws + OFF_CNT);
  float* sum1 = (float*)(ws + OFF_STATS);
  float* ssq1 = sum1 + 256;
  float* sum4 = sum1 + 512;
  float* ssq4 = sum1 + 768;
  float* sc1 = (float*)(ws + OFF_BN);
  float* sh1 = sc1 + 256;
  float* sc4 = sc1 + 512;
  float* sh4 = sc1 + 768;
  int* flag_ = (int*)(ws + OFF_FLAG);
  short* W1T  = (short*)(ws + OFF_W1T);
  short* W2T  = (short*)(ws + OFF_W2T);
  short* Wl1T = (short*)(ws + OFF_WL1T);
  int* csr_   = (int*)(ws + OFF_CSR);
  short* bufA = (short*)(ws + OFF_BUFA);
  short* bufB = (short*)(ws + OFF_BUFB);
  int* pairs_ = (int*)(ws + OFF_BUFA);  // alias: dead before k_agg2 writes bufA
  short* xb   = bufB;                   // alias: dead before GEMM1 writes bufB

  hipMemsetAsync(ws + OFF_STATS, 0, 4096, stream);
  k_detect<<<1, 256, 0, stream>>>(ew, flag_);
  k_cvtW<<<640, 256, 0, stream>>>(W1, W2, Wl1, W1T, W2T, Wl1T);
  k_cvtX<<<12500, 256, 0, stream>>>(x, xb);
  k_count<<<CGRID, 1024, 0, stream>>>(ew, flag_, cnt_);
  k_colscan<<<1, 1024, 0, stream>>>(cnt_, bases_, off_);
  k_scatter<<<CGRID, 1024, 0, stream>>>(ew, flag_, cnt_, pairs_);
  k_bsort<<<NBUCK, 256, 0, stream>>>(pairs_, bases_, off_, csr_);
  k_agg2<<<25000, 256, 0, stream>>>(xb, off_, csr_, bufA);
  k_gemm<0, 0, 1><<<1564, 256, 0, stream>>>(bufA, W1T, b1, bufB, NN,
                                            nullptr, nullptr, sum1, ssq1);
  k_bnprep<<<1, 256, 0, stream>>>(sum1, ssq1, g1, be1, sc1, sh1, NN);
  k_gemm<1, 1, 1><<<1564, 256, 0, stream>>>(bufB, W2T, b2, bufA, NN,
                                            sc1, sh1, sum4, ssq4);
  k_bnprep<<<1, 256, 0, stream>>>(sum4, ssq4, g4, be4, sc4, sh4, NN);
  k_head<<<782, 256, 0, stream>>>(bufA, x, Wl1T, bl1, Wl3, bl3, sc4, sh4, out, NN);
}

// Round 4
// 327.581 us; speedup vs baseline: 2.6755x; 1.1670x over previous
//
#include <hip/hip_runtime.h>

constexpr int NN = 100000;   // nodes
constexpr int NE = 1600000;  // edges
constexpr int HD = 256;      // hidden
constexpr int NBUCK = 782;   // ceil(NN/128)
constexpr int CGRID = 98;    // count/scatter blocks (98*16384 >= NE)

typedef __attribute__((ext_vector_type(4))) float  f32x4;
typedef __attribute__((ext_vector_type(2))) float  f32x2;
typedef __attribute__((ext_vector_type(8))) short  bf16x8;

#if defined(__has_builtin)
#if __has_builtin(__builtin_amdgcn_cvt_pk_f32_fp8) && __has_builtin(__builtin_amdgcn_cvt_pk_fp8_f32)
#define HAVE_FP8_CVT 1
#endif
#endif
#ifndef HAVE_FP8_CVT
#define HAVE_FP8_CVT 0
#endif

__device__ __forceinline__ float bf2f(unsigned short u) {
  union { unsigned int i; float f; } c;
  c.i = ((unsigned int)u) << 16;
  return c.f;
}
__device__ __forceinline__ short f2bf(float f) {
  union { float f; unsigned int i; } c; c.f = f;
  unsigned int i = c.i + 0x7fffu + ((c.i >> 16) & 1u);
  return (short)(i >> 16);
}

// ---- edge dtype detection: int64 -> all odd 32-bit words (high words) are 0 ----
__global__ void k_detect(const int* __restrict__ ew, int* __restrict__ flag) {
  __shared__ int bad;
  if (threadIdx.x == 0) bad = 0;
  __syncthreads();
  int nz = 0;
  for (int i = threadIdx.x; i < 2048; i += 256) nz |= ew[2 * i + 1];
  if (nz) atomicOr(&bad, 1);
  __syncthreads();
  if (threadIdx.x == 0) *flag = (bad == 0) ? 1 : 0;
}

// ---- convert weights to bf16, transposed for LDS-friendly B staging ----
__global__ void k_cvtW(const float* __restrict__ W1, const float* __restrict__ W2,
                       const float* __restrict__ Wl1, short* __restrict__ W1T,
                       short* __restrict__ W2T, short* __restrict__ Wl1T) {
  int b = blockIdx.x, t = threadIdx.x;
  if (b < 256)       W1T[b * 256 + t]        = f2bf(W1[t * 256 + b]);
  else if (b < 512){ int n = b - 256; W2T[n * 256 + t]  = f2bf(W2[t * 256 + n]); }
  else             { int n = b - 512; Wl1T[n * 256 + t] = f2bf(Wl1[t * 128 + n]); }
}

// ---- x (f32) -> quantized gather copy ----
#if HAVE_FP8_CVT
// fp8 e4m3 via HW packed converters: 25.6MB footprint, 256B/row
__global__ void k_cvtX(const float* __restrict__ x, void* __restrict__ xq) {
  int c = blockIdx.x * 256 + threadIdx.x;  // 3.2M chunks of 8, grid exact
  float4 a = ((const float4*)x)[2 * (size_t)c];
  float4 b = ((const float4*)x)[2 * (size_t)c + 1];
  int p0 = 0, p1 = 0;
  p0 = __builtin_amdgcn_cvt_pk_fp8_f32(a.x, a.y, p0, false);
  p0 = __builtin_amdgcn_cvt_pk_fp8_f32(a.z, a.w, p0, true);
  p1 = __builtin_amdgcn_cvt_pk_fp8_f32(b.x, b.y, p1, false);
  p1 = __builtin_amdgcn_cvt_pk_fp8_f32(b.z, b.w, p1, true);
  ((int2*)xq)[c] = make_int2(p0, p1);
}
#else
__global__ void k_cvtX(const float* __restrict__ x, void* __restrict__ xq) {
  int c = blockIdx.x * 256 + threadIdx.x;
  float4 a = ((const float4*)x)[2 * (size_t)c];
  float4 b = ((const float4*)x)[2 * (size_t)c + 1];
  bf16x8 o;
  o[0] = f2bf(a.x); o[1] = f2bf(a.y); o[2] = f2bf(a.z); o[3] = f2bf(a.w);
  o[4] = f2bf(b.x); o[5] = f2bf(b.y); o[6] = f2bf(b.z); o[7] = f2bf(b.w);
  ((bf16x8*)xq)[c] = o;
}
#endif

// ---- pass 1: per-block bucket histogram (no global atomics) ----
__global__ __launch_bounds__(1024) void k_count(const int* __restrict__ ew,
                                                const int* __restrict__ flag,
                                                int* __restrict__ cntmat) {
  __shared__ int lcnt[NBUCK];
  int m64 = *flag;
  int t = threadIdx.x;
  for (int i = t; i < NBUCK; i += 1024) lcnt[i] = 0;
  __syncthreads();
  int base = blockIdx.x * 16384;
#pragma unroll
  for (int u = 0; u < 16; u++) {
    int e = base + u * 1024 + t;
    if (e < NE) {
      int d = m64 ? ew[2 * (NE + e)] : ew[NE + e];
      atomicAdd(&lcnt[d >> 7], 1);
    }
  }
  __syncthreads();
  for (int i = t; i < NBUCK; i += 1024) cntmat[blockIdx.x * NBUCK + i] = lcnt[i];
}

// ---- pass 2: column scan -> per-(block,bucket) bases + bucket bases ----
__global__ __launch_bounds__(1024) void k_colscan(int* __restrict__ cntmat,
                                                  int* __restrict__ bases,
                                                  int* __restrict__ off_) {
  __shared__ int tot[1024];
  int t = threadIdx.x;
  int sum = 0;
  if (t < NBUCK) {
    for (int g = 0; g < CGRID; g++) sum += cntmat[g * NBUCK + t];
    tot[t] = sum;
  }
  __syncthreads();
  int v = (t < NBUCK) ? sum : 0;
  for (int o = 1; o < 1024; o <<= 1) {
    int u = (t >= o && t < NBUCK) ? tot[t - o] : 0;
    __syncthreads();
    if (t < NBUCK) tot[t] += u;
    __syncthreads();
  }
  if (t < NBUCK) {
    int b = tot[t] - v;  // exclusive
    bases[t] = b;
    int run = b;
    for (int g = 0; g < CGRID; g++) {
      int c = cntmat[g * NBUCK + t];
      cntmat[g * NBUCK + t] = run;
      run += c;
    }
  }
  if (t == NBUCK) bases[NBUCK] = NE;
  if (t == NBUCK + 1) off_[NN] = NE;
}

// ---- pass 3: dense bucketed scatter of packed (src | ld<<17) ----
__global__ __launch_bounds__(1024) void k_scatter(const int* __restrict__ ew,
                                                  const int* __restrict__ flag,
                                                  const int* __restrict__ cntmat,
                                                  int* __restrict__ pairs) {
  __shared__ int lcur[NBUCK];
  int m64 = *flag;
  int t = threadIdx.x;
  for (int i = t; i < NBUCK; i += 1024) lcur[i] = cntmat[blockIdx.x * NBUCK + i];
  __syncthreads();
  int base = blockIdx.x * 16384;
#pragma unroll
  for (int u = 0; u < 16; u++) {
    int e = base + u * 1024 + t;
    if (e < NE) {
      int d = m64 ? ew[2 * (NE + e)] : ew[NE + e];
      int s = m64 ? ew[2 * e] : ew[e];
      int slot = atomicAdd(&lcur[d >> 7], 1);
      pairs[slot] = s | ((d & 127) << 17);
    }
  }
}

// ---- pass 4: per-bucket counting sort in LDS -> off_ + csr ----
__global__ __launch_bounds__(256) void k_bsort(const int* __restrict__ pairs,
                                               const int* __restrict__ bases,
                                               int* __restrict__ off_,
                                               int* __restrict__ csr) {
  __shared__ int lcnt[128], lofs[128], lcur[128];
  int b = blockIdx.x, t = threadIdx.x;
  int s0 = bases[b], s1 = bases[b + 1];
  if (t < 128) lcnt[t] = 0;
  __syncthreads();
  for (int j = s0 + t; j < s1; j += 256) atomicAdd(&lcnt[(pairs[j] >> 17) & 127], 1);
  __syncthreads();
  int v = (t < 128) ? lcnt[t] : 0;
  if (t < 128) lofs[t] = v;
  __syncthreads();
  for (int o = 1; o < 128; o <<= 1) {
    int u = (t >= o && t < 128) ? lofs[t - o] : 0;
    __syncthreads();
    if (t < 128) lofs[t] += u;
    __syncthreads();
  }
  if (t < 128) {
    int ex = lofs[t] - v;  // exclusive
    lcur[t] = ex;
    int node = b * 128 + t;
    if (node < NN) off_[node] = s0 + ex;
  }
  __syncthreads();
  for (int j = s0 + t; j < s1; j += 256) {
    int p = pairs[j];
    int slot = atomicAdd(&lcur[(p >> 17) & 127], 1);
    csr[s0 + slot] = p & 0x1FFFF;
  }
}

// one WAVE per node, lane owns 4 columns, 8-deep load ILP
#if HAVE_FP8_CVT
__global__ __launch_bounds__(256) void k_agg2(const void* __restrict__ xq,
                                              const int* __restrict__ off_,
                                              const int* __restrict__ csr,
                                              short* __restrict__ h0) {
  int node = blockIdx.x * 4 + (threadIdx.x >> 6);  // grid 25000 exact
  int lane = threadIdx.x & 63;
  const unsigned char* xb = (const unsigned char*)xq;
  size_t boff = (size_t)lane * 4;  // byte offset within 256B row
  int s0 = off_[node], s1 = off_[node + 1];
  int sw = *(const int*)(xb + (size_t)node * 256 + boff);
  f32x2 slo = __builtin_amdgcn_cvt_pk_f32_fp8(sw, false);
  f32x2 shi = __builtin_amdgcn_cvt_pk_f32_fp8(sw, true);
  float a0 = slo[0], a1 = slo[1], a2 = shi[0], a3 = shi[1];
  int j = s0;
  while (j + 8 <= s1) {
    int idx[8];
#pragma unroll
    for (int u = 0; u < 8; u++) idx[u] = csr[j + u];
    int w[8];
#pragma unroll
    for (int u = 0; u < 8; u++) w[u] = *(const int*)(xb + (size_t)idx[u] * 256 + boff);
#pragma unroll
    for (int u = 0; u < 8; u++) {
      f32x2 lo = __builtin_amdgcn_cvt_pk_f32_fp8(w[u], false);
      f32x2 hi = __builtin_amdgcn_cvt_pk_f32_fp8(w[u], true);
      a0 += lo[0]; a1 += lo[1]; a2 += hi[0]; a3 += hi[1];
    }
    j += 8;
  }
  if (j + 4 <= s1) {
    int idx[4];
#pragma unroll
    for (int u = 0; u < 4; u++) idx[u] = csr[j + u];
    int w[4];
#pragma unroll
    for (int u = 0; u < 4; u++) w[u] = *(const int*)(xb + (size_t)idx[u] * 256 + boff);
#pragma unroll
    for (int u = 0; u < 4; u++) {
      f32x2 lo = __builtin_amdgcn_cvt_pk_f32_fp8(w[u], false);
      f32x2 hi = __builtin_amdgcn_cvt_pk_f32_fp8(w[u], true);
      a0 += lo[0]; a1 += lo[1]; a2 += hi[0]; a3 += hi[1];
    }
    j += 4;
  }
  for (; j < s1; j++) {
    int s = csr[j];
    int w = *(const int*)(xb + (size_t)s * 256 + boff);
    f32x2 lo = __builtin_amdgcn_cvt_pk_f32_fp8(w, false);
    f32x2 hi = __builtin_amdgcn_cvt_pk_f32_fp8(w, true);
    a0 += lo[0]; a1 += lo[1]; a2 += hi[0]; a3 += hi[1];
  }
  ushort4 o;
  o.x = (ushort)f2bf(a0); o.y = (ushort)f2bf(a1);
  o.z = (ushort)f2bf(a2); o.w = (ushort)f2bf(a3);
  *(ushort4*)((ushort*)h0 + (size_t)node * 256 + (size_t)lane * 4) = o;
}
#else
__global__ __launch_bounds__(256) void k_agg2(const void* __restrict__ xq,
                                              const int* __restrict__ off_,
                                              const int* __restrict__ csr,
                                              short* __restrict__ h0) {
  int node = blockIdx.x * 4 + (threadIdx.x >> 6);
  int lane = threadIdx.x & 63;
  const ushort* xu = (const ushort*)xq;
  size_t coff = (size_t)lane * 4;
  int s0 = off_[node], s1 = off_[node + 1];
  ushort4 sv = *(const ushort4*)(xu + (size_t)node * 256 + coff);
  float a0 = bf2f(sv.x), a1 = bf2f(sv.y), a2 = bf2f(sv.z), a3 = bf2f(sv.w);
  int j = s0;
  while (j + 8 <= s1) {
    int idx[8];
#pragma unroll
    for (int u = 0; u < 8; u++) idx[u] = csr[j + u];
    ushort4 v[8];
#pragma unroll
    for (int u = 0; u < 8; u++) v[u] = *(const ushort4*)(xu + (size_t)idx[u] * 256 + coff);
#pragma unroll
    for (int u = 0; u < 8; u++) {
      a0 += bf2f(v[u].x); a1 += bf2f(v[u].y);
      a2 += bf2f(v[u].z); a3 += bf2f(v[u].w);
    }
    j += 8;
  }
  for (; j < s1; j++) {
    int s = csr[j];
    ushort4 v = *(const ushort4*)(xu + (size_t)s * 256 + coff);
    a0 += bf2f(v.x); a1 += bf2f(v.y); a2 += bf2f(v.z); a3 += bf2f(v.w);
  }
  ushort4 o;
  o.x = (ushort)f2bf(a0); o.y = (ushort)f2bf(a1);
  o.z = (ushort)f2bf(a2); o.w = (ushort)f2bf(a3);
  *(ushort4*)((ushort*)h0 + (size_t)node * 256 + coff) = o;
}
#endif

// C[M x 256] = act(A' * B + bias); A' = optional bn+relu transform of A (fused elem1)
// STATS: per-column sum/sumsq of the (activated, f32) output via shfl+LDS+atomics
template <int ACT, int TIN, int STATS>
__global__ __launch_bounds__(256) void k_gemm(const short* __restrict__ A,
                                              const short* __restrict__ BT,
                                              const float* __restrict__ bias,
                                              short* __restrict__ C, int M,
                                              const float* __restrict__ tsc,
                                              const float* __restrict__ tsh,
                                              float* __restrict__ gsum,
                                              float* __restrict__ gssq) {
  __shared__ short ldsA[4096];  // [128][32] bf16
  __shared__ short ldsB[4096];  // [128 cols][32 k] bf16
  __shared__ float lsc[256], lsh[256];
  __shared__ float lsum[128], lssq[128];
  int tid = threadIdx.x;
  if (TIN) { lsc[tid] = tsc[tid]; lsh[tid] = tsh[tid]; }
  if (STATS && tid < 128) { lsum[tid] = 0.f; lssq[tid] = 0.f; }
  __syncthreads();
  int bm = blockIdx.x >> 1, bn = blockIdx.x & 1;
  int bm0 = bm * 128, bn0 = bn * 128;
  int lane = tid & 63, w = tid >> 6;
  int wm = w >> 1, wn = w & 1;
  int lr = lane & 15, lg = lane >> 4;
  f32x4 acc[4][4] = {};
  for (int kt = 0; kt < 256; kt += 32) {
#pragma unroll
    for (int c = 0; c < 2; c++) {
      int chunk = c * 256 + tid;
      int row = chunk >> 2;
      int kc = (chunk & 3) * 8;
      int rA = bm0 + row; if (rA > M - 1) rA = M - 1;
      bf16x8 va = *(const bf16x8*)(A + (size_t)rA * 256 + kt + kc);
      if (TIN) {
        bf16x8 tt;
#pragma unroll
        for (int jj = 0; jj < 8; jj++) {
          float f = bf2f((unsigned short)va[jj]) * lsc[kt + kc + jj] + lsh[kt + kc + jj];
          f = fmaxf(f, 0.f);
          tt[jj] = f2bf(f);
        }
        va = tt;
      }
      *((bf16x8*)ldsA + chunk) = va;
      *((bf16x8*)ldsB + chunk) = *(const bf16x8*)(BT + (size_t)(bn0 + row) * 256 + kt + kc);
    }
    __syncthreads();
    bf16x8 af[4], bfr[4];
#pragma unroll
    for (int mi = 0; mi < 4; mi++) af[mi] = *((const bf16x8*)ldsA + ((wm * 64 + mi * 16 + lr) * 4 + lg));
#pragma unroll
    for (int ni = 0; ni < 4; ni++) bfr[ni] = *((const bf16x8*)ldsB + ((wn * 64 + ni * 16 + lr) * 4 + lg));
#pragma unroll
    for (int mi = 0; mi < 4; mi++)
#pragma unroll
      for (int ni = 0; ni < 4; ni++)
        acc[mi][ni] = __builtin_amdgcn_mfma_f32_16x16x32_bf16(af[mi], bfr[ni], acc[mi][ni], 0, 0, 0);
    __syncthreads();
  }
#pragma unroll
  for (int ni = 0; ni < 4; ni++) {
    int col = bn0 + wn * 64 + ni * 16 + lr;
    float bv = bias[col];
    float ps = 0.f, pq = 0.f;
#pragma unroll
    for (int mi = 0; mi < 4; mi++) {
#pragma unroll
      for (int r = 0; r < 4; r++) {
        int row = bm0 + wm * 64 + mi * 16 + lg * 4 + r;
        float tv = acc[mi][ni][r] + bv;
        if (ACT == 1) tv = tv > 0.f ? tv : 0.01f * tv;  // lrelu(lrelu(t,0.1),0.1)
        if (row < M) {
          if (STATS) { ps += tv; pq += tv * tv; }
          C[(size_t)row * 256 + col] = f2bf(tv);
        }
      }
    }
    if (STATS) {
      ps += __shfl_xor(ps, 16); pq += __shfl_xor(pq, 16);
      ps += __shfl_xor(ps, 32); pq += __shfl_xor(pq, 32);
      if (lane < 16) {
        atomicAdd(&lsum[wn * 64 + ni * 16 + lane], ps);
        atomicAdd(&lssq[wn * 64 + ni * 16 + lane], pq);
      }
    }
  }
  if (STATS) {
    __syncthreads();
    if (tid < 128) {
      atomicAdd(&gsum[bn0 + tid], lsum[tid]);
      atomicAdd(&gssq[bn0 + tid], lssq[tid]);
    }
  }
}

__global__ void k_bnprep(const float* __restrict__ sum, const float* __restrict__ ssq,
                         const float* __restrict__ g, const float* __restrict__ be,
                         float* __restrict__ scale, float* __restrict__ shift, int M) {
  int c = threadIdx.x;
  float mu = sum[c] / (float)M;
  float var = ssq[c] / (float)M - mu * mu;
  float rs = rsqrtf(var + 1e-5f);
  float sc = g[c] * rs;
  scale[c] = sc;
  shift[c] = be[c] - mu * sc;
}

// head with fused elem2 on A-staging:
//   A' = bf16( x + 0.01 * lrelu(bn4(V)) );  z = lrelu(A' @ Wl1 + bl1);  out = z @ Wl3 + bl3
__global__ __launch_bounds__(256) void k_head(const short* __restrict__ V,
                                              const float* __restrict__ x,
                                              const short* __restrict__ BT,
                                              const float* __restrict__ bl1,
                                              const float* __restrict__ Wl3,
                                              const float* __restrict__ bl3,
                                              const float* __restrict__ tsc,
                                              const float* __restrict__ tsh,
                                              float* __restrict__ out, int M) {
  __shared__ char smem[128 * 140 * 2 + 1280 * 4];  // z(bf16, stride 140) + wl3(f32)
  __shared__ float lsc[256], lsh[256];
  short* zs  = (short*)smem;
  float* wl3 = (float*)(smem + 128 * 140 * 2);
  short* ldsA = (short*)smem;          // staging aliases z region (dead until after K loop)
  short* ldsB = (short*)smem + 4096;
  int tid = threadIdx.x;
  for (int i = tid; i < 1280; i += 256) wl3[i] = Wl3[i];
  lsc[tid] = tsc[tid]; lsh[tid] = tsh[tid];
  __syncthreads();
  int bm0 = blockIdx.x * 128;
  int lane = tid & 63, w = tid >> 6;
  int wm = w >> 1, wn = w & 1;
  int lr = lane & 15, lg = lane >> 4;
  f32x4 acc[4][4] = {};
  for (int kt = 0; kt < 256; kt += 32) {
#pragma unroll
    for (int c = 0; c < 2; c++) {
      int chunk = c * 256 + tid;
      int row = chunk >> 2;
      int kc = (chunk & 3) * 8;
      int rA = bm0 + row; if (rA > M - 1) rA = M - 1;
      bf16x8 va = *(const bf16x8*)(V + (size_t)rA * 256 + kt + kc);
      float4 x0 = *(const float4*)(x + (size_t)rA * 256 + kt + kc);
      float4 x1 = *(const float4*)(x + (size_t)rA * 256 + kt + kc + 4);
      float xs[8] = {x0.x, x0.y, x0.z, x0.w, x1.x, x1.y, x1.z, x1.w};
      bf16x8 tt;
#pragma unroll
      for (int jj = 0; jj < 8; jj++) {
        float f = bf2f((unsigned short)va[jj]) * lsc[kt + kc + jj] + lsh[kt + kc + jj];
        f = f > 0.f ? f : 0.1f * f;
        tt[jj] = f2bf(xs[jj] + 0.01f * f);
      }
      *((bf16x8*)ldsA + chunk) = tt;
      *((bf16x8*)ldsB + chunk) = *(const bf16x8*)(BT + (size_t)row * 256 + kt + kc);
    }
    __syncthreads();
    bf16x8 af[4], bfr[4];
#pragma unroll
    for (int mi = 0; mi < 4; mi++) af[mi] = *((const bf16x8*)ldsA + ((wm * 64 + mi * 16 + lr) * 4 + lg));
#pragma unroll
    for (int ni = 0; ni < 4; ni++) bfr[ni] = *((const bf16x8*)ldsB + ((wn * 64 + ni * 16 + lr) * 4 + lg));
#pragma unroll
    for (int mi = 0; mi < 4; mi++)
#pragma unroll
      for (int ni = 0; ni < 4; ni++)
        acc[mi][ni] = __builtin_amdgcn_mfma_f32_16x16x32_bf16(af[mi], bfr[ni], acc[mi][ni], 0, 0, 0);
    __syncthreads();
  }
#pragma unroll
  for (int ni = 0; ni < 4; ni++) {
    int col = wn * 64 + ni * 16 + lr;
    float bv = bl1[col];
#pragma unroll
    for (int mi = 0; mi < 4; mi++) {
#pragma unroll
      for (int r = 0; r < 4; r++) {
        int rl = wm * 64 + mi * 16 + lg * 4 + r;
        float tv = acc[mi][ni][r] + bv;
        tv = tv > 0.f ? tv : 0.1f * tv;
        zs[rl * 140 + col] = f2bf(tv);
      }
    }
  }
  __syncthreads();
  int r = tid >> 1, ch = tid & 1;
  float av[5];
#pragma unroll
  for (int c = 0; c < 5; c++) av[c] = bl3[ch * 5 + c];
  for (int k = 0; k < 128; k++) {
    float zv = bf2f((unsigned short)zs[r * 140 + k]);
#pragma unroll
    for (int c = 0; c < 5; c++) av[c] += zv * wl3[k * 10 + ch * 5 + c];
  }
  int grow = bm0 + r;
  if (grow < M) {
#pragma unroll
    for (int c = 0; c < 5; c++) out[(size_t)grow * 10 + ch * 5 + c] = av[c];
  }
}

extern "C" void kernel_launch(void* const* d_in, const int* in_sizes, int n_in,
                              void* d_out, int out_size, void* d_ws, size_t ws_size,
                              hipStream_t stream) {
  const float* x   = (const float*)d_in[0];
  const int*   ew  = (const int*)d_in[1];
  const float* W1  = (const float*)d_in[2];
  const float* b1  = (const float*)d_in[3];
  const float* g1  = (const float*)d_in[4];
  const float* be1 = (const float*)d_in[5];
  const float* W2  = (const float*)d_in[6];
  const float* b2  = (const float*)d_in[7];
  const float* g4  = (const float*)d_in[8];
  const float* be4 = (const float*)d_in[9];
  const float* Wl1 = (const float*)d_in[10];
  const float* bl1 = (const float*)d_in[11];
  const float* Wl3 = (const float*)d_in[12];
  const float* bl3 = (const float*)d_in[13];
  float* out = (float*)d_out;

  char* ws = (char*)d_ws;
  const size_t OFF_OFF  = 0;          // (N+1) ints
  const size_t OFF_BASES= 400128;     // NBUCK+1 ints
  const size_t OFF_CNT  = 800256;     // CGRID x NBUCK ints (306KB)
  const size_t OFF_STATS= 1200384;    // 4x256 f32 (sum1,ssq1,sum4,ssq4) -- memset
  const size_t OFF_BN   = 1204480;    // 4x256 f32 (sc1,sh1,sc4,sh4)
  const size_t OFF_FLAG = 1208576;
  const size_t OFF_W1T  = 1209216;
  const size_t OFF_W2T  = 1340288;
  const size_t OFF_WL1T = 1471360;
  const size_t OFF_CSR  = 1536896;    // NE ints (6.4MB)
  const size_t OFF_BUFA = 7936896;    // 51.2MB ; pairs (6.4MB) aliases this
  const size_t OFF_BUFB = 59136896;   // xq aliases bufB (xq dead before GEMM1 writes bufB)
  if (ws_size < 110336896) return;

  int* off_  = (int*)(ws + OFF_OFF);
  int* bases_= (int*)(ws + OFF_BASES);
  int* cnt_  = (int*)(ws + OFF_CNT);
  float* sum1 = (float*)(ws + OFF_STATS);
  float* ssq1 = sum1 + 256;
  float* sum4 = sum1 + 512;
  float* ssq4 = sum1 + 768;
  float* sc1 = (float*)(ws + OFF_BN);
  float* sh1 = sc1 + 256;
  float* sc4 = sc1 + 512;
  float* sh4 = sc1 + 768;
  int* flag_ = (int*)(ws + OFF_FLAG);
  short* W1T  = (short*)(ws + OFF_W1T);
  short* W2T  = (short*)(ws + OFF_W2T);
  short* Wl1T = (short*)(ws + OFF_WL1T);
  int* csr_   = (int*)(ws + OFF_CSR);
  short* bufA = (short*)(ws + OFF_BUFA);
  short* bufB = (short*)(ws + OFF_BUFB);
  int* pairs_ = (int*)(ws + OFF_BUFA);  // alias: dead before k_agg2 writes bufA
  void* xq    = (void*)bufB;            // alias: dead before GEMM1 writes bufB

  hipMemsetAsync(ws + OFF_STATS, 0, 4096, stream);
  k_detect<<<1, 256, 0, stream>>>(ew, flag_);
  k_cvtW<<<640, 256, 0, stream>>>(W1, W2, Wl1, W1T, W2T, Wl1T);
  k_cvtX<<<12500, 256, 0, stream>>>(x, xq);
  k_count<<<CGRID, 1024, 0, stream>>>(ew, flag_, cnt_);
  k_colscan<<<1, 1024, 0, stream>>>(cnt_, bases_, off_);
  k_scatter<<<CGRID, 1024, 0, stream>>>(ew, flag_, cnt_, pairs_);
  k_bsort<<<NBUCK, 256, 0, stream>>>(pairs_, bases_, off_, csr_);
  k_agg2<<<25000, 256, 0, stream>>>(xq, off_, csr_, bufA);
  k_gemm<0, 0, 1><<<1564, 256, 0, stream>>>(bufA, W1T, b1, bufB, NN,
                                            nullptr, nullptr, sum1, ssq1);
  k_bnprep<<<1, 256, 0, stream>>>(sum1, ssq1, g1, be1, sc1, sh1, NN);
  k_gemm<1, 1, 1><<<1564, 256, 0, stream>>>(bufB, W2T, b2, bufA, NN,
                                            sc1, sh1, sum4, ssq4);
  k_bnprep<<<1, 256, 0, stream>>>(sum4, ssq4, g4, be4, sc4, sh4, NN);
  k_head<<<782, 256, 0, stream>>>(bufA, x, Wl1T, bl1, Wl3, bl3, sc4, sh4, out, NN);
}

// Round 5
// 303.873 us; speedup vs baseline: 2.8842x; 1.0780x over previous
//
#include <hip/hip_runtime.h>

constexpr int NN = 100000;   // nodes
constexpr int NE = 1600000;  // edges
constexpr int HD = 256;      // hidden
constexpr int NBUCK = 782;   // ceil(NN/128)
constexpr int CGRID = 98;    // count/scatter blocks (98*16384 >= NE)

typedef __attribute__((ext_vector_type(4))) float  f32x4;
typedef __attribute__((ext_vector_type(2))) float  f32x2;
typedef __attribute__((ext_vector_type(8))) short  bf16x8;

#if defined(__has_builtin)
#if __has_builtin(__builtin_amdgcn_cvt_pk_f32_fp8) && __has_builtin(__builtin_amdgcn_cvt_pk_fp8_f32)
#define HAVE_FP8_CVT 1
#endif
#endif
#ifndef HAVE_FP8_CVT
#define HAVE_FP8_CVT 0
#endif

__device__ __forceinline__ float bf2f(unsigned short u) {
  union { unsigned int i; float f; } c;
  c.i = ((unsigned int)u) << 16;
  return c.f;
}
__device__ __forceinline__ short f2bf(float f) {
  union { float f; unsigned int i; } c; c.f = f;
  unsigned int i = c.i + 0x7fffu + ((c.i >> 16) & 1u);
  return (short)(i >> 16);
}

// async global->LDS, 16B per lane; LDS dest is wave-uniform base + lane*16
__device__ __forceinline__ void gload16(const void* g, void* l) {
  __builtin_amdgcn_global_load_lds(
      (const __attribute__((address_space(1))) unsigned int*)g,
      (__attribute__((address_space(3))) unsigned int*)l, 16, 0, 0);
}

// ---- edge dtype detection: int64 -> all odd 32-bit words (high words) are 0 ----
__global__ void k_detect(const int* __restrict__ ew, int* __restrict__ flag) {
  __shared__ int bad;
  if (threadIdx.x == 0) bad = 0;
  __syncthreads();
  int nz = 0;
  for (int i = threadIdx.x; i < 2048; i += 256) nz |= ew[2 * i + 1];
  if (nz) atomicOr(&bad, 1);
  __syncthreads();
  if (threadIdx.x == 0) *flag = (bad == 0) ? 1 : 0;
}

// ---- convert weights to bf16, transposed for LDS-friendly B staging ----
__global__ void k_cvtW(const float* __restrict__ W1, const float* __restrict__ W2,
                       const float* __restrict__ Wl1, short* __restrict__ W1T,
                       short* __restrict__ W2T, short* __restrict__ Wl1T) {
  int b = blockIdx.x, t = threadIdx.x;
  if (b < 256)       W1T[b * 256 + t]        = f2bf(W1[t * 256 + b]);
  else if (b < 512){ int n = b - 256; W2T[n * 256 + t]  = f2bf(W2[t * 256 + n]); }
  else             { int n = b - 512; Wl1T[n * 256 + t] = f2bf(Wl1[t * 128 + n]); }
}

// ---- x (f32) -> quantized gather copy ----
#if HAVE_FP8_CVT
__global__ void k_cvtX(const float* __restrict__ x, void* __restrict__ xq) {
  int c = blockIdx.x * 256 + threadIdx.x;  // 3.2M chunks of 8, grid exact
  float4 a = ((const float4*)x)[2 * (size_t)c];
  float4 b = ((const float4*)x)[2 * (size_t)c + 1];
  int p0 = 0, p1 = 0;
  p0 = __builtin_amdgcn_cvt_pk_fp8_f32(a.x, a.y, p0, false);
  p0 = __builtin_amdgcn_cvt_pk_fp8_f32(a.z, a.w, p0, true);
  p1 = __builtin_amdgcn_cvt_pk_fp8_f32(b.x, b.y, p1, false);
  p1 = __builtin_amdgcn_cvt_pk_fp8_f32(b.z, b.w, p1, true);
  ((int2*)xq)[c] = make_int2(p0, p1);
}
#else
__global__ void k_cvtX(const float* __restrict__ x, void* __restrict__ xq) {
  int c = blockIdx.x * 256 + threadIdx.x;
  float4 a = ((const float4*)x)[2 * (size_t)c];
  float4 b = ((const float4*)x)[2 * (size_t)c + 1];
  bf16x8 o;
  o[0] = f2bf(a.x); o[1] = f2bf(a.y); o[2] = f2bf(a.z); o[3] = f2bf(a.w);
  o[4] = f2bf(b.x); o[5] = f2bf(b.y); o[6] = f2bf(b.z); o[7] = f2bf(b.w);
  ((bf16x8*)xq)[c] = o;
}
#endif

// ---- pass 1: per-block bucket histogram (no global atomics) ----
__global__ __launch_bounds__(1024) void k_count(const int* __restrict__ ew,
                                                const int* __restrict__ flag,
                                                int* __restrict__ cntmat) {
  __shared__ int lcnt[NBUCK];
  int m64 = *flag;
  int t = threadIdx.x;
  for (int i = t; i < NBUCK; i += 1024) lcnt[i] = 0;
  __syncthreads();
  int base = blockIdx.x * 16384;
#pragma unroll
  for (int u = 0; u < 16; u++) {
    int e = base + u * 1024 + t;
    if (e < NE) {
      int d = m64 ? ew[2 * (NE + e)] : ew[NE + e];
      atomicAdd(&lcnt[d >> 7], 1);
    }
  }
  __syncthreads();
  for (int i = t; i < NBUCK; i += 1024) cntmat[blockIdx.x * NBUCK + i] = lcnt[i];
}

// ---- pass 2: column scan -> per-(block,bucket) bases + bucket bases ----
__global__ __launch_bounds__(1024) void k_colscan(int* __restrict__ cntmat,
                                                  int* __restrict__ bases,
                                                  int* __restrict__ off_) {
  __shared__ int tot[1024];
  int t = threadIdx.x;
  int sum = 0;
  if (t < NBUCK) {
    for (int g = 0; g < CGRID; g++) sum += cntmat[g * NBUCK + t];
    tot[t] = sum;
  }
  __syncthreads();
  int v = (t < NBUCK) ? sum : 0;
  for (int o = 1; o < 1024; o <<= 1) {
    int u = (t >= o && t < NBUCK) ? tot[t - o] : 0;
    __syncthreads();
    if (t < NBUCK) tot[t] += u;
    __syncthreads();
  }
  if (t < NBUCK) {
    int b = tot[t] - v;  // exclusive
    bases[t] = b;
    int run = b;
    for (int g = 0; g < CGRID; g++) {
      int c = cntmat[g * NBUCK + t];
      cntmat[g * NBUCK + t] = run;
      run += c;
    }
  }
  if (t == NBUCK) bases[NBUCK] = NE;
  if (t == NBUCK + 1) off_[NN] = NE;
}

// ---- pass 3: dense bucketed scatter of packed (src | ld<<17) ----
__global__ __launch_bounds__(1024) void k_scatter(const int* __restrict__ ew,
                                                  const int* __restrict__ flag,
                                                  const int* __restrict__ cntmat,
                                                  int* __restrict__ pairs) {
  __shared__ int lcur[NBUCK];
  int m64 = *flag;
  int t = threadIdx.x;
  for (int i = t; i < NBUCK; i += 1024) lcur[i] = cntmat[blockIdx.x * NBUCK + i];
  __syncthreads();
  int base = blockIdx.x * 16384;
#pragma unroll
  for (int u = 0; u < 16; u++) {
    int e = base + u * 1024 + t;
    if (e < NE) {
      int d = m64 ? ew[2 * (NE + e)] : ew[NE + e];
      int s = m64 ? ew[2 * e] : ew[e];
      int slot = atomicAdd(&lcur[d >> 7], 1);
      pairs[slot] = s | ((d & 127) << 17);
    }
  }
}

// ---- pass 4: per-bucket counting sort in LDS -> off_ + csr ----
__global__ __launch_bounds__(256) void k_bsort(const int* __restrict__ pairs,
                                               const int* __restrict__ bases,
                                               int* __restrict__ off_,
                                               int* __restrict__ csr) {
  __shared__ int lcnt[128], lofs[128], lcur[128];
  int b = blockIdx.x, t = threadIdx.x;
  int s0 = bases[b], s1 = bases[b + 1];
  if (t < 128) lcnt[t] = 0;
  __syncthreads();
  for (int j = s0 + t; j < s1; j += 256) atomicAdd(&lcnt[(pairs[j] >> 17) & 127], 1);
  __syncthreads();
  int v = (t < 128) ? lcnt[t] : 0;
  if (t < 128) lofs[t] = v;
  __syncthreads();
  for (int o = 1; o < 128; o <<= 1) {
    int u = (t >= o && t < 128) ? lofs[t - o] : 0;
    __syncthreads();
    if (t < 128) lofs[t] += u;
    __syncthreads();
  }
  if (t < 128) {
    int ex = lofs[t] - v;  // exclusive
    lcur[t] = ex;
    int node = b * 128 + t;
    if (node < NN) off_[node] = s0 + ex;
  }
  __syncthreads();
  for (int j = s0 + t; j < s1; j += 256) {
    int p = pairs[j];
    int slot = atomicAdd(&lcur[(p >> 17) & 127], 1);
    csr[s0 + slot] = p & 0x1FFFF;
  }
}

// one WAVE per node, lane owns 4 columns, 8-deep load ILP
#if HAVE_FP8_CVT
__global__ __launch_bounds__(256) void k_agg2(const void* __restrict__ xq,
                                              const int* __restrict__ off_,
                                              const int* __restrict__ csr,
                                              short* __restrict__ h0) {
  int node = blockIdx.x * 4 + (threadIdx.x >> 6);  // grid 25000 exact
  int lane = threadIdx.x & 63;
  const unsigned char* xb = (const unsigned char*)xq;
  size_t boff = (size_t)lane * 4;  // byte offset within 256B row
  int s0 = off_[node], s1 = off_[node + 1];
  int sw = *(const int*)(xb + (size_t)node * 256 + boff);
  f32x2 slo = __builtin_amdgcn_cvt_pk_f32_fp8(sw, false);
  f32x2 shi = __builtin_amdgcn_cvt_pk_f32_fp8(sw, true);
  float a0 = slo[0], a1 = slo[1], a2 = shi[0], a3 = shi[1];
  int j = s0;
  while (j + 8 <= s1) {
    int idx[8];
#pragma unroll
    for (int u = 0; u < 8; u++) idx[u] = csr[j + u];
    int w[8];
#pragma unroll
    for (int u = 0; u < 8; u++) w[u] = *(const int*)(xb + (size_t)idx[u] * 256 + boff);
#pragma unroll
    for (int u = 0; u < 8; u++) {
      f32x2 lo = __builtin_amdgcn_cvt_pk_f32_fp8(w[u], false);
      f32x2 hi = __builtin_amdgcn_cvt_pk_f32_fp8(w[u], true);
      a0 += lo[0]; a1 += lo[1]; a2 += hi[0]; a3 += hi[1];
    }
    j += 8;
  }
  if (j + 4 <= s1) {
    int idx[4];
#pragma unroll
    for (int u = 0; u < 4; u++) idx[u] = csr[j + u];
    int w[4];
#pragma unroll
    for (int u = 0; u < 4; u++) w[u] = *(const int*)(xb + (size_t)idx[u] * 256 + boff);
#pragma unroll
    for (int u = 0; u < 4; u++) {
      f32x2 lo = __builtin_amdgcn_cvt_pk_f32_fp8(w[u], false);
      f32x2 hi = __builtin_amdgcn_cvt_pk_f32_fp8(w[u], true);
      a0 += lo[0]; a1 += lo[1]; a2 += hi[0]; a3 += hi[1];
    }
    j += 4;
  }
  for (; j < s1; j++) {
    int s = csr[j];
    int w = *(const int*)(xb + (size_t)s * 256 + boff);
    f32x2 lo = __builtin_amdgcn_cvt_pk_f32_fp8(w, false);
    f32x2 hi = __builtin_amdgcn_cvt_pk_f32_fp8(w, true);
    a0 += lo[0]; a1 += lo[1]; a2 += hi[0]; a3 += hi[1];
  }
  ushort4 o;
  o.x = (ushort)f2bf(a0); o.y = (ushort)f2bf(a1);
  o.z = (ushort)f2bf(a2); o.w = (ushort)f2bf(a3);
  *(ushort4*)((ushort*)h0 + (size_t)node * 256 + (size_t)lane * 4) = o;
}
#else
__global__ __launch_bounds__(256) void k_agg2(const void* __restrict__ xq,
                                              const int* __restrict__ off_,
                                              const int* __restrict__ csr,
                                              short* __restrict__ h0) {
  int node = blockIdx.x * 4 + (threadIdx.x >> 6);
  int lane = threadIdx.x & 63;
  const ushort* xu = (const ushort*)xq;
  size_t coff = (size_t)lane * 4;
  int s0 = off_[node], s1 = off_[node + 1];
  ushort4 sv = *(const ushort4*)(xu + (size_t)node * 256 + coff);
  float a0 = bf2f(sv.x), a1 = bf2f(sv.y), a2 = bf2f(sv.z), a3 = bf2f(sv.w);
  int j = s0;
  while (j + 8 <= s1) {
    int idx[8];
#pragma unroll
    for (int u = 0; u < 8; u++) idx[u] = csr[j + u];
    ushort4 v[8];
#pragma unroll
    for (int u = 0; u < 8; u++) v[u] = *(const ushort4*)(xu + (size_t)idx[u] * 256 + coff);
#pragma unroll
    for (int u = 0; u < 8; u++) {
      a0 += bf2f(v[u].x); a1 += bf2f(v[u].y);
      a2 += bf2f(v[u].z); a3 += bf2f(v[u].w);
    }
    j += 8;
  }
  for (; j < s1; j++) {
    int s = csr[j];
    ushort4 v = *(const ushort4*)(xu + (size_t)s * 256 + coff);
    a0 += bf2f(v.x); a1 += bf2f(v.y); a2 += bf2f(v.z); a3 += bf2f(v.w);
  }
  ushort4 o;
  o.x = (ushort)f2bf(a0); o.y = (ushort)f2bf(a1);
  o.z = (ushort)f2bf(a2); o.w = (ushort)f2bf(a3);
  *(ushort4*)((ushort*)h0 + (size_t)node * 256 + coff) = o;
}
#endif

// ============================================================================
// MFMA GEMM, 128x128 tile, BK=64, double-buffered, XOR-swizzled LDS,
// global_load_lds staging, coalesced C-store via padded LDS bounce.
// A[M x 256] bf16, BT[256][256] bf16 (rows are output cols). TIN=1: A' =
// relu(bn(A)) applied during reg-staging. STATS: per-column sum/ssq of output.
// LDS swizzle invariant: logical k-slot s (16B, 8 elems) of row r lives at
// physical slot s ^ (r&7); applied identically on stage-source and ds_read.
// ============================================================================
template <int ACT, int TIN, int STATS>
__global__ __launch_bounds__(256, 2) void k_gemm(const short* __restrict__ A,
                                              const short* __restrict__ BT,
                                              const float* __restrict__ bias,
                                              short* __restrict__ C, int M,
                                              const float* __restrict__ tsc,
                                              const float* __restrict__ tsh,
                                              float* __restrict__ gsum,
                                              float* __restrict__ gssq) {
  __shared__ char smem[65536];               // 2 x (A 16KB + B 16KB); epilogue bounce overlays
  __shared__ float lsc[256], lsh[256];
  __shared__ float lsum[128], lssq[128];
  int tid = threadIdx.x;
  int lane = tid & 63, w = tid >> 6;
  if (TIN) { lsc[tid] = tsc[tid]; lsh[tid] = tsh[tid]; }
  if (STATS && tid < 128) { lsum[tid] = 0.f; lssq[tid] = 0.f; }
  int bm = blockIdx.x >> 1, bn = blockIdx.x & 1;
  int bm0 = bm * 128, bn0 = bn * 128;
  int wm = w >> 1, wn = w & 1;
  int lr = lane & 15, lg = lane >> 4;
  f32x4 acc[4][4] = {};
  __syncthreads();  // lsc/lsh visible before any TIN transform

  bf16x8 stg[4];  // TIN reg-staging

  // K-loop: 4 steps of BK=64, 2-phase (stage next, compute current, barrier)
#pragma unroll 1
  for (int it = 0; it < 4; ++it) {
    int b = it & 1;
    if (it == 0) {
      // prologue: stage buf0 @ kt=0
      if (TIN) {
#pragma unroll
        for (int i = 0; i < 4; ++i) {
          int p = tid + 256 * i, row = p >> 3, s = (p & 7) ^ (row & 7);
          int grow = bm0 + row; if (grow > M - 1) grow = M - 1;
          stg[i] = *(const bf16x8*)(A + (size_t)grow * 256 + s * 8);
        }
      } else {
#pragma unroll
        for (int q = 0; q < 4; ++q) {
          int wc = w * 4 + q;
          int p = wc * 64 + lane, row = p >> 3, s = (p & 7) ^ (row & 7);
          int grow = bm0 + row; if (grow > M - 1) grow = M - 1;
          gload16(A + (size_t)grow * 256 + s * 8, smem + wc * 1024);
        }
      }
#pragma unroll
      for (int q = 0; q < 4; ++q) {
        int wc = w * 4 + q;
        int p = wc * 64 + lane, row = p >> 3, s = (p & 7) ^ (row & 7);
        gload16(BT + (size_t)(bn0 + row) * 256 + s * 8, smem + 16384 + wc * 1024);
      }
      if (TIN) {
#pragma unroll
        for (int i = 0; i < 4; ++i) {
          int p = tid + 256 * i, row = p >> 3, s = (p & 7) ^ (row & 7);
          int k0 = s * 8;
          float4 sc0 = *(const float4*)&lsc[k0], sc1 = *(const float4*)&lsc[k0 + 4];
          float4 sh0 = *(const float4*)&lsh[k0], sh1 = *(const float4*)&lsh[k0 + 4];
          bf16x8 v = stg[i], o;
          o[0] = f2bf(fmaxf(bf2f((unsigned short)v[0]) * sc0.x + sh0.x, 0.f));
          o[1] = f2bf(fmaxf(bf2f((unsigned short)v[1]) * sc0.y + sh0.y, 0.f));
          o[2] = f2bf(fmaxf(bf2f((unsigned short)v[2]) * sc0.z + sh0.z, 0.f));
          o[3] = f2bf(fmaxf(bf2f((unsigned short)v[3]) * sc0.w + sh0.w, 0.f));
          o[4] = f2bf(fmaxf(bf2f((unsigned short)v[4]) * sc1.x + sh1.x, 0.f));
          o[5] = f2bf(fmaxf(bf2f((unsigned short)v[5]) * sc1.y + sh1.y, 0.f));
          o[6] = f2bf(fmaxf(bf2f((unsigned short)v[6]) * sc1.z + sh1.z, 0.f));
          o[7] = f2bf(fmaxf(bf2f((unsigned short)v[7]) * sc1.w + sh1.w, 0.f));
          *(bf16x8*)(smem + p * 16) = o;
        }
      }
      __syncthreads();
    }
    int ktn = (it + 1) * 64;
    if (it < 3) {
      // issue next-buffer staging (overlaps with MFMA below; drained at barrier)
      char* nb = smem + (b ^ 1) * 32768;
      if (TIN) {
#pragma unroll
        for (int i = 0; i < 4; ++i) {
          int p = tid + 256 * i, row = p >> 3, s = (p & 7) ^ (row & 7);
          int grow = bm0 + row; if (grow > M - 1) grow = M - 1;
          stg[i] = *(const bf16x8*)(A + (size_t)grow * 256 + ktn + s * 8);
        }
      } else {
#pragma unroll
        for (int q = 0; q < 4; ++q) {
          int wc = w * 4 + q;
          int p = wc * 64 + lane, row = p >> 3, s = (p & 7) ^ (row & 7);
          int grow = bm0 + row; if (grow > M - 1) grow = M - 1;
          gload16(A + (size_t)grow * 256 + ktn + s * 8, nb + wc * 1024);
        }
      }
#pragma unroll
      for (int q = 0; q < 4; ++q) {
        int wc = w * 4 + q;
        int p = wc * 64 + lane, row = p >> 3, s = (p & 7) ^ (row & 7);
        gload16(BT + (size_t)(bn0 + row) * 256 + ktn + s * 8, nb + 16384 + wc * 1024);
      }
    }
    // compute current buffer
    const char* sa = smem + b * 32768;
    const char* sb = sa + 16384;
#pragma unroll
    for (int ks = 0; ks < 2; ++ks) {
      bf16x8 af[4], bfr[4];
#pragma unroll
      for (int mi = 0; mi < 4; ++mi) {
        int row = wm * 64 + mi * 16 + lr;
        int q = (lg + 4 * ks) ^ (row & 7);
        af[mi] = *(const bf16x8*)(sa + row * 128 + q * 16);
      }
#pragma unroll
      for (int ni = 0; ni < 4; ++ni) {
        int row = wn * 64 + ni * 16 + lr;
        int q = (lg + 4 * ks) ^ (row & 7);
        bfr[ni] = *(const bf16x8*)(sb + row * 128 + q * 16);
      }
#pragma unroll
      for (int mi = 0; mi < 4; ++mi)
#pragma unroll
        for (int ni = 0; ni < 4; ++ni)
          acc[mi][ni] = __builtin_amdgcn_mfma_f32_16x16x32_bf16(af[mi], bfr[ni], acc[mi][ni], 0, 0, 0);
    }
    if (TIN && it < 3) {
      // transform + LDS write after MFMA (loads have landed by now)
      char* nb = smem + (b ^ 1) * 32768;
#pragma unroll
      for (int i = 0; i < 4; ++i) {
        int p = tid + 256 * i, row = p >> 3, s = (p & 7) ^ (row & 7);
        int k0 = ktn + s * 8;
        float4 sc0 = *(const float4*)&lsc[k0], sc1 = *(const float4*)&lsc[k0 + 4];
        float4 sh0 = *(const float4*)&lsh[k0], sh1 = *(const float4*)&lsh[k0 + 4];
        bf16x8 v = stg[i], o;
        o[0] = f2bf(fmaxf(bf2f((unsigned short)v[0]) * sc0.x + sh0.x, 0.f));
        o[1] = f2bf(fmaxf(bf2f((unsigned short)v[1]) * sc0.y + sh0.y, 0.f));
        o[2] = f2bf(fmaxf(bf2f((unsigned short)v[2]) * sc0.z + sh0.z, 0.f));
        o[3] = f2bf(fmaxf(bf2f((unsigned short)v[3]) * sc0.w + sh0.w, 0.f));
        o[4] = f2bf(fmaxf(bf2f((unsigned short)v[4]) * sc1.x + sh1.x, 0.f));
        o[5] = f2bf(fmaxf(bf2f((unsigned short)v[5]) * sc1.y + sh1.y, 0.f));
        o[6] = f2bf(fmaxf(bf2f((unsigned short)v[6]) * sc1.z + sh1.z, 0.f));
        o[7] = f2bf(fmaxf(bf2f((unsigned short)v[7]) * sc1.w + sh1.w, 0.f));
        *(bf16x8*)(nb + p * 16) = o;
      }
    }
    __syncthreads();  // drains vmcnt+lgkmcnt: next buf fully staged; this buf's reads done
  }

  // ---- epilogue: bias+act, stats, bounce to padded LDS, coalesced store ----
  short* zs = (short*)smem;  // [128][136] bf16 (stride 272B breaks bank aliasing)
#pragma unroll
  for (int ni = 0; ni < 4; ++ni) {
    int col = wn * 64 + ni * 16 + lr;
    float bv = bias[bn0 + col];
    float ps = 0.f, pq = 0.f;
#pragma unroll
    for (int mi = 0; mi < 4; ++mi) {
#pragma unroll
      for (int r = 0; r < 4; ++r) {
        int row = wm * 64 + mi * 16 + lg * 4 + r;
        float tv = acc[mi][ni][r] + bv;
        if (ACT == 1) tv = tv > 0.f ? tv : 0.01f * tv;  // lrelu(lrelu(t,0.1),0.1)
        if (STATS && (bm0 + row) < M) { ps += tv; pq += tv * tv; }
        zs[row * 136 + col] = f2bf(tv);
      }
    }
    if (STATS) {
      ps += __shfl_xor(ps, 16); pq += __shfl_xor(pq, 16);
      ps += __shfl_xor(ps, 32); pq += __shfl_xor(pq, 32);
      if (lane < 16) {
        atomicAdd(&lsum[wn * 64 + ni * 16 + lane], ps);
        atomicAdd(&lssq[wn * 64 + ni * 16 + lane], pq);
      }
    }
  }
  __syncthreads();
  {
    int row = tid >> 1;
    int grow = bm0 + row;
    if (grow < M) {
#pragma unroll
      for (int i = 0; i < 8; ++i) {
        int cs = (tid & 1) * 8 + i;
        bf16x8 v = *(const bf16x8*)((const char*)zs + row * 272 + cs * 16);
        *(bf16x8*)(C + (size_t)grow * 256 + bn0 + cs * 8) = v;
      }
    }
  }
  if (STATS) {
    if (tid < 128) {
      atomicAdd(&gsum[bn0 + tid], lsum[tid]);
      atomicAdd(&gssq[bn0 + tid], lssq[tid]);
    }
  }
}

__global__ void k_bnprep(const float* __restrict__ sum, const float* __restrict__ ssq,
                         const float* __restrict__ g, const float* __restrict__ be,
                         float* __restrict__ scale, float* __restrict__ shift, int M) {
  int c = threadIdx.x;
  float mu = sum[c] / (float)M;
  float var = ssq[c] / (float)M - mu * mu;
  float rs = rsqrtf(var + 1e-5f);
  float sc = g[c] * rs;
  scale[c] = sc;
  shift[c] = be[c] - mu * sc;
}

// head with fused elem2 on A-staging:
//   A' = bf16( x + 0.01 * lrelu(bn4(V)) );  z = lrelu(A' @ Wl1 + bl1);  out = z @ Wl3 + bl3
__global__ __launch_bounds__(256) void k_head(const short* __restrict__ V,
                                              const float* __restrict__ x,
                                              const short* __restrict__ BT,
                                              const float* __restrict__ bl1,
                                              const float* __restrict__ Wl3,
                                              const float* __restrict__ bl3,
                                              const float* __restrict__ tsc,
                                              const float* __restrict__ tsh,
                                              float* __restrict__ out, int M) {
  __shared__ char smem[128 * 140 * 2 + 1280 * 4];  // z(bf16, stride 140) + wl3(f32)
  __shared__ float lsc[256], lsh[256];
  short* zs  = (short*)smem;
  float* wl3 = (float*)(smem + 128 * 140 * 2);
  short* ldsA = (short*)smem;          // staging aliases z region (dead until after K loop)
  short* ldsB = (short*)smem + 4096;
  int tid = threadIdx.x;
  for (int i = tid; i < 1280; i += 256) wl3[i] = Wl3[i];
  lsc[tid] = tsc[tid]; lsh[tid] = tsh[tid];
  __syncthreads();
  int bm0 = blockIdx.x * 128;
  int lane = tid & 63, w = tid >> 6;
  int wm = w >> 1, wn = w & 1;
  int lr = lane & 15, lg = lane >> 4;
  f32x4 acc[4][4] = {};
  for (int kt = 0; kt < 256; kt += 32) {
#pragma unroll
    for (int c = 0; c < 2; c++) {
      int chunk = c * 256 + tid;
      int row = chunk >> 2;
      int kc = (chunk & 3) * 8;
      int rA = bm0 + row; if (rA > M - 1) rA = M - 1;
      bf16x8 va = *(const bf16x8*)(V + (size_t)rA * 256 + kt + kc);
      float4 x0 = *(const float4*)(x + (size_t)rA * 256 + kt + kc);
      float4 x1 = *(const float4*)(x + (size_t)rA * 256 + kt + kc + 4);
      float xs[8] = {x0.x, x0.y, x0.z, x0.w, x1.x, x1.y, x1.z, x1.w};
      bf16x8 tt;
#pragma unroll
      for (int jj = 0; jj < 8; jj++) {
        float f = bf2f((unsigned short)va[jj]) * lsc[kt + kc + jj] + lsh[kt + kc + jj];
        f = f > 0.f ? f : 0.1f * f;
        tt[jj] = f2bf(xs[jj] + 0.01f * f);
      }
      *((bf16x8*)ldsA + chunk) = tt;
      *((bf16x8*)ldsB + chunk) = *(const bf16x8*)(BT + (size_t)row * 256 + kt + kc);
    }
    __syncthreads();
    bf16x8 af[4], bfr[4];
#pragma unroll
    for (int mi = 0; mi < 4; mi++) af[mi] = *((const bf16x8*)ldsA + ((wm * 64 + mi * 16 + lr) * 4 + lg));
#pragma unroll
    for (int ni = 0; ni < 4; ni++) bfr[ni] = *((const bf16x8*)ldsB + ((wn * 64 + ni * 16 + lr) * 4 + lg));
#pragma unroll
    for (int mi = 0; mi < 4; mi++)
#pragma unroll
      for (int ni = 0; ni < 4; ni++)
        acc[mi][ni] = __builtin_amdgcn_mfma_f32_16x16x32_bf16(af[mi], bfr[ni], acc[mi][ni], 0, 0, 0);
    __syncthreads();
  }
#pragma unroll
  for (int ni = 0; ni < 4; ni++) {
    int col = wn * 64 + ni * 16 + lr;
    float bv = bl1[col];
#pragma unroll
    for (int mi = 0; mi < 4; mi++) {
#pragma unroll
      for (int r = 0; r < 4; r++) {
        int rl = wm * 64 + mi * 16 + lg * 4 + r;
        float tv = acc[mi][ni][r] + bv;
        tv = tv > 0.f ? tv : 0.1f * tv;
        zs[rl * 140 + col] = f2bf(tv);
      }
    }
  }
  __syncthreads();
  int r = tid >> 1, ch = tid & 1;
  float av[5];
#pragma unroll
  for (int c = 0; c < 5; c++) av[c] = bl3[ch * 5 + c];
  for (int k = 0; k < 128; k++) {
    float zv = bf2f((unsigned short)zs[r * 140 + k]);
#pragma unroll
    for (int c = 0; c < 5; c++) av[c] += zv * wl3[k * 10 + ch * 5 + c];
  }
  int grow = bm0 + r;
  if (grow < M) {
#pragma unroll
    for (int c = 0; c < 5; c++) out[(size_t)grow * 10 + ch * 5 + c] = av[c];
  }
}

extern "C" void kernel_launch(void* const* d_in, const int* in_sizes, int n_in,
                              void* d_out, int out_size, void* d_ws, size_t ws_size,
                              hipStream_t stream) {
  const float* x   = (const float*)d_in[0];
  const int*   ew  = (const int*)d_in[1];
  const float* W1  = (const float*)d_in[2];
  const float* b1  = (const float*)d_in[3];
  const float* g1  = (const float*)d_in[4];
  const float* be1 = (const float*)d_in[5];
  const float* W2  = (const float*)d_in[6];
  const float* b2  = (const float*)d_in[7];
  const float* g4  = (const float*)d_in[8];
  const float* be4 = (const float*)d_in[9];
  const float* Wl1 = (const float*)d_in[10];
  const float* bl1 = (const float*)d_in[11];
  const float* Wl3 = (const float*)d_in[12];
  const float* bl3 = (const float*)d_in[13];
  float* out = (float*)d_out;

  char* ws = (char*)d_ws;
  const size_t OFF_OFF  = 0;          // (N+1) ints
  const size_t OFF_BASES= 400128;     // NBUCK+1 ints
  const size_t OFF_CNT  = 800256;     // CGRID x NBUCK ints (306KB)
  const size_t OFF_STATS= 1200384;    // 4x256 f32 (sum1,ssq1,sum4,ssq4) -- memset
  const size_t OFF_BN   = 1204480;    // 4x256 f32 (sc1,sh1,sc4,sh4)
  const size_t OFF_FLAG = 1208576;
  const size_t OFF_W1T  = 1209216;
  const size_t OFF_W2T  = 1340288;
  const size_t OFF_WL1T = 1471360;
  const size_t OFF_CSR  = 1536896;    // NE ints (6.4MB)
  const size_t OFF_BUFA = 7936896;    // 51.2MB ; pairs (6.4MB) aliases this
  const size_t OFF_BUFB = 59136896;   // xq aliases bufB (xq dead before GEMM1 writes bufB)
  if (ws_size < 110336896) return;

  int* off_  = (int*)(ws + OFF_OFF);
  int* bases_= (int*)(ws + OFF_BASES);
  int* cnt_  = (int*)(ws + OFF_CNT);
  float* sum1 = (float*)(ws + OFF_STATS);
  float* ssq1 = sum1 + 256;
  float* sum4 = sum1 + 512;
  float* ssq4 = sum1 + 768;
  float* sc1 = (float*)(ws + OFF_BN);
  float* sh1 = sc1 + 256;
  float* sc4 = sc1 + 512;
  float* sh4 = sc1 + 768;
  int* flag_ = (int*)(ws + OFF_FLAG);
  short* W1T  = (short*)(ws + OFF_W1T);
  short* W2T  = (short*)(ws + OFF_W2T);
  short* Wl1T = (short*)(ws + OFF_WL1T);
  int* csr_   = (int*)(ws + OFF_CSR);
  short* bufA = (short*)(ws + OFF_BUFA);
  short* bufB = (short*)(ws + OFF_BUFB);
  int* pairs_ = (int*)(ws + OFF_BUFA);  // alias: dead before k_agg2 writes bufA
  void* xq    = (void*)bufB;            // alias: dead before GEMM1 writes bufB

  hipMemsetAsync(ws + OFF_STATS, 0, 4096, stream);
  k_detect<<<1, 256, 0, stream>>>(ew, flag_);
  k_cvtW<<<640, 256, 0, stream>>>(W1, W2, Wl1, W1T, W2T, Wl1T);
  k_cvtX<<<12500, 256, 0, stream>>>(x, xq);
  k_count<<<CGRID, 1024, 0, stream>>>(ew, flag_, cnt_);
  k_colscan<<<1, 1024, 0, stream>>>(cnt_, bases_, off_);
  k_scatter<<<CGRID, 1024, 0, stream>>>(ew, flag_, cnt_, pairs_);
  k_bsort<<<NBUCK, 256, 0, stream>>>(pairs_, bases_, off_, csr_);
  k_agg2<<<25000, 256, 0, stream>>>(xq, off_, csr_, bufA);
  k_gemm<0, 0, 1><<<1564, 256, 0, stream>>>(bufA, W1T, b1, bufB, NN,
                                            nullptr, nullptr, sum1, ssq1);
  k_bnprep<<<1, 256, 0, stream>>>(sum1, ssq1, g1, be1, sc1, sh1, NN);
  k_gemm<1, 1, 1><<<1564, 256, 0, stream>>>(bufB, W2T, b2, bufA, NN,
                                            sc1, sh1, sum4, ssq4);
  k_bnprep<<<1, 256, 0, stream>>>(sum4, ssq4, g4, be4, sc4, sh4, NN);
  k_head<<<782, 256, 0, stream>>>(bufA, x, Wl1T, bl1, Wl3, bl3, sc4, sh4, out, NN);
}

// Round 6
// 300.436 us; speedup vs baseline: 2.9172x; 1.0114x over previous
//
#include <hip/hip_runtime.h>

constexpr int NN = 100000;   // nodes
constexpr int NE = 1600000;  // edges
constexpr int HD = 256;      // hidden
constexpr int NBUCK = 782;   // ceil(NN/128)
constexpr int CGRID = 98;    // count/scatter blocks (98*16384 >= NE)

typedef __attribute__((ext_vector_type(4))) float  f32x4;
typedef __attribute__((ext_vector_type(2))) float  f32x2;
typedef __attribute__((ext_vector_type(8))) short  bf16x8;

#if defined(__has_builtin)
#if __has_builtin(__builtin_amdgcn_cvt_pk_f32_fp8) && __has_builtin(__builtin_amdgcn_cvt_pk_fp8_f32)
#define HAVE_FP8_CVT 1
#endif
#endif
#ifndef HAVE_FP8_CVT
#define HAVE_FP8_CVT 0
#endif

__device__ __forceinline__ float bf2f(unsigned short u) {
  union { unsigned int i; float f; } c;
  c.i = ((unsigned int)u) << 16;
  return c.f;
}
__device__ __forceinline__ short f2bf(float f) {
  union { float f; unsigned int i; } c; c.f = f;
  unsigned int i = c.i + 0x7fffu + ((c.i >> 16) & 1u);
  return (short)(i >> 16);
}

// async global->LDS, 16B per lane; LDS dest is wave-uniform base + lane*16
__device__ __forceinline__ void gload16(const void* g, void* l) {
  __builtin_amdgcn_global_load_lds(
      (const __attribute__((address_space(1))) unsigned int*)g,
      (__attribute__((address_space(3))) unsigned int*)l, 16, 0, 0);
}

// ---- edge dtype detection: int64 -> all odd 32-bit words (high words) are 0 ----
__global__ void k_detect(const int* __restrict__ ew, int* __restrict__ flag) {
  __shared__ int bad;
  if (threadIdx.x == 0) bad = 0;
  __syncthreads();
  int nz = 0;
  for (int i = threadIdx.x; i < 2048; i += 256) nz |= ew[2 * i + 1];
  if (nz) atomicOr(&bad, 1);
  __syncthreads();
  if (threadIdx.x == 0) *flag = (bad == 0) ? 1 : 0;
}

// ---- convert weights to bf16, transposed; Wl3 -> padded [16][128] bf16 ----
__global__ void k_cvtW(const float* __restrict__ W1, const float* __restrict__ W2,
                       const float* __restrict__ Wl1, const float* __restrict__ Wl3,
                       short* __restrict__ W1T, short* __restrict__ W2T,
                       short* __restrict__ Wl1T, short* __restrict__ Wl3T) {
  int b = blockIdx.x, t = threadIdx.x;
  if (b < 256)       W1T[b * 256 + t]        = f2bf(W1[t * 256 + b]);
  else if (b < 512){ int n = b - 256; W2T[n * 256 + t]  = f2bf(W2[t * 256 + n]); }
  else if (b < 640){ int n = b - 512; Wl1T[n * 256 + t] = f2bf(Wl1[t * 128 + n]); }
  else {
    if (t < 128) {
#pragma unroll
      for (int c = 0; c < 16; ++c)
        Wl3T[c * 128 + t] = (c < 10) ? f2bf(Wl3[t * 10 + c]) : (short)0;
    }
  }
}

// ---- x (f32) -> quantized gather copy ----
#if HAVE_FP8_CVT
__global__ void k_cvtX(const float* __restrict__ x, void* __restrict__ xq) {
  int c = blockIdx.x * 256 + threadIdx.x;  // 3.2M chunks of 8, grid exact
  float4 a = ((const float4*)x)[2 * (size_t)c];
  float4 b = ((const float4*)x)[2 * (size_t)c + 1];
  int p0 = 0, p1 = 0;
  p0 = __builtin_amdgcn_cvt_pk_fp8_f32(a.x, a.y, p0, false);
  p0 = __builtin_amdgcn_cvt_pk_fp8_f32(a.z, a.w, p0, true);
  p1 = __builtin_amdgcn_cvt_pk_fp8_f32(b.x, b.y, p1, false);
  p1 = __builtin_amdgcn_cvt_pk_fp8_f32(b.z, b.w, p1, true);
  ((int2*)xq)[c] = make_int2(p0, p1);
}
#else
__global__ void k_cvtX(const float* __restrict__ x, void* __restrict__ xq) {
  int c = blockIdx.x * 256 + threadIdx.x;
  float4 a = ((const float4*)x)[2 * (size_t)c];
  float4 b = ((const float4*)x)[2 * (size_t)c + 1];
  bf16x8 o;
  o[0] = f2bf(a.x); o[1] = f2bf(a.y); o[2] = f2bf(a.z); o[3] = f2bf(a.w);
  o[4] = f2bf(b.x); o[5] = f2bf(b.y); o[6] = f2bf(b.z); o[7] = f2bf(b.w);
  ((bf16x8*)xq)[c] = o;
}
#endif

// ---- pass 1: per-block bucket histogram (no global atomics) ----
__global__ __launch_bounds__(1024) void k_count(const int* __restrict__ ew,
                                                const int* __restrict__ flag,
                                                int* __restrict__ cntmat) {
  __shared__ int lcnt[NBUCK];
  int m64 = *flag;
  int t = threadIdx.x;
  for (int i = t; i < NBUCK; i += 1024) lcnt[i] = 0;
  __syncthreads();
  int base = blockIdx.x * 16384;
#pragma unroll
  for (int u = 0; u < 16; u++) {
    int e = base + u * 1024 + t;
    if (e < NE) {
      int d = m64 ? ew[2 * (NE + e)] : ew[NE + e];
      atomicAdd(&lcnt[d >> 7], 1);
    }
  }
  __syncthreads();
  for (int i = t; i < NBUCK; i += 1024) cntmat[blockIdx.x * NBUCK + i] = lcnt[i];
}

// ---- pass 2: column scan -> per-(block,bucket) bases + bucket bases ----
__global__ __launch_bounds__(1024) void k_colscan(int* __restrict__ cntmat,
                                                  int* __restrict__ bases,
                                                  int* __restrict__ off_) {
  __shared__ int tot[1024];
  int t = threadIdx.x;
  int sum = 0;
  if (t < NBUCK) {
    for (int g = 0; g < CGRID; g++) sum += cntmat[g * NBUCK + t];
    tot[t] = sum;
  }
  __syncthreads();
  int v = (t < NBUCK) ? sum : 0;
  for (int o = 1; o < 1024; o <<= 1) {
    int u = (t >= o && t < NBUCK) ? tot[t - o] : 0;
    __syncthreads();
    if (t < NBUCK) tot[t] += u;
    __syncthreads();
  }
  if (t < NBUCK) {
    int b = tot[t] - v;  // exclusive
    bases[t] = b;
    int run = b;
    for (int g = 0; g < CGRID; g++) {
      int c = cntmat[g * NBUCK + t];
      cntmat[g * NBUCK + t] = run;
      run += c;
    }
  }
  if (t == NBUCK) bases[NBUCK] = NE;
  if (t == NBUCK + 1) off_[NN] = NE;
}

// ---- pass 3: dense bucketed scatter of packed (src | ld<<17) ----
__global__ __launch_bounds__(1024) void k_scatter(const int* __restrict__ ew,
                                                  const int* __restrict__ flag,
                                                  const int* __restrict__ cntmat,
                                                  int* __restrict__ pairs) {
  __shared__ int lcur[NBUCK];
  int m64 = *flag;
  int t = threadIdx.x;
  for (int i = t; i < NBUCK; i += 1024) lcur[i] = cntmat[blockIdx.x * NBUCK + i];
  __syncthreads();
  int base = blockIdx.x * 16384;
#pragma unroll
  for (int u = 0; u < 16; u++) {
    int e = base + u * 1024 + t;
    if (e < NE) {
      int d = m64 ? ew[2 * (NE + e)] : ew[NE + e];
      int s = m64 ? ew[2 * e] : ew[e];
      int slot = atomicAdd(&lcur[d >> 7], 1);
      pairs[slot] = s | ((d & 127) << 17);
    }
  }
}

// ---- pass 4: per-bucket counting sort in LDS -> off_ + csr ----
__global__ __launch_bounds__(256) void k_bsort(const int* __restrict__ pairs,
                                               const int* __restrict__ bases,
                                               int* __restrict__ off_,
                                               int* __restrict__ csr) {
  __shared__ int lcnt[128], lofs[128], lcur[128];
  int b = blockIdx.x, t = threadIdx.x;
  int s0 = bases[b], s1 = bases[b + 1];
  if (t < 128) lcnt[t] = 0;
  __syncthreads();
  for (int j = s0 + t; j < s1; j += 256) atomicAdd(&lcnt[(pairs[j] >> 17) & 127], 1);
  __syncthreads();
  int v = (t < 128) ? lcnt[t] : 0;
  if (t < 128) lofs[t] = v;
  __syncthreads();
  for (int o = 1; o < 128; o <<= 1) {
    int u = (t >= o && t < 128) ? lofs[t - o] : 0;
    __syncthreads();
    if (t < 128) lofs[t] += u;
    __syncthreads();
  }
  if (t < 128) {
    int ex = lofs[t] - v;  // exclusive
    lcur[t] = ex;
    int node = b * 128 + t;
    if (node < NN) off_[node] = s0 + ex;
  }
  __syncthreads();
  for (int j = s0 + t; j < s1; j += 256) {
    int p = pairs[j];
    int slot = atomicAdd(&lcur[(p >> 17) & 127], 1);
    csr[s0 + slot] = p & 0x1FFFF;
  }
}

// one WAVE per node, lane owns 4 columns, 8-deep load ILP
#if HAVE_FP8_CVT
__global__ __launch_bounds__(256) void k_agg2(const void* __restrict__ xq,
                                              const int* __restrict__ off_,
                                              const int* __restrict__ csr,
                                              short* __restrict__ h0) {
  int node = blockIdx.x * 4 + (threadIdx.x >> 6);  // grid 25000 exact
  int lane = threadIdx.x & 63;
  const unsigned char* xb = (const unsigned char*)xq;
  size_t boff = (size_t)lane * 4;  // byte offset within 256B row
  int s0 = off_[node], s1 = off_[node + 1];
  int sw = *(const int*)(xb + (size_t)node * 256 + boff);
  f32x2 slo = __builtin_amdgcn_cvt_pk_f32_fp8(sw, false);
  f32x2 shi = __builtin_amdgcn_cvt_pk_f32_fp8(sw, true);
  float a0 = slo[0], a1 = slo[1], a2 = shi[0], a3 = shi[1];
  int j = s0;
  while (j + 8 <= s1) {
    int idx[8];
#pragma unroll
    for (int u = 0; u < 8; u++) idx[u] = csr[j + u];
    int w[8];
#pragma unroll
    for (int u = 0; u < 8; u++) w[u] = *(const int*)(xb + (size_t)idx[u] * 256 + boff);
#pragma unroll
    for (int u = 0; u < 8; u++) {
      f32x2 lo = __builtin_amdgcn_cvt_pk_f32_fp8(w[u], false);
      f32x2 hi = __builtin_amdgcn_cvt_pk_f32_fp8(w[u], true);
      a0 += lo[0]; a1 += lo[1]; a2 += hi[0]; a3 += hi[1];
    }
    j += 8;
  }
  if (j + 4 <= s1) {
    int idx[4];
#pragma unroll
    for (int u = 0; u < 4; u++) idx[u] = csr[j + u];
    int w[4];
#pragma unroll
    for (int u = 0; u < 4; u++) w[u] = *(const int*)(xb + (size_t)idx[u] * 256 + boff);
#pragma unroll
    for (int u = 0; u < 4; u++) {
      f32x2 lo = __builtin_amdgcn_cvt_pk_f32_fp8(w[u], false);
      f32x2 hi = __builtin_amdgcn_cvt_pk_f32_fp8(w[u], true);
      a0 += lo[0]; a1 += lo[1]; a2 += hi[0]; a3 += hi[1];
    }
    j += 4;
  }
  for (; j < s1; j++) {
    int s = csr[j];
    int w = *(const int*)(xb + (size_t)s * 256 + boff);
    f32x2 lo = __builtin_amdgcn_cvt_pk_f32_fp8(w, false);
    f32x2 hi = __builtin_amdgcn_cvt_pk_f32_fp8(w, true);
    a0 += lo[0]; a1 += lo[1]; a2 += hi[0]; a3 += hi[1];
  }
  ushort4 o;
  o.x = (ushort)f2bf(a0); o.y = (ushort)f2bf(a1);
  o.z = (ushort)f2bf(a2); o.w = (ushort)f2bf(a3);
  *(ushort4*)((ushort*)h0 + (size_t)node * 256 + (size_t)lane * 4) = o;
}
#else
__global__ __launch_bounds__(256) void k_agg2(const void* __restrict__ xq,
                                              const int* __restrict__ off_,
                                              const int* __restrict__ csr,
                                              short* __restrict__ h0) {
  int node = blockIdx.x * 4 + (threadIdx.x >> 6);
  int lane = threadIdx.x & 63;
  const ushort* xu = (const ushort*)xq;
  size_t coff = (size_t)lane * 4;
  int s0 = off_[node], s1 = off_[node + 1];
  ushort4 sv = *(const ushort4*)(xu + (size_t)node * 256 + coff);
  float a0 = bf2f(sv.x), a1 = bf2f(sv.y), a2 = bf2f(sv.z), a3 = bf2f(sv.w);
  int j = s0;
  while (j + 8 <= s1) {
    int idx[8];
#pragma unroll
    for (int u = 0; u < 8; u++) idx[u] = csr[j + u];
    ushort4 v[8];
#pragma unroll
    for (int u = 0; u < 8; u++) v[u] = *(const ushort4*)(xu + (size_t)idx[u] * 256 + coff);
#pragma unroll
    for (int u = 0; u < 8; u++) {
      a0 += bf2f(v[u].x); a1 += bf2f(v[u].y);
      a2 += bf2f(v[u].z); a3 += bf2f(v[u].w);
    }
    j += 8;
  }
  for (; j < s1; j++) {
    int s = csr[j];
    ushort4 v = *(const ushort4*)(xu + (size_t)s * 256 + coff);
    a0 += bf2f(v.x); a1 += bf2f(v.y); a2 += bf2f(v.z); a3 += bf2f(v.w);
  }
  ushort4 o;
  o.x = (ushort)f2bf(a0); o.y = (ushort)f2bf(a1);
  o.z = (ushort)f2bf(a2); o.w = (ushort)f2bf(a3);
  *(ushort4*)((ushort*)h0 + (size_t)node * 256 + coff) = o;
}
#endif

// ============================================================================
// MFMA GEMM, 128x128 tile, BK=64, double-buffered, XOR-swizzled LDS,
// global_load_lds staging, coalesced C-store via padded LDS bounce.
// ============================================================================
template <int ACT, int TIN, int STATS>
__global__ __launch_bounds__(256, 2) void k_gemm(const short* __restrict__ A,
                                              const short* __restrict__ BT,
                                              const float* __restrict__ bias,
                                              short* __restrict__ C, int M,
                                              const float* __restrict__ tsc,
                                              const float* __restrict__ tsh,
                                              float* __restrict__ gsum,
                                              float* __restrict__ gssq) {
  __shared__ char smem[65536];               // 2 x (A 16KB + B 16KB); epilogue bounce overlays
  __shared__ float lsc[256], lsh[256];
  __shared__ float lsum[128], lssq[128];
  int tid = threadIdx.x;
  int lane = tid & 63, w = tid >> 6;
  if (TIN) { lsc[tid] = tsc[tid]; lsh[tid] = tsh[tid]; }
  if (STATS && tid < 128) { lsum[tid] = 0.f; lssq[tid] = 0.f; }
  int bm = blockIdx.x >> 1, bn = blockIdx.x & 1;
  int bm0 = bm * 128, bn0 = bn * 128;
  int wm = w >> 1, wn = w & 1;
  int lr = lane & 15, lg = lane >> 4;
  f32x4 acc[4][4] = {};
  __syncthreads();  // lsc/lsh visible before any TIN transform

  bf16x8 stg[4];  // TIN reg-staging

#pragma unroll 1
  for (int it = 0; it < 4; ++it) {
    int b = it & 1;
    if (it == 0) {
      if (TIN) {
#pragma unroll
        for (int i = 0; i < 4; ++i) {
          int p = tid + 256 * i, row = p >> 3, s = (p & 7) ^ (row & 7);
          int grow = bm0 + row; if (grow > M - 1) grow = M - 1;
          stg[i] = *(const bf16x8*)(A + (size_t)grow * 256 + s * 8);
        }
      } else {
#pragma unroll
        for (int q = 0; q < 4; ++q) {
          int wc = w * 4 + q;
          int p = wc * 64 + lane, row = p >> 3, s = (p & 7) ^ (row & 7);
          int grow = bm0 + row; if (grow > M - 1) grow = M - 1;
          gload16(A + (size_t)grow * 256 + s * 8, smem + wc * 1024);
        }
      }
#pragma unroll
      for (int q = 0; q < 4; ++q) {
        int wc = w * 4 + q;
        int p = wc * 64 + lane, row = p >> 3, s = (p & 7) ^ (row & 7);
        gload16(BT + (size_t)(bn0 + row) * 256 + s * 8, smem + 16384 + wc * 1024);
      }
      if (TIN) {
#pragma unroll
        for (int i = 0; i < 4; ++i) {
          int p = tid + 256 * i, row = p >> 3, s = (p & 7) ^ (row & 7);
          int k0 = s * 8;
          float4 sc0 = *(const float4*)&lsc[k0], sc1 = *(const float4*)&lsc[k0 + 4];
          float4 sh0 = *(const float4*)&lsh[k0], sh1 = *(const float4*)&lsh[k0 + 4];
          bf16x8 v = stg[i], o;
          o[0] = f2bf(fmaxf(bf2f((unsigned short)v[0]) * sc0.x + sh0.x, 0.f));
          o[1] = f2bf(fmaxf(bf2f((unsigned short)v[1]) * sc0.y + sh0.y, 0.f));
          o[2] = f2bf(fmaxf(bf2f((unsigned short)v[2]) * sc0.z + sh0.z, 0.f));
          o[3] = f2bf(fmaxf(bf2f((unsigned short)v[3]) * sc0.w + sh0.w, 0.f));
          o[4] = f2bf(fmaxf(bf2f((unsigned short)v[4]) * sc1.x + sh1.x, 0.f));
          o[5] = f2bf(fmaxf(bf2f((unsigned short)v[5]) * sc1.y + sh1.y, 0.f));
          o[6] = f2bf(fmaxf(bf2f((unsigned short)v[6]) * sc1.z + sh1.z, 0.f));
          o[7] = f2bf(fmaxf(bf2f((unsigned short)v[7]) * sc1.w + sh1.w, 0.f));
          *(bf16x8*)(smem + p * 16) = o;
        }
      }
      __syncthreads();
    }
    int ktn = (it + 1) * 64;
    if (it < 3) {
      char* nb = smem + (b ^ 1) * 32768;
      if (TIN) {
#pragma unroll
        for (int i = 0; i < 4; ++i) {
          int p = tid + 256 * i, row = p >> 3, s = (p & 7) ^ (row & 7);
          int grow = bm0 + row; if (grow > M - 1) grow = M - 1;
          stg[i] = *(const bf16x8*)(A + (size_t)grow * 256 + ktn + s * 8);
        }
      } else {
#pragma unroll
        for (int q = 0; q < 4; ++q) {
          int wc = w * 4 + q;
          int p = wc * 64 + lane, row = p >> 3, s = (p & 7) ^ (row & 7);
          int grow = bm0 + row; if (grow > M - 1) grow = M - 1;
          gload16(A + (size_t)grow * 256 + ktn + s * 8, nb + wc * 1024);
        }
      }
#pragma unroll
      for (int q = 0; q < 4; ++q) {
        int wc = w * 4 + q;
        int p = wc * 64 + lane, row = p >> 3, s = (p & 7) ^ (row & 7);
        gload16(BT + (size_t)(bn0 + row) * 256 + ktn + s * 8, nb + 16384 + wc * 1024);
      }
    }
    const char* sa = smem + b * 32768;
    const char* sb = sa + 16384;
#pragma unroll
    for (int ks = 0; ks < 2; ++ks) {
      bf16x8 af[4], bfr[4];
#pragma unroll
      for (int mi = 0; mi < 4; ++mi) {
        int row = wm * 64 + mi * 16 + lr;
        int q = (lg + 4 * ks) ^ (row & 7);
        af[mi] = *(const bf16x8*)(sa + row * 128 + q * 16);
      }
#pragma unroll
      for (int ni = 0; ni < 4; ++ni) {
        int row = wn * 64 + ni * 16 + lr;
        int q = (lg + 4 * ks) ^ (row & 7);
        bfr[ni] = *(const bf16x8*)(sb + row * 128 + q * 16);
      }
#pragma unroll
      for (int mi = 0; mi < 4; ++mi)
#pragma unroll
        for (int ni = 0; ni < 4; ++ni)
          acc[mi][ni] = __builtin_amdgcn_mfma_f32_16x16x32_bf16(af[mi], bfr[ni], acc[mi][ni], 0, 0, 0);
    }
    if (TIN && it < 3) {
      char* nb = smem + (b ^ 1) * 32768;
#pragma unroll
      for (int i = 0; i < 4; ++i) {
        int p = tid + 256 * i, row = p >> 3, s = (p & 7) ^ (row & 7);
        int k0 = ktn + s * 8;
        float4 sc0 = *(const float4*)&lsc[k0], sc1 = *(const float4*)&lsc[k0 + 4];
        float4 sh0 = *(const float4*)&lsh[k0], sh1 = *(const float4*)&lsh[k0 + 4];
        bf16x8 v = stg[i], o;
        o[0] = f2bf(fmaxf(bf2f((unsigned short)v[0]) * sc0.x + sh0.x, 0.f));
        o[1] = f2bf(fmaxf(bf2f((unsigned short)v[1]) * sc0.y + sh0.y, 0.f));
        o[2] = f2bf(fmaxf(bf2f((unsigned short)v[2]) * sc0.z + sh0.z, 0.f));
        o[3] = f2bf(fmaxf(bf2f((unsigned short)v[3]) * sc0.w + sh0.w, 0.f));
        o[4] = f2bf(fmaxf(bf2f((unsigned short)v[4]) * sc1.x + sh1.x, 0.f));
        o[5] = f2bf(fmaxf(bf2f((unsigned short)v[5]) * sc1.y + sh1.y, 0.f));
        o[6] = f2bf(fmaxf(bf2f((unsigned short)v[6]) * sc1.z + sh1.z, 0.f));
        o[7] = f2bf(fmaxf(bf2f((unsigned short)v[7]) * sc1.w + sh1.w, 0.f));
        *(bf16x8*)(nb + p * 16) = o;
      }
    }
    __syncthreads();
  }

  short* zs = (short*)smem;  // [128][136] bf16
#pragma unroll
  for (int ni = 0; ni < 4; ++ni) {
    int col = wn * 64 + ni * 16 + lr;
    float bv = bias[bn0 + col];
    float ps = 0.f, pq = 0.f;
#pragma unroll
    for (int mi = 0; mi < 4; ++mi) {
#pragma unroll
      for (int r = 0; r < 4; ++r) {
        int row = wm * 64 + mi * 16 + lg * 4 + r;
        float tv = acc[mi][ni][r] + bv;
        if (ACT == 1) tv = tv > 0.f ? tv : 0.01f * tv;
        if (STATS && (bm0 + row) < M) { ps += tv; pq += tv * tv; }
        zs[row * 136 + col] = f2bf(tv);
      }
    }
    if (STATS) {
      ps += __shfl_xor(ps, 16); pq += __shfl_xor(pq, 16);
      ps += __shfl_xor(ps, 32); pq += __shfl_xor(pq, 32);
      if (lane < 16) {
        atomicAdd(&lsum[wn * 64 + ni * 16 + lane], ps);
        atomicAdd(&lssq[wn * 64 + ni * 16 + lane], pq);
      }
    }
  }
  __syncthreads();
  {
    int row = tid >> 1;
    int grow = bm0 + row;
    if (grow < M) {
#pragma unroll
      for (int i = 0; i < 8; ++i) {
        int cs = (tid & 1) * 8 + i;
        bf16x8 v = *(const bf16x8*)((const char*)zs + row * 272 + cs * 16);
        *(bf16x8*)(C + (size_t)grow * 256 + bn0 + cs * 8) = v;
      }
    }
  }
  if (STATS) {
    if (tid < 128) {
      atomicAdd(&gsum[bn0 + tid], lsum[tid]);
      atomicAdd(&gssq[bn0 + tid], lssq[tid]);
    }
  }
}

__global__ void k_bnprep(const float* __restrict__ sum, const float* __restrict__ ssq,
                         const float* __restrict__ g, const float* __restrict__ be,
                         float* __restrict__ scale, float* __restrict__ shift, int M) {
  int c = threadIdx.x;
  float mu = sum[c] / (float)M;
  float var = ssq[c] / (float)M - mu * mu;
  float rs = rsqrtf(var + 1e-5f);
  float sc = g[c] * rs;
  scale[c] = sc;
  shift[c] = be[c] - mu * sc;
}

// ============================================================================
// head: A' = bf16(x + 0.01*lrelu(bn4(V)));  z = lrelu(A' @ Wl1 + bl1) [128];
// out = z @ Wl3 + bl3 [10] via a 128x16 MFMA pass (Wl3T bf16 [16][128], padded).
// Same skeleton as k_gemm: BK=64, dbuf, XOR swizzle, gload_lds for B.
// ============================================================================
__global__ __launch_bounds__(256, 2) void k_head(const short* __restrict__ V,
                                                 const float* __restrict__ x,
                                                 const short* __restrict__ BT,
                                                 const float* __restrict__ bl1,
                                                 const short* __restrict__ wl3t,
                                                 const float* __restrict__ bl3,
                                                 const float* __restrict__ tsc,
                                                 const float* __restrict__ tsh,
                                                 float* __restrict__ out, int M) {
  __shared__ char smem[65536];   // dbuf A/B; epilogue z[128][136] overlays
  __shared__ float lsc[256], lsh[256];
  __shared__ short wl3s[2048];   // [16][128] bf16
  int tid = threadIdx.x;
  int lane = tid & 63, w = tid >> 6;
  lsc[tid] = tsc[tid]; lsh[tid] = tsh[tid];
  {
    int p = w * 64 + lane;
    gload16(wl3t + (size_t)p * 8, (char*)wl3s + w * 1024);
  }
  int bm0 = blockIdx.x * 128;
  int wm = w >> 1, wn = w & 1;
  int lr = lane & 15, lg = lane >> 4;
  f32x4 acc[4][4] = {};
  __syncthreads();

  bf16x8 stgv[4];
  float stgx[4][8];

#pragma unroll 1
  for (int it = 0; it < 4; ++it) {
    int b = it & 1;
    if (it == 0) {
#pragma unroll
      for (int i = 0; i < 4; ++i) {
        int p = tid + 256 * i, row = p >> 3, s = (p & 7) ^ (row & 7);
        int grow = bm0 + row; if (grow > M - 1) grow = M - 1;
        size_t base = (size_t)grow * 256 + s * 8;
        stgv[i] = *(const bf16x8*)(V + base);
        *(float4*)&stgx[i][0] = *(const float4*)(x + base);
        *(float4*)&stgx[i][4] = *(const float4*)(x + base + 4);
      }
#pragma unroll
      for (int q = 0; q < 4; ++q) {
        int wc = w * 4 + q;
        int p = wc * 64 + lane, row = p >> 3, s = (p & 7) ^ (row & 7);
        gload16(BT + (size_t)row * 256 + s * 8, smem + 16384 + wc * 1024);
      }
#pragma unroll
      for (int i = 0; i < 4; ++i) {
        int p = tid + 256 * i, row = p >> 3, s = (p & 7) ^ (row & 7);
        int k0 = s * 8;
        bf16x8 v = stgv[i], o;
#pragma unroll
        for (int jj = 0; jj < 8; ++jj) {
          float f = bf2f((unsigned short)v[jj]) * lsc[k0 + jj] + lsh[k0 + jj];
          f = f > 0.f ? f : 0.1f * f;
          o[jj] = f2bf(stgx[i][jj] + 0.01f * f);
        }
        *(bf16x8*)(smem + p * 16) = o;
      }
      __syncthreads();
    }
    int ktn = (it + 1) * 64;
    if (it < 3) {
      char* nb = smem + (b ^ 1) * 32768;
#pragma unroll
      for (int i = 0; i < 4; ++i) {
        int p = tid + 256 * i, row = p >> 3, s = (p & 7) ^ (row & 7);
        int grow = bm0 + row; if (grow > M - 1) grow = M - 1;
        size_t base = (size_t)grow * 256 + ktn + s * 8;
        stgv[i] = *(const bf16x8*)(V + base);
        *(float4*)&stgx[i][0] = *(const float4*)(x + base);
        *(float4*)&stgx[i][4] = *(const float4*)(x + base + 4);
      }
#pragma unroll
      for (int q = 0; q < 4; ++q) {
        int wc = w * 4 + q;
        int p = wc * 64 + lane, row = p >> 3, s = (p & 7) ^ (row & 7);
        gload16(BT + (size_t)row * 256 + ktn + s * 8, nb + 16384 + wc * 1024);
      }
    }
    const char* sa = smem + b * 32768;
    const char* sb = sa + 16384;
#pragma unroll
    for (int ks = 0; ks < 2; ++ks) {
      bf16x8 af[4], bfr[4];
#pragma unroll
      for (int mi = 0; mi < 4; ++mi) {
        int row = wm * 64 + mi * 16 + lr;
        int q = (lg + 4 * ks) ^ (row & 7);
        af[mi] = *(const bf16x8*)(sa + row * 128 + q * 16);
      }
#pragma unroll
      for (int ni = 0; ni < 4; ++ni) {
        int row = wn * 64 + ni * 16 + lr;
        int q = (lg + 4 * ks) ^ (row & 7);
        bfr[ni] = *(const bf16x8*)(sb + row * 128 + q * 16);
      }
#pragma unroll
      for (int mi = 0; mi < 4; ++mi)
#pragma unroll
        for (int ni = 0; ni < 4; ++ni)
          acc[mi][ni] = __builtin_amdgcn_mfma_f32_16x16x32_bf16(af[mi], bfr[ni], acc[mi][ni], 0, 0, 0);
    }
    if (it < 3) {
      char* nb = smem + (b ^ 1) * 32768;
#pragma unroll
      for (int i = 0; i < 4; ++i) {
        int p = tid + 256 * i, row = p >> 3, s = (p & 7) ^ (row & 7);
        int k0 = ktn + s * 8;
        bf16x8 v = stgv[i], o;
#pragma unroll
        for (int jj = 0; jj < 8; ++jj) {
          float f = bf2f((unsigned short)v[jj]) * lsc[k0 + jj] + lsh[k0 + jj];
          f = f > 0.f ? f : 0.1f * f;
          o[jj] = f2bf(stgx[i][jj] + 0.01f * f);
        }
        *(bf16x8*)(nb + p * 16) = o;
      }
    }
    __syncthreads();
  }

  // z epilogue -> LDS [128][136] bf16
  short* zs = (short*)smem;
#pragma unroll
  for (int ni = 0; ni < 4; ++ni) {
    int col = wn * 64 + ni * 16 + lr;
    float bv = bl1[col];
#pragma unroll
    for (int mi = 0; mi < 4; ++mi) {
#pragma unroll
      for (int r = 0; r < 4; ++r) {
        int row = wm * 64 + mi * 16 + lg * 4 + r;
        float tv = acc[mi][ni][r] + bv;
        tv = tv > 0.f ? tv : 0.1f * tv;
        zs[row * 136 + col] = f2bf(tv);
      }
    }
  }
  __syncthreads();

  // out = z @ Wl3 + bl3 via MFMA: each wave does 2 M-tiles, N=16 (10 valid)
  f32x4 acc2[2] = {};
#pragma unroll
  for (int kk = 0; kk < 4; ++kk) {
    bf16x8 bfr = *(const bf16x8*)((const char*)wl3s + lr * 256 + (kk * 4 + lg) * 16);
#pragma unroll
    for (int m = 0; m < 2; ++m) {
      int row = (w * 2 + m) * 16 + lr;
      bf16x8 af = *(const bf16x8*)((const char*)zs + row * 272 + (kk * 4 + lg) * 16);
      acc2[m] = __builtin_amdgcn_mfma_f32_16x16x32_bf16(af, bfr, acc2[m], 0, 0, 0);
    }
  }
  if (lr < 10) {
    float bv = bl3[lr];
#pragma unroll
    for (int m = 0; m < 2; ++m) {
#pragma unroll
      for (int r = 0; r < 4; ++r) {
        int row = (w * 2 + m) * 16 + lg * 4 + r;
        int grow = bm0 + row;
        if (grow < M) out[(size_t)grow * 10 + lr] = acc2[m][r] + bv;
      }
    }
  }
}

extern "C" void kernel_launch(void* const* d_in, const int* in_sizes, int n_in,
                              void* d_out, int out_size, void* d_ws, size_t ws_size,
                              hipStream_t stream) {
  const float* x   = (const float*)d_in[0];
  const int*   ew  = (const int*)d_in[1];
  const float* W1  = (const float*)d_in[2];
  const float* b1  = (const float*)d_in[3];
  const float* g1  = (const float*)d_in[4];
  const float* be1 = (const float*)d_in[5];
  const float* W2  = (const float*)d_in[6];
  const float* b2  = (const float*)d_in[7];
  const float* g4  = (const float*)d_in[8];
  const float* be4 = (const float*)d_in[9];
  const float* Wl1 = (const float*)d_in[10];
  const float* bl1 = (const float*)d_in[11];
  const float* Wl3 = (const float*)d_in[12];
  const float* bl3 = (const float*)d_in[13];
  float* out = (float*)d_out;

  char* ws = (char*)d_ws;
  const size_t OFF_OFF  = 0;          // (N+1) ints
  const size_t OFF_BASES= 400128;     // NBUCK+1 ints
  const size_t OFF_CNT  = 800256;     // CGRID x NBUCK ints (306KB)
  const size_t OFF_WL3T = 1106944;    // 16x128 bf16 (4KB), in CNT region slack
  const size_t OFF_STATS= 1200384;    // 4x256 f32 -- memset
  const size_t OFF_BN   = 1204480;    // 4x256 f32 (sc1,sh1,sc4,sh4)
  const size_t OFF_FLAG = 1208576;
  const size_t OFF_W1T  = 1209216;
  const size_t OFF_W2T  = 1340288;
  const size_t OFF_WL1T = 1471360;
  const size_t OFF_CSR  = 1536896;    // NE ints (6.4MB)
  const size_t OFF_BUFA = 7936896;    // 51.2MB ; pairs (6.4MB) aliases this
  const size_t OFF_BUFB = 59136896;   // xq aliases bufB
  if (ws_size < 110336896) return;

  int* off_  = (int*)(ws + OFF_OFF);
  int* bases_= (int*)(ws + OFF_BASES);
  int* cnt_  = (int*)(ws + OFF_CNT);
  float* sum1 = (float*)(ws + OFF_STATS);
  float* ssq1 = sum1 + 256;
  float* sum4 = sum1 + 512;
  float* ssq4 = sum1 + 768;
  float* sc1 = (float*)(ws + OFF_BN);
  float* sh1 = sc1 + 256;
  float* sc4 = sc1 + 512;
  float* sh4 = sc1 + 768;
  int* flag_ = (int*)(ws + OFF_FLAG);
  short* W1T  = (short*)(ws + OFF_W1T);
  short* W2T  = (short*)(ws + OFF_W2T);
  short* Wl1T = (short*)(ws + OFF_WL1T);
  short* Wl3T = (short*)(ws + OFF_WL3T);
  int* csr_   = (int*)(ws + OFF_CSR);
  short* bufA = (short*)(ws + OFF_BUFA);
  short* bufB = (short*)(ws + OFF_BUFB);
  int* pairs_ = (int*)(ws + OFF_BUFA);  // alias: dead before k_agg2 writes bufA
  void* xq    = (void*)bufB;            // alias: dead before GEMM1 writes bufB

  hipMemsetAsync(ws + OFF_STATS, 0, 4096, stream);
  k_detect<<<1, 256, 0, stream>>>(ew, flag_);
  k_cvtW<<<641, 256, 0, stream>>>(W1, W2, Wl1, Wl3, W1T, W2T, Wl1T, Wl3T);
  k_cvtX<<<12500, 256, 0, stream>>>(x, xq);
  k_count<<<CGRID, 1024, 0, stream>>>(ew, flag_, cnt_);
  k_colscan<<<1, 1024, 0, stream>>>(cnt_, bases_, off_);
  k_scatter<<<CGRID, 1024, 0, stream>>>(ew, flag_, cnt_, pairs_);
  k_bsort<<<NBUCK, 256, 0, stream>>>(pairs_, bases_, off_, csr_);
  k_agg2<<<25000, 256, 0, stream>>>(xq, off_, csr_, bufA);
  k_gemm<0, 0, 1><<<1564, 256, 0, stream>>>(bufA, W1T, b1, bufB, NN,
                                            nullptr, nullptr, sum1, ssq1);
  k_bnprep<<<1, 256, 0, stream>>>(sum1, ssq1, g1, be1, sc1, sh1, NN);
  k_gemm<1, 1, 1><<<1564, 256, 0, stream>>>(bufB, W2T, b2, bufA, NN,
                                            sc1, sh1, sum4, ssq4);
  k_bnprep<<<1, 256, 0, stream>>>(sum4, ssq4, g4, be4, sc4, sh4, NN);
  k_head<<<782, 256, 0, stream>>>(bufA, x, Wl1T, bl1, Wl3T, bl3, sc4, sh4, out, NN);
}

// Round 7
// 267.375 us; speedup vs baseline: 3.2779x; 1.1237x over previous
//
#include <hip/hip_runtime.h>

constexpr int NN = 100000;   // nodes
constexpr int NE = 1600000;  // edges
constexpr int NBUCK = 782;   // ceil(NN/128)
constexpr int CGRID = 98;    // count/scatter blocks (98*16384 >= NE)

typedef __attribute__((ext_vector_type(4))) float  f32x4;
typedef __attribute__((ext_vector_type(2))) float  f32x2;
typedef __attribute__((ext_vector_type(8))) short  bf16x8;

__device__ __forceinline__ float bf2f(unsigned short u) {
  union { unsigned int i; float f; } c;
  c.i = ((unsigned int)u) << 16;
  return c.f;
}
__device__ __forceinline__ short f2bf(float f) {
  union { float f; unsigned int i; } c; c.f = f;
  unsigned int i = c.i + 0x7fffu + ((c.i >> 16) & 1u);
  return (short)(i >> 16);
}
__device__ __forceinline__ unsigned char f2fp8(float f) {
  int w = __builtin_amdgcn_cvt_pk_fp8_f32(f, 0.f, 0, false);
  return (unsigned char)(w & 0xff);
}
__device__ __forceinline__ void up4(int wv, float* f) {
  f32x2 a = __builtin_amdgcn_cvt_pk_f32_fp8(wv, false);
  f32x2 b = __builtin_amdgcn_cvt_pk_f32_fp8(wv, true);
  f[0] = a[0]; f[1] = a[1]; f[2] = b[0]; f[3] = b[1];
}

// async global->LDS, 16B per lane; LDS dest is wave-uniform base + lane*16
__device__ __forceinline__ void gload16(const void* g, void* l) {
  __builtin_amdgcn_global_load_lds(
      (const __attribute__((address_space(1))) unsigned int*)g,
      (__attribute__((address_space(3))) unsigned int*)l, 16, 0, 0);
}

// ---- edge dtype detection + stats zeroing ----
__global__ void k_detect(const int* __restrict__ ew, int* __restrict__ flag,
                         float* __restrict__ zst) {
  __shared__ int bad;
  if (threadIdx.x == 0) bad = 0;
  for (int i = threadIdx.x; i < 1024; i += 256) zst[i] = 0.f;
  __syncthreads();
  int nz = 0;
  for (int i = threadIdx.x; i < 2048; i += 256) nz |= ew[2 * i + 1];
  if (nz) atomicOr(&bad, 1);
  __syncthreads();
  if (threadIdx.x == 0) *flag = (bad == 0) ? 1 : 0;
}

// ---- weights: W1,W2 -> fp8 transposed; Wl1 -> bf16 T; Wl3 -> bf16 [16][128] ----
__global__ void k_cvtW(const float* __restrict__ W1, const float* __restrict__ W2,
                       const float* __restrict__ Wl1, const float* __restrict__ Wl3,
                       unsigned char* __restrict__ W1T8, unsigned char* __restrict__ W2T8,
                       short* __restrict__ Wl1T, short* __restrict__ Wl3T) {
  int b = blockIdx.x, t = threadIdx.x;
  if (b < 256)       W1T8[b * 256 + t]       = f2fp8(W1[t * 256 + b]);
  else if (b < 512){ int n = b - 256; W2T8[n * 256 + t] = f2fp8(W2[t * 256 + n]); }
  else if (b < 640){ int n = b - 512; Wl1T[n * 256 + t] = f2bf(Wl1[t * 128 + n]); }
  else {
    if (t < 128) {
#pragma unroll
      for (int c = 0; c < 16; ++c)
        Wl3T[c * 128 + t] = (c < 10) ? f2bf(Wl3[t * 10 + c]) : (short)0;
    }
  }
}

// ---- x (f32) -> fp8 gather copy ----
__global__ void k_cvtX(const float* __restrict__ x, void* __restrict__ xq) {
  int c = blockIdx.x * 256 + threadIdx.x;  // 3.2M chunks of 8, grid exact
  float4 a = ((const float4*)x)[2 * (size_t)c];
  float4 b = ((const float4*)x)[2 * (size_t)c + 1];
  int p0 = 0, p1 = 0;
  p0 = __builtin_amdgcn_cvt_pk_fp8_f32(a.x, a.y, p0, false);
  p0 = __builtin_amdgcn_cvt_pk_fp8_f32(a.z, a.w, p0, true);
  p1 = __builtin_amdgcn_cvt_pk_fp8_f32(b.x, b.y, p1, false);
  p1 = __builtin_amdgcn_cvt_pk_fp8_f32(b.z, b.w, p1, true);
  ((int2*)xq)[c] = make_int2(p0, p1);
}

// ---- pass 1: per-block bucket histogram (no global atomics) ----
__global__ __launch_bounds__(1024) void k_count(const int* __restrict__ ew,
                                                const int* __restrict__ flag,
                                                int* __restrict__ cntmat) {
  __shared__ int lcnt[NBUCK];
  int m64 = *flag;
  int t = threadIdx.x;
  for (int i = t; i < NBUCK; i += 1024) lcnt[i] = 0;
  __syncthreads();
  int base = blockIdx.x * 16384;
#pragma unroll
  for (int u = 0; u < 16; u++) {
    int e = base + u * 1024 + t;
    if (e < NE) {
      int d = m64 ? ew[2 * (NE + e)] : ew[NE + e];
      atomicAdd(&lcnt[d >> 7], 1);
    }
  }
  __syncthreads();
  for (int i = t; i < NBUCK; i += 1024) cntmat[blockIdx.x * NBUCK + i] = lcnt[i];
}

// ---- pass 2: column scan -> per-(block,bucket) bases + bucket bases ----
__global__ __launch_bounds__(1024) void k_colscan(int* __restrict__ cntmat,
                                                  int* __restrict__ bases,
                                                  int* __restrict__ off_) {
  __shared__ int tot[1024];
  int t = threadIdx.x;
  int sum = 0;
  if (t < NBUCK) {
    for (int g = 0; g < CGRID; g++) sum += cntmat[g * NBUCK + t];
    tot[t] = sum;
  }
  __syncthreads();
  int v = (t < NBUCK) ? sum : 0;
  for (int o = 1; o < 1024; o <<= 1) {
    int u = (t >= o && t < NBUCK) ? tot[t - o] : 0;
    __syncthreads();
    if (t < NBUCK) tot[t] += u;
    __syncthreads();
  }
  if (t < NBUCK) {
    int b = tot[t] - v;  // exclusive
    bases[t] = b;
    int run = b;
    for (int g = 0; g < CGRID; g++) {
      int c = cntmat[g * NBUCK + t];
      cntmat[g * NBUCK + t] = run;
      run += c;
    }
  }
  if (t == NBUCK) bases[NBUCK] = NE;
  if (t == NBUCK + 1) off_[NN] = NE;
}

// ---- pass 3: dense bucketed scatter of packed (src | ld<<17) ----
__global__ __launch_bounds__(1024) void k_scatter(const int* __restrict__ ew,
                                                  const int* __restrict__ flag,
                                                  const int* __restrict__ cntmat,
                                                  int* __restrict__ pairs) {
  __shared__ int lcur[NBUCK];
  int m64 = *flag;
  int t = threadIdx.x;
  for (int i = t; i < NBUCK; i += 1024) lcur[i] = cntmat[blockIdx.x * NBUCK + i];
  __syncthreads();
  int base = blockIdx.x * 16384;
#pragma unroll
  for (int u = 0; u < 16; u++) {
    int e = base + u * 1024 + t;
    if (e < NE) {
      int d = m64 ? ew[2 * (NE + e)] : ew[NE + e];
      int s = m64 ? ew[2 * e] : ew[e];
      int slot = atomicAdd(&lcur[d >> 7], 1);
      pairs[slot] = s | ((d & 127) << 17);
    }
  }
}

// ---- pass 4: per-bucket counting sort in LDS -> off_ + csr ----
__global__ __launch_bounds__(256) void k_bsort(const int* __restrict__ pairs,
                                               const int* __restrict__ bases,
                                               int* __restrict__ off_,
                                               int* __restrict__ csr) {
  __shared__ int lcnt[128], lofs[128], lcur[128];
  int b = blockIdx.x, t = threadIdx.x;
  int s0 = bases[b], s1 = bases[b + 1];
  if (t < 128) lcnt[t] = 0;
  __syncthreads();
  for (int j = s0 + t; j < s1; j += 256) atomicAdd(&lcnt[(pairs[j] >> 17) & 127], 1);
  __syncthreads();
  int v = (t < 128) ? lcnt[t] : 0;
  if (t < 128) lofs[t] = v;
  __syncthreads();
  for (int o = 1; o < 128; o <<= 1) {
    int u = (t >= o && t < 128) ? lofs[t - o] : 0;
    __syncthreads();
    if (t < 128) lofs[t] += u;
    __syncthreads();
  }
  if (t < 128) {
    int ex = lofs[t] - v;  // exclusive
    lcur[t] = ex;
    int node = b * 128 + t;
    if (node < NN) off_[node] = s0 + ex;
  }
  __syncthreads();
  for (int j = s0 + t; j < s1; j += 256) {
    int p = pairs[j];
    int slot = atomicAdd(&lcur[(p >> 17) & 127], 1);
    csr[s0 + slot] = p & 0x1FFFF;
  }
}

// one WAVE per node, lane owns 4 columns; fp8 in, fp8 out
__global__ __launch_bounds__(256) void k_agg2(const void* __restrict__ xq,
                                              const int* __restrict__ off_,
                                              const int* __restrict__ csr,
                                              unsigned char* __restrict__ h0) {
  int node = blockIdx.x * 4 + (threadIdx.x >> 6);  // grid 25000 exact
  int lane = threadIdx.x & 63;
  const unsigned char* xb = (const unsigned char*)xq;
  size_t boff = (size_t)lane * 4;  // byte offset within 256B row
  int s0 = off_[node], s1 = off_[node + 1];
  int sw = *(const int*)(xb + (size_t)node * 256 + boff);
  f32x2 slo = __builtin_amdgcn_cvt_pk_f32_fp8(sw, false);
  f32x2 shi = __builtin_amdgcn_cvt_pk_f32_fp8(sw, true);
  float a0 = slo[0], a1 = slo[1], a2 = shi[0], a3 = shi[1];
  int j = s0;
  while (j + 8 <= s1) {
    int idx[8];
#pragma unroll
    for (int u = 0; u < 8; u++) idx[u] = csr[j + u];
    int w[8];
#pragma unroll
    for (int u = 0; u < 8; u++) w[u] = *(const int*)(xb + (size_t)idx[u] * 256 + boff);
#pragma unroll
    for (int u = 0; u < 8; u++) {
      f32x2 lo = __builtin_amdgcn_cvt_pk_f32_fp8(w[u], false);
      f32x2 hi = __builtin_amdgcn_cvt_pk_f32_fp8(w[u], true);
      a0 += lo[0]; a1 += lo[1]; a2 += hi[0]; a3 += hi[1];
    }
    j += 8;
  }
  if (j + 4 <= s1) {
    int idx[4];
#pragma unroll
    for (int u = 0; u < 4; u++) idx[u] = csr[j + u];
    int w[4];
#pragma unroll
    for (int u = 0; u < 4; u++) w[u] = *(const int*)(xb + (size_t)idx[u] * 256 + boff);
#pragma unroll
    for (int u = 0; u < 4; u++) {
      f32x2 lo = __builtin_amdgcn_cvt_pk_f32_fp8(w[u], false);
      f32x2 hi = __builtin_amdgcn_cvt_pk_f32_fp8(w[u], true);
      a0 += lo[0]; a1 += lo[1]; a2 += hi[0]; a3 += hi[1];
    }
    j += 4;
  }
  for (; j < s1; j++) {
    int s = csr[j];
    int w = *(const int*)(xb + (size_t)s * 256 + boff);
    f32x2 lo = __builtin_amdgcn_cvt_pk_f32_fp8(w, false);
    f32x2 hi = __builtin_amdgcn_cvt_pk_f32_fp8(w, true);
    a0 += lo[0]; a1 += lo[1]; a2 += hi[0]; a3 += hi[1];
  }
  int o = 0;
  o = __builtin_amdgcn_cvt_pk_fp8_f32(a0, a1, o, false);
  o = __builtin_amdgcn_cvt_pk_fp8_f32(a2, a3, o, true);
  ((int*)h0)[(size_t)node * 64 + lane] = o;
}

// ============================================================================
// fp8 MFMA GEMM, 128x128 tile, BK=64 (64B/row), double-buffered.
// LDS layout: 2-row units of 128B = 8 slots of 16B; physical slot = logical
// slot-in-unit ^ (unit&7)  -> conflict-free ds_read_b64 fragments.
// TIN=1: A' = fp8(relu(bn(A))) during reg staging (issue-early/write-late).
// STATS: per-column sum/ssq of f32 epilogue values.
// ============================================================================
template <int ACT, int TIN, int STATS>
__global__ __launch_bounds__(256, 2) void k_gemm8(
    const unsigned char* __restrict__ A, const unsigned char* __restrict__ BT,
    const float* __restrict__ bias, unsigned char* __restrict__ C, int M,
    const float* __restrict__ tsc, const float* __restrict__ tsh,
    float* __restrict__ gsum, float* __restrict__ gssq) {
  __shared__ char smem[32768];   // 2 x (A 8KB + B 8KB); epilogue bounce overlays
  __shared__ float lsc[256], lsh[256];
  __shared__ float lsum[128], lssq[128];
  int tid = threadIdx.x, lane = tid & 63, w = tid >> 6;
  if (TIN) { lsc[tid] = tsc[tid]; lsh[tid] = tsh[tid]; }
  if (STATS && tid < 128) { lsum[tid] = 0.f; lssq[tid] = 0.f; }
  int bm = blockIdx.x >> 1, bn = blockIdx.x & 1;
  int bm0 = bm * 128, bn0 = bn * 128;
  int wm = w >> 1, wn = w & 1;
  int lr = lane & 15, lg = lane >> 4;
  f32x4 acc[4][4] = {};
  __syncthreads();

  int4 stg[2];  // raw fp8 reg staging (TIN)

#pragma unroll 1
  for (int it = 0; it < 4; ++it) {
    int b = it & 1;
    if (it == 0) {
      // prologue: stage buf0 @ kt=0
      if (TIN) {
#pragma unroll
        for (int i = 0; i < 2; ++i) {
          int p = i * 256 + tid, unit = p >> 3, u = (p & 7) ^ (unit & 7);
          int srow = unit * 2 + (u >> 2), slot = u & 3;
          int grow = bm0 + srow; if (grow > M - 1) grow = M - 1;
          stg[i] = *(const int4*)(A + (size_t)grow * 256 + slot * 16);
        }
      } else {
#pragma unroll
        for (int q = 0; q < 2; ++q) {
          int wc = w * 2 + q;
          int p = wc * 64 + lane, unit = p >> 3, u = (p & 7) ^ (unit & 7);
          int srow = unit * 2 + (u >> 2), slot = u & 3;
          int grow = bm0 + srow; if (grow > M - 1) grow = M - 1;
          gload16(A + (size_t)grow * 256 + slot * 16, smem + wc * 1024);
        }
      }
#pragma unroll
      for (int q = 0; q < 2; ++q) {
        int wc = w * 2 + q;
        int p = wc * 64 + lane, unit = p >> 3, u = (p & 7) ^ (unit & 7);
        int srow = unit * 2 + (u >> 2), slot = u & 3;
        gload16(BT + (size_t)(bn0 + srow) * 256 + slot * 16, smem + 8192 + wc * 1024);
      }
      if (TIN) {
#pragma unroll
        for (int i = 0; i < 2; ++i) {
          int p = i * 256 + tid, unit = p >> 3, u = (p & 7) ^ (unit & 7);
          int slot = u & 3;
          int k0 = slot * 16;
          float f[16];
          up4(stg[i].x, f); up4(stg[i].y, f + 4); up4(stg[i].z, f + 8); up4(stg[i].w, f + 12);
#pragma unroll
          for (int jj = 0; jj < 16; ++jj) f[jj] = fmaxf(f[jj] * lsc[k0 + jj] + lsh[k0 + jj], 0.f);
          int w0 = 0, w1 = 0, w2 = 0, w3 = 0;
          w0 = __builtin_amdgcn_cvt_pk_fp8_f32(f[0], f[1], w0, false);
          w0 = __builtin_amdgcn_cvt_pk_fp8_f32(f[2], f[3], w0, true);
          w1 = __builtin_amdgcn_cvt_pk_fp8_f32(f[4], f[5], w1, false);
          w1 = __builtin_amdgcn_cvt_pk_fp8_f32(f[6], f[7], w1, true);
          w2 = __builtin_amdgcn_cvt_pk_fp8_f32(f[8], f[9], w2, false);
          w2 = __builtin_amdgcn_cvt_pk_fp8_f32(f[10], f[11], w2, true);
          w3 = __builtin_amdgcn_cvt_pk_fp8_f32(f[12], f[13], w3, false);
          w3 = __builtin_amdgcn_cvt_pk_fp8_f32(f[14], f[15], w3, true);
          *(int4*)(smem + p * 16) = make_int4(w0, w1, w2, w3);
        }
      }
      __syncthreads();
    }
    int ktn = (it + 1) * 64;
    if (it < 3) {
      char* nb = smem + (b ^ 1) * 16384;
      if (TIN) {
#pragma unroll
        for (int i = 0; i < 2; ++i) {
          int p = i * 256 + tid, unit = p >> 3, u = (p & 7) ^ (unit & 7);
          int srow = unit * 2 + (u >> 2), slot = u & 3;
          int grow = bm0 + srow; if (grow > M - 1) grow = M - 1;
          stg[i] = *(const int4*)(A + (size_t)grow * 256 + ktn + slot * 16);
        }
      } else {
#pragma unroll
        for (int q = 0; q < 2; ++q) {
          int wc = w * 2 + q;
          int p = wc * 64 + lane, unit = p >> 3, u = (p & 7) ^ (unit & 7);
          int srow = unit * 2 + (u >> 2), slot = u & 3;
          int grow = bm0 + srow; if (grow > M - 1) grow = M - 1;
          gload16(A + (size_t)grow * 256 + ktn + slot * 16, nb + wc * 1024);
        }
      }
#pragma unroll
      for (int q = 0; q < 2; ++q) {
        int wc = w * 2 + q;
        int p = wc * 64 + lane, unit = p >> 3, u = (p & 7) ^ (unit & 7);
        int srow = unit * 2 + (u >> 2), slot = u & 3;
        gload16(BT + (size_t)(bn0 + srow) * 256 + ktn + slot * 16, nb + 8192 + wc * 1024);
      }
    }
    const char* sa = smem + b * 16384;
    const char* sb = sa + 8192;
#pragma unroll
    for (int ks = 0; ks < 2; ++ks) {
      long af[4], bfr[4];
#pragma unroll
      for (int mi = 0; mi < 4; ++mi) {
        int row = wm * 64 + mi * 16 + lr;
        int unit = row >> 1;
        int u = (row & 1) * 4 + ks * 2 + (lg >> 1);
        int up = u ^ (unit & 7);
        af[mi] = *(const long*)(sa + unit * 128 + up * 16 + (lg & 1) * 8);
      }
#pragma unroll
      for (int ni = 0; ni < 4; ++ni) {
        int row = wn * 64 + ni * 16 + lr;
        int unit = row >> 1;
        int u = (row & 1) * 4 + ks * 2 + (lg >> 1);
        int up = u ^ (unit & 7);
        bfr[ni] = *(const long*)(sb + unit * 128 + up * 16 + (lg & 1) * 8);
      }
#pragma unroll
      for (int mi = 0; mi < 4; ++mi)
#pragma unroll
        for (int ni = 0; ni < 4; ++ni)
          acc[mi][ni] = __builtin_amdgcn_mfma_f32_16x16x32_fp8_fp8(af[mi], bfr[ni], acc[mi][ni], 0, 0, 0);
    }
    if (TIN && it < 3) {
      char* nb = smem + (b ^ 1) * 16384;
#pragma unroll
      for (int i = 0; i < 2; ++i) {
        int p = i * 256 + tid, unit = p >> 3, u = (p & 7) ^ (unit & 7);
        int slot = u & 3;
        int k0 = ktn + slot * 16;
        float f[16];
        up4(stg[i].x, f); up4(stg[i].y, f + 4); up4(stg[i].z, f + 8); up4(stg[i].w, f + 12);
#pragma unroll
        for (int jj = 0; jj < 16; ++jj) f[jj] = fmaxf(f[jj] * lsc[k0 + jj] + lsh[k0 + jj], 0.f);
        int w0 = 0, w1 = 0, w2 = 0, w3 = 0;
        w0 = __builtin_amdgcn_cvt_pk_fp8_f32(f[0], f[1], w0, false);
        w0 = __builtin_amdgcn_cvt_pk_fp8_f32(f[2], f[3], w0, true);
        w1 = __builtin_amdgcn_cvt_pk_fp8_f32(f[4], f[5], w1, false);
        w1 = __builtin_amdgcn_cvt_pk_fp8_f32(f[6], f[7], w1, true);
        w2 = __builtin_amdgcn_cvt_pk_fp8_f32(f[8], f[9], w2, false);
        w2 = __builtin_amdgcn_cvt_pk_fp8_f32(f[10], f[11], w2, true);
        w3 = __builtin_amdgcn_cvt_pk_fp8_f32(f[12], f[13], w3, false);
        w3 = __builtin_amdgcn_cvt_pk_fp8_f32(f[14], f[15], w3, true);
        *(int4*)(nb + p * 16) = make_int4(w0, w1, w2, w3);
      }
    }
    __syncthreads();
  }

  // ---- epilogue: bias+act, stats, fp8 bounce to padded LDS, coalesced store ----
  unsigned char* zs = (unsigned char*)smem;  // [128][144] fp8
#pragma unroll
  for (int ni = 0; ni < 4; ++ni) {
    int col = wn * 64 + ni * 16 + lr;
    float bv = bias[bn0 + col];
    float ps = 0.f, pq = 0.f;
#pragma unroll
    for (int mi = 0; mi < 4; ++mi) {
#pragma unroll
      for (int r = 0; r < 4; ++r) {
        int row = wm * 64 + mi * 16 + lg * 4 + r;
        float tv = acc[mi][ni][r] + bv;
        if (ACT == 1) tv = tv > 0.f ? tv : 0.01f * tv;  // lrelu(lrelu(t,0.1),0.1)
        if (STATS && (bm0 + row) < M) { ps += tv; pq += tv * tv; }
        zs[row * 144 + col] = f2fp8(tv);
      }
    }
    if (STATS) {
      ps += __shfl_xor(ps, 16); pq += __shfl_xor(pq, 16);
      ps += __shfl_xor(ps, 32); pq += __shfl_xor(pq, 32);
      if (lane < 16) {
        atomicAdd(&lsum[wn * 64 + ni * 16 + lane], ps);
        atomicAdd(&lssq[wn * 64 + ni * 16 + lane], pq);
      }
    }
  }
  __syncthreads();
  {
    int row = tid >> 1;
    int grow = bm0 + row;
    if (grow < M) {
#pragma unroll
      for (int i = 0; i < 4; ++i) {
        int cs = (tid & 1) * 64 + i * 16;
        int4 v = *(const int4*)(zs + row * 144 + cs);
        *(int4*)(C + (size_t)grow * 256 + bn0 + cs) = v;
      }
    }
  }
  if (STATS) {
    if (tid < 128) {
      atomicAdd(&gsum[bn0 + tid], lsum[tid]);
      atomicAdd(&gssq[bn0 + tid], lssq[tid]);
    }
  }
}

__global__ void k_bnprep(const float* __restrict__ sum, const float* __restrict__ ssq,
                         const float* __restrict__ g, const float* __restrict__ be,
                         float* __restrict__ scale, float* __restrict__ shift, int M) {
  int c = threadIdx.x;
  float mu = sum[c] / (float)M;
  float var = ssq[c] / (float)M - mu * mu;
  float rs = rsqrtf(var + 1e-5f);
  float sc = g[c] * rs;
  scale[c] = sc;
  shift[c] = be[c] - mu * sc;
}

// ============================================================================
// head: A' = bf16(x + 0.01*lrelu(bn4(V[fp8])));  z = lrelu(A' @ Wl1 + bl1);
// out = z @ Wl3 + bl3 via 128x16 MFMA pass. bf16 MFMA (precision-critical).
// ============================================================================
__global__ __launch_bounds__(256, 2) void k_head(const unsigned char* __restrict__ Vq,
                                                 const float* __restrict__ x,
                                                 const short* __restrict__ BT,
                                                 const float* __restrict__ bl1,
                                                 const short* __restrict__ wl3t,
                                                 const float* __restrict__ bl3,
                                                 const float* __restrict__ tsc,
                                                 const float* __restrict__ tsh,
                                                 float* __restrict__ out, int M) {
  __shared__ char smem[65536];   // dbuf A'/B (bf16); epilogue z[128][136] overlays
  __shared__ float lsc[256], lsh[256];
  __shared__ short wl3s[2048];   // [16][128] bf16
  int tid = threadIdx.x;
  int lane = tid & 63, w = tid >> 6;
  lsc[tid] = tsc[tid]; lsh[tid] = tsh[tid];
  {
    int p = w * 64 + lane;
    gload16(wl3t + (size_t)p * 8, (char*)wl3s + w * 1024);
  }
  int bm0 = blockIdx.x * 128;
  int wm = w >> 1, wn = w & 1;
  int lr = lane & 15, lg = lane >> 4;
  f32x4 acc[4][4] = {};
  __syncthreads();

  int2 stgv[4];
  float stgx[4][8];

#pragma unroll 1
  for (int it = 0; it < 4; ++it) {
    int b = it & 1;
    if (it == 0) {
#pragma unroll
      for (int i = 0; i < 4; ++i) {
        int p = tid + 256 * i, row = p >> 3, s = (p & 7) ^ (row & 7);
        int grow = bm0 + row; if (grow > M - 1) grow = M - 1;
        size_t base = (size_t)grow * 256 + s * 8;
        stgv[i] = *(const int2*)(Vq + base);
        *(float4*)&stgx[i][0] = *(const float4*)(x + base);
        *(float4*)&stgx[i][4] = *(const float4*)(x + base + 4);
      }
#pragma unroll
      for (int q = 0; q < 4; ++q) {
        int wc = w * 4 + q;
        int p = wc * 64 + lane, row = p >> 3, s = (p & 7) ^ (row & 7);
        gload16(BT + (size_t)row * 256 + s * 8, smem + 16384 + wc * 1024);
      }
#pragma unroll
      for (int i = 0; i < 4; ++i) {
        int p = tid + 256 * i, row = p >> 3, s = (p & 7) ^ (row & 7);
        int k0 = s * 8;
        float fv[8];
        up4(stgv[i].x, fv); up4(stgv[i].y, fv + 4);
        bf16x8 o;
#pragma unroll
        for (int jj = 0; jj < 8; ++jj) {
          float f = fv[jj] * lsc[k0 + jj] + lsh[k0 + jj];
          f = f > 0.f ? f : 0.1f * f;
          o[jj] = f2bf(stgx[i][jj] + 0.01f * f);
        }
        *(bf16x8*)(smem + p * 16) = o;
      }
      __syncthreads();
    }
    int ktn = (it + 1) * 64;
    if (it < 3) {
      char* nb = smem + (b ^ 1) * 32768;
#pragma unroll
      for (int i = 0; i < 4; ++i) {
        int p = tid + 256 * i, row = p >> 3, s = (p & 7) ^ (row & 7);
        int grow = bm0 + row; if (grow > M - 1) grow = M - 1;
        size_t base = (size_t)grow * 256 + ktn + s * 8;
        stgv[i] = *(const int2*)(Vq + base);
        *(float4*)&stgx[i][0] = *(const float4*)(x + base);
        *(float4*)&stgx[i][4] = *(const float4*)(x + base + 4);
      }
#pragma unroll
      for (int q = 0; q < 4; ++q) {
        int wc = w * 4 + q;
        int p = wc * 64 + lane, row = p >> 3, s = (p & 7) ^ (row & 7);
        gload16(BT + (size_t)row * 256 + ktn + s * 8, nb + 16384 + wc * 1024);
      }
    }
    const char* sa = smem + b * 32768;
    const char* sb = sa + 16384;
#pragma unroll
    for (int ks = 0; ks < 2; ++ks) {
      bf16x8 af[4], bfr[4];
#pragma unroll
      for (int mi = 0; mi < 4; ++mi) {
        int row = wm * 64 + mi * 16 + lr;
        int q = (lg + 4 * ks) ^ (row & 7);
        af[mi] = *(const bf16x8*)(sa + row * 128 + q * 16);
      }
#pragma unroll
      for (int ni = 0; ni < 4; ++ni) {
        int row = wn * 64 + ni * 16 + lr;
        int q = (lg + 4 * ks) ^ (row & 7);
        bfr[ni] = *(const bf16x8*)(sb + row * 128 + q * 16);
      }
#pragma unroll
      for (int mi = 0; mi < 4; ++mi)
#pragma unroll
        for (int ni = 0; ni < 4; ++ni)
          acc[mi][ni] = __builtin_amdgcn_mfma_f32_16x16x32_bf16(af[mi], bfr[ni], acc[mi][ni], 0, 0, 0);
    }
    if (it < 3) {
      char* nb = smem + (b ^ 1) * 32768;
#pragma unroll
      for (int i = 0; i < 4; ++i) {
        int p = tid + 256 * i, row = p >> 3, s = (p & 7) ^ (row & 7);
        int k0 = ktn + s * 8;
        float fv[8];
        up4(stgv[i].x, fv); up4(stgv[i].y, fv + 4);
        bf16x8 o;
#pragma unroll
        for (int jj = 0; jj < 8; ++jj) {
          float f = fv[jj] * lsc[k0 + jj] + lsh[k0 + jj];
          f = f > 0.f ? f : 0.1f * f;
          o[jj] = f2bf(stgx[i][jj] + 0.01f * f);
        }
        *(bf16x8*)(nb + p * 16) = o;
      }
    }
    __syncthreads();
  }

  // z epilogue -> LDS [128][136] bf16
  short* zs = (short*)smem;
#pragma unroll
  for (int ni = 0; ni < 4; ++ni) {
    int col = wn * 64 + ni * 16 + lr;
    float bv = bl1[col];
#pragma unroll
    for (int mi = 0; mi < 4; ++mi) {
#pragma unroll
      for (int r = 0; r < 4; ++r) {
        int row = wm * 64 + mi * 16 + lg * 4 + r;
        float tv = acc[mi][ni][r] + bv;
        tv = tv > 0.f ? tv : 0.1f * tv;
        zs[row * 136 + col] = f2bf(tv);
      }
    }
  }
  __syncthreads();

  // out = z @ Wl3 + bl3 via MFMA: each wave does 2 M-tiles, N=16 (10 valid)
  f32x4 acc2[2] = {};
#pragma unroll
  for (int kk = 0; kk < 4; ++kk) {
    bf16x8 bfr = *(const bf16x8*)((const char*)wl3s + lr * 256 + (kk * 4 + lg) * 16);
#pragma unroll
    for (int m = 0; m < 2; ++m) {
      int row = (w * 2 + m) * 16 + lr;
      bf16x8 af = *(const bf16x8*)((const char*)zs + row * 272 + (kk * 4 + lg) * 16);
      acc2[m] = __builtin_amdgcn_mfma_f32_16x16x32_bf16(af, bfr, acc2[m], 0, 0, 0);
    }
  }
  if (lr < 10) {
    float bv = bl3[lr];
#pragma unroll
    for (int m = 0; m < 2; ++m) {
#pragma unroll
      for (int r = 0; r < 4; ++r) {
        int row = (w * 2 + m) * 16 + lg * 4 + r;
        int grow = bm0 + row;
        if (grow < M) out[(size_t)grow * 10 + lr] = acc2[m][r] + bv;
      }
    }
  }
}

extern "C" void kernel_launch(void* const* d_in, const int* in_sizes, int n_in,
                              void* d_out, int out_size, void* d_ws, size_t ws_size,
                              hipStream_t stream) {
  const float* x   = (const float*)d_in[0];
  const int*   ew  = (const int*)d_in[1];
  const float* W1  = (const float*)d_in[2];
  const float* b1  = (const float*)d_in[3];
  const float* g1  = (const float*)d_in[4];
  const float* be1 = (const float*)d_in[5];
  const float* W2  = (const float*)d_in[6];
  const float* b2  = (const float*)d_in[7];
  const float* g4  = (const float*)d_in[8];
  const float* be4 = (const float*)d_in[9];
  const float* Wl1 = (const float*)d_in[10];
  const float* bl1 = (const float*)d_in[11];
  const float* Wl3 = (const float*)d_in[12];
  const float* bl3 = (const float*)d_in[13];
  float* out = (float*)d_out;

  char* ws = (char*)d_ws;
  const size_t OFF_OFF  = 0;          // (N+1) ints
  const size_t OFF_BASES= 400128;     // NBUCK+1 ints
  const size_t OFF_CNT  = 800256;     // CGRID x NBUCK ints (306KB)
  const size_t OFF_WL3T = 1106944;    // 16x128 bf16 (4KB)
  const size_t OFF_STATS= 1200384;    // 4x256 f32 (zeroed in k_detect)
  const size_t OFF_BN   = 1204480;    // 4x256 f32 (sc1,sh1,sc4,sh4)
  const size_t OFF_FLAG = 1208576;
  const size_t OFF_W1T  = 1209216;    // fp8 64KB
  const size_t OFF_W2T  = 1340288;    // fp8 64KB
  const size_t OFF_WL1T = 1471360;    // bf16 64KB
  const size_t OFF_CSR  = 1536896;    // NE ints (6.4MB)
  const size_t OFF_BUFA = 7936896;    // pairs (6.4MB) aliases; h0/h2 fp8 25.6MB
  const size_t OFF_BUFB = 59136896;   // xq fp8 25.6MB aliases; h1 fp8 25.6MB
  if (ws_size < 110336896) return;

  int* off_  = (int*)(ws + OFF_OFF);
  int* bases_= (int*)(ws + OFF_BASES);
  int* cnt_  = (int*)(ws + OFF_CNT);
  float* sum1 = (float*)(ws + OFF_STATS);
  float* ssq1 = sum1 + 256;
  float* sum4 = sum1 + 512;
  float* ssq4 = sum1 + 768;
  float* sc1 = (float*)(ws + OFF_BN);
  float* sh1 = sc1 + 256;
  float* sc4 = sc1 + 512;
  float* sh4 = sc1 + 768;
  int* flag_ = (int*)(ws + OFF_FLAG);
  unsigned char* W1T8 = (unsigned char*)(ws + OFF_W1T);
  unsigned char* W2T8 = (unsigned char*)(ws + OFF_W2T);
  short* Wl1T = (short*)(ws + OFF_WL1T);
  short* Wl3T = (short*)(ws + OFF_WL3T);
  int* csr_   = (int*)(ws + OFF_CSR);
  unsigned char* bufA = (unsigned char*)(ws + OFF_BUFA);
  unsigned char* bufB = (unsigned char*)(ws + OFF_BUFB);
  int* pairs_ = (int*)(ws + OFF_BUFA);  // alias: dead before k_agg2 writes bufA
  void* xq    = (void*)bufB;            // alias: dead before GEMM1 writes bufB

  k_detect<<<1, 256, 0, stream>>>(ew, flag_, sum1);
  k_cvtW<<<641, 256, 0, stream>>>(W1, W2, Wl1, Wl3, W1T8, W2T8, Wl1T, Wl3T);
  k_cvtX<<<12500, 256, 0, stream>>>(x, xq);
  k_count<<<CGRID, 1024, 0, stream>>>(ew, flag_, cnt_);
  k_colscan<<<1, 1024, 0, stream>>>(cnt_, bases_, off_);
  k_scatter<<<CGRID, 1024, 0, stream>>>(ew, flag_, cnt_, pairs_);
  k_bsort<<<NBUCK, 256, 0, stream>>>(pairs_, bases_, off_, csr_);
  k_agg2<<<25000, 256, 0, stream>>>(xq, off_, csr_, bufA);
  k_gemm8<0, 0, 1><<<1564, 256, 0, stream>>>(bufA, W1T8, b1, bufB, NN,
                                             nullptr, nullptr, sum1, ssq1);
  k_bnprep<<<1, 256, 0, stream>>>(sum1, ssq1, g1, be1, sc1, sh1, NN);
  k_gemm8<1, 1, 1><<<1564, 256, 0, stream>>>(bufB, W2T8, b2, bufA, NN,
                                             sc1, sh1, sum4, ssq4);
  k_bnprep<<<1, 256, 0, stream>>>(sum4, ssq4, g4, be4, sc4, sh4, NN);
  k_head<<<782, 256, 0, stream>>>(bufA, x, Wl1T, bl1, Wl3T, bl3, sc4, sh4, out, NN);
}